// Round 1
// baseline (6433.689 us; speedup 1.0000x reference)
//
#include <hip/hip_runtime.h>
#include <math.h>

#define EPS_F 1e-5f

// ---------------------------------------------------------------------------
// Per-block (sum, sumsq) reduction -> 2 atomicAdds into stats[2*cidx].
// Block = 256 threads = 4 waves of 64.
// ---------------------------------------------------------------------------
__device__ __forceinline__ void block_stats_atomic(float acc, float* __restrict__ stats, int cidx)
{
    float s = acc, s2 = acc * acc;
    #pragma unroll
    for (int off = 32; off > 0; off >>= 1) {
        s  += __shfl_down(s,  off, 64);
        s2 += __shfl_down(s2, off, 64);
    }
    __shared__ float red[8];
    int wv = threadIdx.x >> 6;
    if ((threadIdx.x & 63) == 0) { red[wv] = s; red[4 + wv] = s2; }
    __syncthreads();
    if (threadIdx.x == 0) {
        atomicAdd(&stats[2 * cidx],     red[0] + red[1] + red[2] + red[3]);
        atomicAdd(&stats[2 * cidx + 1], red[4] + red[5] + red[6] + red[7]);
    }
}

// ---------------------------------------------------------------------------
// KxK conv, stride 1, reflect pad K/2. One block = (b, oc, 256-pixel tile).
// Weights (Cin*K*K floats for this oc) staged in LDS.
// ---------------------------------------------------------------------------
template<int K, bool STATS, bool TANH>
__global__ __launch_bounds__(256) void conv_reflect(
    const float* __restrict__ in, const float* __restrict__ wgt,
    const float* __restrict__ bias, float* __restrict__ out,
    float* __restrict__ stats, int Cin, int Cout, int H, int W)
{
    const int HW    = H * W;
    const int tiles = HW >> 8;
    int bi   = blockIdx.x;
    int tile = bi % tiles;
    int t2   = bi / tiles;
    int oc   = t2 % Cout;
    int b    = t2 / Cout;
    int p    = (tile << 8) + threadIdx.x;
    int y    = p / W, x = p - y * W;

    extern __shared__ float lw[];
    const int K2 = K * K;
    int nw = Cin * K2;
    for (int e = threadIdx.x; e < nw; e += 256) lw[e] = wgt[oc * nw + e];
    __syncthreads();

    const int P = K / 2;
    int iys[K], ixs[K];
    #pragma unroll
    for (int k = 0; k < K; k++) {
        int iy = y - P + k;
        iy = iy < 0 ? -iy : iy;
        iy = iy >= H ? 2 * H - 2 - iy : iy;
        iys[k] = iy * W;
        int ix = x - P + k;
        ix = ix < 0 ? -ix : ix;
        ix = ix >= W ? 2 * W - 2 - ix : ix;
        ixs[k] = ix;
    }

    float acc = bias[oc];
    const float* inb = in + (size_t)b * Cin * HW;
    for (int ci = 0; ci < Cin; ci++) {
        const float* ip = inb + (size_t)ci * HW;
        const float* wp = lw + ci * K2;
        #pragma unroll
        for (int ky = 0; ky < K; ky++) {
            const float* rowp = ip + iys[ky];
            #pragma unroll
            for (int kx = 0; kx < K; kx++)
                acc = fmaf(rowp[ixs[kx]], wp[ky * K + kx], acc);
        }
    }
    out[(size_t)(b * Cout + oc) * HW + p] = TANH ? tanhf(acc) : acc;
    if (STATS) block_stats_atomic(acc, stats, b * Cout + oc);
}

// ---------------------------------------------------------------------------
// 3x3 conv, stride 2, zero pad 1.  Hout = Hin/2.
// ---------------------------------------------------------------------------
__global__ __launch_bounds__(256) void conv3s2(
    const float* __restrict__ in, const float* __restrict__ wgt,
    const float* __restrict__ bias, float* __restrict__ out,
    float* __restrict__ stats, int Cin, int Cout,
    int Hin, int Win, int Hout, int Wout)
{
    const int HWo   = Hout * Wout;
    const int tiles = HWo >> 8;
    int bi   = blockIdx.x;
    int tile = bi % tiles;
    int t2   = bi / tiles;
    int oc   = t2 % Cout;
    int b    = t2 / Cout;
    int p    = (tile << 8) + threadIdx.x;
    int y    = p / Wout, x = p - y * Wout;

    extern __shared__ float lw[];
    int nw = Cin * 9;
    for (int e = threadIdx.x; e < nw; e += 256) lw[e] = wgt[oc * nw + e];
    __syncthreads();

    int iy0 = 2 * y - 1, ix0 = 2 * x - 1;
    const int HWi = Hin * Win;
    const float* inb = in + (size_t)b * Cin * HWi;
    float acc = bias[oc];
    for (int ci = 0; ci < Cin; ci++) {
        const float* ip = inb + (size_t)ci * HWi;
        const float* wp = lw + ci * 9;
        #pragma unroll
        for (int ky = 0; ky < 3; ky++) {
            int iy = iy0 + ky;
            if ((unsigned)iy >= (unsigned)Hin) continue;
            const float* rowp = ip + iy * Win;
            #pragma unroll
            for (int kx = 0; kx < 3; kx++) {
                int ix = ix0 + kx;
                if ((unsigned)ix >= (unsigned)Win) continue;
                acc = fmaf(rowp[ix], wp[ky * 3 + kx], acc);
            }
        }
    }
    out[(size_t)(b * Cout + oc) * HWo + p] = acc;
    block_stats_atomic(acc, stats, b * Cout + oc);
}

// ---------------------------------------------------------------------------
// ConvTranspose2d k=3 s=2 p=1 op=1, torch weight layout (Cin, Cout, 3, 3).
// Direct gather: tap (ky,kx) valid iff (y+1-ky) even etc.  Hout = 2*Hin.
// ---------------------------------------------------------------------------
__global__ __launch_bounds__(256) void deconv3s2(
    const float* __restrict__ in, const float* __restrict__ wgt,
    const float* __restrict__ bias, float* __restrict__ out,
    float* __restrict__ stats, int Cin, int Cout,
    int Hin, int Win, int Hout, int Wout)
{
    const int HWo   = Hout * Wout;
    const int tiles = HWo >> 8;
    int bi   = blockIdx.x;
    int tile = bi % tiles;
    int t2   = bi / tiles;
    int oc   = t2 % Cout;
    int b    = t2 / Cout;
    int p    = (tile << 8) + threadIdx.x;
    int y    = p / Wout, x = p - y * Wout;

    extern __shared__ float lw[];   // [Cin][9] for this oc
    int nw = Cin * 9;
    for (int e = threadIdx.x; e < nw; e += 256) {
        int ci = e / 9, k = e - ci * 9;
        lw[e] = wgt[(ci * Cout + oc) * 9 + k];
    }
    __syncthreads();

    const int HWi = Hin * Win;
    const float* inb = in + (size_t)b * Cin * HWi;
    float acc = bias[oc];
    #pragma unroll
    for (int ky = 0; ky < 3; ky++) {
        int ty = y + 1 - ky;
        int iy = ty >> 1;
        if ((ty & 1) || (unsigned)iy >= (unsigned)Hin) continue;
        #pragma unroll
        for (int kx = 0; kx < 3; kx++) {
            int tx = x + 1 - kx;
            int ix = tx >> 1;
            if ((tx & 1) || (unsigned)ix >= (unsigned)Win) continue;
            const float* ip = inb + iy * Win + ix;
            const float* wp = lw + ky * 3 + kx;
            for (int ci = 0; ci < Cin; ci++)
                acc = fmaf(ip[(size_t)ci * HWi], wp[ci * 9], acc);
        }
    }
    out[(size_t)(b * Cout + oc) * HWo + p] = acc;
    block_stats_atomic(acc, stats, b * Cout + oc);
}

// ---------------------------------------------------------------------------
// In-place instance-norm + ReLU. stats[2*c] = sum, stats[2*c+1] = sumsq.
// HW is a power of two -> pass log2(HW) as shift.
// ---------------------------------------------------------------------------
__global__ __launch_bounds__(256) void inorm_relu(
    float* __restrict__ buf, const float* __restrict__ stats,
    int shift, float invHW, int N)
{
    int idx = blockIdx.x * 256 + threadIdx.x;
    if (idx >= N) return;
    int c  = idx >> shift;
    float s  = stats[2 * c];
    float s2 = stats[2 * c + 1];
    float m  = s * invHW;
    float v  = fmaf(s2, invHW, -m * m);
    float r  = rsqrtf(v + EPS_F);
    float val = (buf[idx] - m) * r;
    buf[idx] = fmaxf(val, 0.f);
}

// ---------------------------------------------------------------------------
// Segment mean over [B,3,512,512] with labels inst[B,1,512,512] in [0,32).
// acc layout: [32][4] = {sum_c0, sum_c1, sum_c2, count}
// ---------------------------------------------------------------------------
#define HW9 262144
__global__ __launch_bounds__(256) void seg_accum(
    const float* __restrict__ y, const int* __restrict__ inst,
    float* __restrict__ acc)
{
    __shared__ float l[128];
    if (threadIdx.x < 128) l[threadIdx.x] = 0.f;
    __syncthreads();
    int p   = blockIdx.x * 256 + threadIdx.x;
    int b   = p >> 18;
    int r   = p & (HW9 - 1);
    int lab = inst[p] & 31;
    const float* yb = y + (size_t)b * 3 * HW9;
    atomicAdd(&l[lab * 4 + 0], yb[r]);
    atomicAdd(&l[lab * 4 + 1], yb[HW9 + r]);
    atomicAdd(&l[lab * 4 + 2], yb[2 * HW9 + r]);
    atomicAdd(&l[lab * 4 + 3], 1.f);
    __syncthreads();
    if (threadIdx.x < 128) {
        float v = l[threadIdx.x];
        if (v != 0.f) atomicAdd(&acc[threadIdx.x], v);
    }
}

__global__ void seg_final(const float* __restrict__ acc, float* __restrict__ means)
{
    int i = threadIdx.x;
    if (i < 96) {
        int s = i / 3, c = i - s * 3;
        means[i] = acc[s * 4 + c] / fmaxf(acc[s * 4 + 3], 1.f);
    }
}

__global__ __launch_bounds__(256) void seg_scatter(
    const int* __restrict__ inst, const float* __restrict__ means,
    float* __restrict__ out)
{
    int p   = blockIdx.x * 256 + threadIdx.x;
    int b   = p >> 18;
    int r   = p & (HW9 - 1);
    int lab = inst[p] & 31;
    float* ob = out + (size_t)b * 3 * HW9;
    float m0 = means[lab * 3 + 0];
    float m1 = means[lab * 3 + 1];
    float m2 = means[lab * 3 + 2];
    ob[r]           = m0;
    ob[HW9 + r]     = m1;
    ob[2 * HW9 + r] = m2;
}

// ---------------------------------------------------------------------------
// Launch
// ---------------------------------------------------------------------------
extern "C" void kernel_launch(void* const* d_in, const int* in_sizes, int n_in,
                              void* d_out, int out_size, void* d_ws, size_t ws_size,
                              hipStream_t stream)
{
    const float* x_in = (const float*)d_in[0];
    const int*   inst = (const int*)d_in[1];
    const float* W_[10];
    const float* Bs[10];
    for (int i = 0; i < 10; i++) {
        W_[i] = (const float*)d_in[2 + 2 * i];
        Bs[i] = (const float*)d_in[3 + 2 * i];
    }
    float* out = (float*)d_out;

    // Workspace layout (floats): A = 16,777,216 (64MB), B = 8,388,608 (32MB),
    // then stats (5888) + segacc (128) + means (96).
    float* A  = (float*)d_ws;
    float* Bb = A + (size_t)16777216;
    float* st = Bb + (size_t)8388608;
    const int coff[9] = {0, 128, 384, 896, 1920, 3968, 4992, 5504, 5760};
    float* s_[9];
    for (int i = 0; i < 9; i++) s_[i] = st + coff[i];
    float* segacc = st + 5888;
    float* means  = st + 6016;
    hipMemsetAsync(st, 0, 6016 * sizeof(float), stream);

    // L0: 7x7 reflect, 3->16 @512
    conv_reflect<7, true, false><<<dim3(4 * 16 * 1024), dim3(256), 3 * 49 * 4, stream>>>(
        x_in, W_[0], Bs[0], A, s_[0], 3, 16, 512, 512);
    inorm_relu<<<dim3(16777216 / 256), dim3(256), 0, stream>>>(A, s_[0], 18, 1.f / 262144.f, 16777216);

    // L1: 3x3 s2, 16->32 @512->256
    conv3s2<<<dim3(4 * 32 * 256), dim3(256), 16 * 9 * 4, stream>>>(
        A, W_[1], Bs[1], Bb, s_[1], 16, 32, 512, 512, 256, 256);
    inorm_relu<<<dim3(8388608 / 256), dim3(256), 0, stream>>>(Bb, s_[1], 16, 1.f / 65536.f, 8388608);

    // L2: 32->64 @256->128
    conv3s2<<<dim3(4 * 64 * 64), dim3(256), 32 * 9 * 4, stream>>>(
        Bb, W_[2], Bs[2], A, s_[2], 32, 64, 256, 256, 128, 128);
    inorm_relu<<<dim3(4194304 / 256), dim3(256), 0, stream>>>(A, s_[2], 14, 1.f / 16384.f, 4194304);

    // L3: 64->128 @128->64
    conv3s2<<<dim3(4 * 128 * 16), dim3(256), 64 * 9 * 4, stream>>>(
        A, W_[3], Bs[3], Bb, s_[3], 64, 128, 128, 128, 64, 64);
    inorm_relu<<<dim3(2097152 / 256), dim3(256), 0, stream>>>(Bb, s_[3], 12, 1.f / 4096.f, 2097152);

    // L4: 128->256 @64->32
    conv3s2<<<dim3(4 * 256 * 4), dim3(256), 128 * 9 * 4, stream>>>(
        Bb, W_[4], Bs[4], A, s_[4], 128, 256, 64, 64, 32, 32);
    inorm_relu<<<dim3(1048576 / 256), dim3(256), 0, stream>>>(A, s_[4], 10, 1.f / 1024.f, 1048576);

    // L5: deconv 256->128 @32->64
    deconv3s2<<<dim3(4 * 128 * 16), dim3(256), 256 * 9 * 4, stream>>>(
        A, W_[5], Bs[5], Bb, s_[5], 256, 128, 32, 32, 64, 64);
    inorm_relu<<<dim3(2097152 / 256), dim3(256), 0, stream>>>(Bb, s_[5], 12, 1.f / 4096.f, 2097152);

    // L6: deconv 128->64 @64->128
    deconv3s2<<<dim3(4 * 64 * 64), dim3(256), 128 * 9 * 4, stream>>>(
        Bb, W_[6], Bs[6], A, s_[6], 128, 64, 64, 64, 128, 128);
    inorm_relu<<<dim3(4194304 / 256), dim3(256), 0, stream>>>(A, s_[6], 14, 1.f / 16384.f, 4194304);

    // L7: deconv 64->32 @128->256
    deconv3s2<<<dim3(4 * 32 * 256), dim3(256), 64 * 9 * 4, stream>>>(
        A, W_[7], Bs[7], Bb, s_[7], 64, 32, 128, 128, 256, 256);
    inorm_relu<<<dim3(8388608 / 256), dim3(256), 0, stream>>>(Bb, s_[7], 16, 1.f / 65536.f, 8388608);

    // L8: deconv 32->16 @256->512
    deconv3s2<<<dim3(4 * 16 * 1024), dim3(256), 32 * 9 * 4, stream>>>(
        Bb, W_[8], Bs[8], A, s_[8], 32, 16, 256, 256, 512, 512);
    inorm_relu<<<dim3(16777216 / 256), dim3(256), 0, stream>>>(A, s_[8], 18, 1.f / 262144.f, 16777216);

    // L9: 7x7 reflect + tanh, 16->3 @512
    conv_reflect<7, false, true><<<dim3(4 * 3 * 1024), dim3(256), 16 * 49 * 4, stream>>>(
        A, W_[9], Bs[9], Bb, nullptr, 16, 3, 512, 512);

    // Segment mean over the whole batch, then scatter to output.
    seg_accum<<<dim3(1048576 / 256), dim3(256), 0, stream>>>(Bb, inst, segacc);
    seg_final<<<dim3(1), dim3(96), 0, stream>>>(segacc, means);
    seg_scatter<<<dim3(1048576 / 256), dim3(256), 0, stream>>>(inst, means, out);
}

// Round 2
// 1940.536 us; speedup vs baseline: 3.3154x; 3.3154x over previous
//
#include <hip/hip_runtime.h>
#include <math.h>

#define EPS_F 1e-5f

__device__ __forceinline__ float fsel(const float4& v, int c) {
    return c == 0 ? v.x : c == 1 ? v.y : c == 2 ? v.z : v.w;
}

// ---------------------------------------------------------------------------
// Fused per-oc (sum, sumsq) block reduction -> global atomics.
// ---------------------------------------------------------------------------
template<int OCB, int PIXB>
__device__ __forceinline__ void stats_reduce(
    float4 (&a)[PIXB][OCB / 4], float* __restrict__ stats, int cbase)
{
    __shared__ float red[4][OCB][2];
    int lane = threadIdx.x & 63, wv = threadIdx.x >> 6;
    #pragma unroll
    for (int oc = 0; oc < OCB; oc++) {
        float s = 0.f, s2 = 0.f;
        #pragma unroll
        for (int u = 0; u < PIXB; u++) {
            float v = fsel(a[u][oc >> 2], oc & 3);
            s += v; s2 = fmaf(v, v, s2);
        }
        #pragma unroll
        for (int off = 32; off; off >>= 1) {
            s  += __shfl_down(s,  off, 64);
            s2 += __shfl_down(s2, off, 64);
        }
        if (lane == 0) { red[wv][oc][0] = s; red[wv][oc][1] = s2; }
    }
    __syncthreads();
    if ((int)threadIdx.x < OCB) {
        float s = 0.f, s2 = 0.f;
        #pragma unroll
        for (int w = 0; w < 4; w++) { s += red[w][threadIdx.x][0]; s2 += red[w][threadIdx.x][1]; }
        atomicAdd(&stats[2 * (cbase + threadIdx.x)],     s);
        atomicAdd(&stats[2 * (cbase + threadIdx.x) + 1], s2);
    }
}

// ---------------------------------------------------------------------------
// 7x7 stride-1 reflect-pad-3 conv. Thread computes OCB ocs x PIXB pixels.
// Weights in LDS laid out [ci][k][OCB] (float4-aligned, uniform reads).
// ---------------------------------------------------------------------------
template<int OCB, int PIXB, bool STATS, bool TANH>
__global__ __launch_bounds__(256) void conv7k(
    const float* __restrict__ in, const float* __restrict__ wgt,
    const float* __restrict__ bias, float* __restrict__ out,
    float* __restrict__ stats, int Cin, int Cout, int H, int W, int wsh, int nG)
{
    const int HW = H * W;
    const int T  = HW / (256 * PIXB);
    int bi = blockIdx.x;
    int t  = bi % T;  bi /= T;
    int g  = bi % nG;
    int b  = bi / nG;

    extern __shared__ float lw[];
    const int NW = Cin * 49 * OCB;
    for (int e = threadIdx.x; e < NW; e += 256) {
        int oc = e % OCB;
        int k  = (e / OCB) % 49;
        int ci = e / (OCB * 49);
        int ocg = g * OCB + oc;
        lw[e] = (ocg < Cout) ? wgt[((size_t)ocg * Cin + ci) * 49 + k] : 0.f;
    }
    __syncthreads();

    int p[PIXB];
    int iys[PIXB][7], ixs[PIXB][7];
    #pragma unroll
    for (int u = 0; u < PIXB; u++) {
        p[u] = t * (256 * PIXB) + u * 256 + threadIdx.x;
        int y = p[u] >> wsh, x = p[u] & (W - 1);
        #pragma unroll
        for (int k = 0; k < 7; k++) {
            int iy = y - 3 + k;
            iy = iy < 0 ? -iy : iy;
            iy = iy >= H ? 2 * H - 2 - iy : iy;
            iys[u][k] = iy * W;
            int ix = x - 3 + k;
            ix = ix < 0 ? -ix : ix;
            ix = ix >= W ? 2 * W - 2 - ix : ix;
            ixs[u][k] = ix;
        }
    }

    float4 acc[PIXB][OCB / 4];
    #pragma unroll
    for (int q = 0; q < OCB / 4; q++) {
        int o = g * OCB + q * 4;
        float4 bq;
        bq.x = (o + 0 < Cout) ? bias[o + 0] : 0.f;
        bq.y = (o + 1 < Cout) ? bias[o + 1] : 0.f;
        bq.z = (o + 2 < Cout) ? bias[o + 2] : 0.f;
        bq.w = (o + 3 < Cout) ? bias[o + 3] : 0.f;
        #pragma unroll
        for (int u = 0; u < PIXB; u++) acc[u][q] = bq;
    }

    const float* inb = in + (size_t)b * Cin * HW;
    for (int ci = 0; ci < Cin; ci++) {
        const float* ip = inb + (size_t)ci * HW;
        const float4* wq = (const float4*)(lw + (size_t)ci * 49 * OCB);
        #pragma unroll
        for (int ky = 0; ky < 7; ky++) {
            #pragma unroll
            for (int kx = 0; kx < 7; kx++) {
                float v[PIXB];
                #pragma unroll
                for (int u = 0; u < PIXB; u++)
                    v[u] = ip[iys[u][ky] + ixs[u][kx]];
                int k = ky * 7 + kx;
                #pragma unroll
                for (int q = 0; q < OCB / 4; q++) {
                    float4 w = wq[k * (OCB / 4) + q];
                    #pragma unroll
                    for (int u = 0; u < PIXB; u++) {
                        acc[u][q].x = fmaf(v[u], w.x, acc[u][q].x);
                        acc[u][q].y = fmaf(v[u], w.y, acc[u][q].y);
                        acc[u][q].z = fmaf(v[u], w.z, acc[u][q].z);
                        acc[u][q].w = fmaf(v[u], w.w, acc[u][q].w);
                    }
                }
            }
        }
    }

    #pragma unroll
    for (int q = 0; q < OCB / 4; q++) {
        #pragma unroll
        for (int c = 0; c < 4; c++) {
            int ocg = g * OCB + q * 4 + c;
            if (ocg < Cout) {
                float* op = out + (size_t)(b * Cout + ocg) * HW;
                #pragma unroll
                for (int u = 0; u < PIXB; u++) {
                    float vv = fsel(acc[u][q], c);
                    op[p[u]] = TANH ? tanhf(vv) : vv;
                }
            }
        }
    }
    if (STATS) stats_reduce<OCB, PIXB>(acc, stats, b * Cout + g * OCB);
}

// ---------------------------------------------------------------------------
// 3x3 stride-2 zero-pad-1 conv. OCB ocs x PIXB pixels per thread.
// Weights staged per ci-chunk (CH) in LDS [cc][k][OCB].
// ---------------------------------------------------------------------------
template<int OCB, int PIXB>
__global__ __launch_bounds__(256) void conv3s2k(
    const float* __restrict__ in, const float* __restrict__ wgt,
    const float* __restrict__ bias, float* __restrict__ out,
    float* __restrict__ stats, int Cin, int Cout,
    int Hin, int Win, int Hout, int Wout, int wsho, int CH, int nG)
{
    const int HWo = Hout * Wout, HWi = Hin * Win;
    const int T = HWo / (256 * PIXB);
    int bi = blockIdx.x;
    int t  = bi % T;  bi /= T;
    int g  = bi % nG;
    int b  = bi / nG;

    extern __shared__ float lw[];

    int p[PIXB], off[PIXB][9];
    float fy[PIXB], fx[PIXB];
    #pragma unroll
    for (int u = 0; u < PIXB; u++) {
        p[u] = t * (256 * PIXB) + u * 256 + threadIdx.x;
        int y = p[u] >> wsho, x = p[u] & (Wout - 1);
        int iy0 = 2 * y - 1, ix0 = 2 * x - 1;
        fy[u] = iy0 >= 0 ? 1.f : 0.f;
        fx[u] = ix0 >= 0 ? 1.f : 0.f;
        int r0 = (iy0 < 0 ? 0 : iy0) * Win, r1 = (iy0 + 1) * Win, r2 = (iy0 + 2) * Win;
        int c0c = ix0 < 0 ? 0 : ix0, c1 = ix0 + 1, c2 = ix0 + 2;
        off[u][0] = r0 + c0c; off[u][1] = r0 + c1; off[u][2] = r0 + c2;
        off[u][3] = r1 + c0c; off[u][4] = r1 + c1; off[u][5] = r1 + c2;
        off[u][6] = r2 + c0c; off[u][7] = r2 + c1; off[u][8] = r2 + c2;
    }

    float4 acc[PIXB][OCB / 4];
    #pragma unroll
    for (int q = 0; q < OCB / 4; q++) {
        int o = g * OCB + q * 4;
        float4 bq = { bias[o], bias[o + 1], bias[o + 2], bias[o + 3] };
        #pragma unroll
        for (int u = 0; u < PIXB; u++) acc[u][q] = bq;
    }

    const float* inb = in + (size_t)b * Cin * HWi;
    for (int c0 = 0; c0 < Cin; c0 += CH) {
        int nw = CH * 9 * OCB;
        for (int e = threadIdx.x; e < nw; e += 256) {
            int oc = e & (OCB - 1);
            int k  = (e / OCB) % 9;
            int cc = e / (OCB * 9);
            lw[e] = wgt[((size_t)(g * OCB + oc) * Cin + c0 + cc) * 9 + k];
        }
        __syncthreads();
        for (int ci = 0; ci < CH; ci++) {
            const float* ip = inb + (size_t)(c0 + ci) * HWi;
            const float4* wq = (const float4*)(lw + (size_t)ci * 9 * OCB);
            #pragma unroll
            for (int ky = 0; ky < 3; ky++) {
                #pragma unroll
                for (int kx = 0; kx < 3; kx++) {
                    int k = ky * 3 + kx;
                    float v[PIXB];
                    #pragma unroll
                    for (int u = 0; u < PIXB; u++) {
                        float vv = ip[off[u][k]];
                        if (ky == 0) vv *= fy[u];
                        if (kx == 0) vv *= fx[u];
                        v[u] = vv;
                    }
                    #pragma unroll
                    for (int q = 0; q < OCB / 4; q++) {
                        float4 w = wq[k * (OCB / 4) + q];
                        #pragma unroll
                        for (int u = 0; u < PIXB; u++) {
                            acc[u][q].x = fmaf(v[u], w.x, acc[u][q].x);
                            acc[u][q].y = fmaf(v[u], w.y, acc[u][q].y);
                            acc[u][q].z = fmaf(v[u], w.z, acc[u][q].z);
                            acc[u][q].w = fmaf(v[u], w.w, acc[u][q].w);
                        }
                    }
                }
            }
        }
        __syncthreads();
    }

    #pragma unroll
    for (int q = 0; q < OCB / 4; q++) {
        #pragma unroll
        for (int c = 0; c < 4; c++) {
            int ocg = g * OCB + q * 4 + c;
            float* op = out + (size_t)(b * Cout + ocg) * HWo;
            #pragma unroll
            for (int u = 0; u < PIXB; u++) op[p[u]] = fsel(acc[u][q], c);
        }
    }
    stats_reduce<OCB, PIXB>(acc, stats, b * Cout + g * OCB);
}

// ---------------------------------------------------------------------------
// ConvTranspose2d k=3 s=2 p=1 op=1 via parity classes. One block = one
// (b, oc-group, class, tile); tap set is wave-uniform per class.
// Weight layout (Cin, Cout, 3, 3); LDS [cc][t][OCB] per ci-chunk.
// ---------------------------------------------------------------------------
template<int OCB, int PIXB>
__global__ __launch_bounds__(256) void deconvk(
    const float* __restrict__ in, const float* __restrict__ wgt,
    const float* __restrict__ bias, float* __restrict__ out,
    float* __restrict__ stats, int Cin, int Cout,
    int Hin, int Win, int wshi, int CH, int nG)
{
    const int HWi = Hin * Win;
    const int Wout = 2 * Win;
    const int HWo = 4 * HWi;
    const int T = HWi / (256 * PIXB);
    int bi = blockIdx.x;
    int t   = bi % T;  bi /= T;
    int cls = bi & 3;  bi >>= 2;
    int g   = bi % nG;
    int b   = bi / nG;
    int py = cls >> 1, pxc = cls & 1;
    int nky = 1 + py, nkx = 1 + pxc;
    int ntap = nky * nkx;
    int lsh = py + pxc;               // log2(ntap)

    extern __shared__ float lw[];

    int po[PIXB];
    int row0[PIXB], row1[PIXB], col0[PIXB], col1[PIXB];
    float mr0[PIXB], mc0[PIXB];
    #pragma unroll
    for (int u = 0; u < PIXB; u++) {
        int sp = t * (256 * PIXB) + u * 256 + threadIdx.x;
        int sy = sp >> wshi, sx = sp & (Win - 1);
        int iya = sy + py;
        float my = iya < Hin ? 1.f : 0.f;
        int iyac = iya < Hin ? iya : Hin - 1;
        int ixa = sx + pxc;
        float mx = ixa < Win ? 1.f : 0.f;
        int ixac = ixa < Win ? ixa : Win - 1;
        row0[u] = (py ? iyac : sy) * Win;   mr0[u] = py ? my : 1.f;
        row1[u] = sy * Win;
        col0[u] = pxc ? ixac : sx;          mc0[u] = pxc ? mx : 1.f;
        col1[u] = sx;
        po[u] = (2 * sy + py) * Wout + 2 * sx + pxc;
    }

    float4 acc[PIXB][OCB / 4];
    #pragma unroll
    for (int q = 0; q < OCB / 4; q++) {
        int o = g * OCB + q * 4;
        float4 bq = { bias[o], bias[o + 1], bias[o + 2], bias[o + 3] };
        #pragma unroll
        for (int u = 0; u < PIXB; u++) acc[u][q] = bq;
    }

    const float* inb = in + (size_t)b * Cin * HWi;
    for (int c0 = 0; c0 < Cin; c0 += CH) {
        int nw = CH * ntap * OCB;
        for (int e = threadIdx.x; e < nw; e += 256) {
            int oc = e & (OCB - 1);
            int i2 = e / OCB;
            int tt = i2 & (ntap - 1);
            int cc = i2 >> lsh;
            int tky = (nkx == 2) ? (tt >> 1) : tt;
            int tkx = (nkx == 2) ? (tt & 1) : 0;
            int ky = py ? (tky ? 2 : 0) : 1;
            int kx = pxc ? (tkx ? 2 : 0) : 1;
            lw[e] = wgt[((size_t)(c0 + cc) * Cout + g * OCB + oc) * 9 + ky * 3 + kx];
        }
        __syncthreads();
        for (int ci = 0; ci < CH; ci++) {
            const float* ip = inb + (size_t)(c0 + ci) * HWi;
            const float4* wq = (const float4*)(lw + (size_t)ci * ntap * OCB);
            int tt = 0;
            #pragma unroll
            for (int tky = 0; tky < 2; tky++) {
                if (tky >= nky) break;
                #pragma unroll
                for (int tkx = 0; tkx < 2; tkx++) {
                    if (tkx >= nkx) break;
                    float v[PIXB];
                    #pragma unroll
                    for (int u = 0; u < PIXB; u++) {
                        int o = (tky ? row1[u] : row0[u]) + (tkx ? col1[u] : col0[u]);
                        float vv = ip[o];
                        if (tky == 0) vv *= mr0[u];
                        if (tkx == 0) vv *= mc0[u];
                        v[u] = vv;
                    }
                    #pragma unroll
                    for (int q = 0; q < OCB / 4; q++) {
                        float4 w = wq[tt * (OCB / 4) + q];
                        #pragma unroll
                        for (int u = 0; u < PIXB; u++) {
                            acc[u][q].x = fmaf(v[u], w.x, acc[u][q].x);
                            acc[u][q].y = fmaf(v[u], w.y, acc[u][q].y);
                            acc[u][q].z = fmaf(v[u], w.z, acc[u][q].z);
                            acc[u][q].w = fmaf(v[u], w.w, acc[u][q].w);
                        }
                    }
                    tt++;
                }
            }
        }
        __syncthreads();
    }

    #pragma unroll
    for (int q = 0; q < OCB / 4; q++) {
        #pragma unroll
        for (int c = 0; c < 4; c++) {
            int ocg = g * OCB + q * 4 + c;
            float* op = out + (size_t)(b * Cout + ocg) * HWo;
            #pragma unroll
            for (int u = 0; u < PIXB; u++) op[po[u]] = fsel(acc[u][q], c);
        }
    }
    stats_reduce<OCB, PIXB>(acc, stats, b * Cout + g * OCB);
}

// ---------------------------------------------------------------------------
// In-place instance-norm + ReLU, float4.
// ---------------------------------------------------------------------------
__global__ __launch_bounds__(256) void inorm_relu4(
    float4* __restrict__ buf, const float* __restrict__ stats,
    int sh, float invHW, int N4)
{
    int idx = blockIdx.x * 256 + threadIdx.x;
    if (idx >= N4) return;
    int c = idx >> sh;
    float s  = stats[2 * c];
    float s2 = stats[2 * c + 1];
    float m  = s * invHW;
    float v  = fmaf(s2, invHW, -m * m);
    float r  = rsqrtf(v + EPS_F);
    float4 x = buf[idx];
    x.x = fmaxf((x.x - m) * r, 0.f);
    x.y = fmaxf((x.y - m) * r, 0.f);
    x.z = fmaxf((x.z - m) * r, 0.f);
    x.w = fmaxf((x.w - m) * r, 0.f);
    buf[idx] = x;
}

// ---------------------------------------------------------------------------
// Segment mean over [B,3,512,512], labels in [0,32).
// ---------------------------------------------------------------------------
#define HW9 262144
__global__ __launch_bounds__(256) void seg_accum(
    const float* __restrict__ y, const int* __restrict__ inst,
    float* __restrict__ acc)
{
    __shared__ float l[128];
    if (threadIdx.x < 128) l[threadIdx.x] = 0.f;
    __syncthreads();
    int p   = blockIdx.x * 256 + threadIdx.x;
    int b   = p >> 18;
    int r   = p & (HW9 - 1);
    int lab = inst[p] & 31;
    const float* yb = y + (size_t)b * 3 * HW9;
    atomicAdd(&l[lab * 4 + 0], yb[r]);
    atomicAdd(&l[lab * 4 + 1], yb[HW9 + r]);
    atomicAdd(&l[lab * 4 + 2], yb[2 * HW9 + r]);
    atomicAdd(&l[lab * 4 + 3], 1.f);
    __syncthreads();
    if (threadIdx.x < 128) {
        float v = l[threadIdx.x];
        if (v != 0.f) atomicAdd(&acc[threadIdx.x], v);
    }
}

__global__ void seg_final(const float* __restrict__ acc, float* __restrict__ means)
{
    int i = threadIdx.x;
    if (i < 96) {
        int s = i / 3, c = i - s * 3;
        means[i] = acc[s * 4 + c] / fmaxf(acc[s * 4 + 3], 1.f);
    }
}

__global__ __launch_bounds__(256) void seg_scatter(
    const int* __restrict__ inst, const float* __restrict__ means,
    float* __restrict__ out)
{
    int p   = blockIdx.x * 256 + threadIdx.x;
    int b   = p >> 18;
    int r   = p & (HW9 - 1);
    int lab = inst[p] & 31;
    float* ob = out + (size_t)b * 3 * HW9;
    ob[r]           = means[lab * 3 + 0];
    ob[HW9 + r]     = means[lab * 3 + 1];
    ob[2 * HW9 + r] = means[lab * 3 + 2];
}

// ---------------------------------------------------------------------------
// Launch
// ---------------------------------------------------------------------------
extern "C" void kernel_launch(void* const* d_in, const int* in_sizes, int n_in,
                              void* d_out, int out_size, void* d_ws, size_t ws_size,
                              hipStream_t stream)
{
    const float* x_in = (const float*)d_in[0];
    const int*   inst = (const int*)d_in[1];
    const float* W_[10];
    const float* Bs[10];
    for (int i = 0; i < 10; i++) {
        W_[i] = (const float*)d_in[2 + 2 * i];
        Bs[i] = (const float*)d_in[3 + 2 * i];
    }
    float* out = (float*)d_out;

    float* A  = (float*)d_ws;
    float* Bb = A + (size_t)16777216;
    float* st = Bb + (size_t)8388608;
    const int coff[9] = {0, 128, 384, 896, 1920, 3968, 4992, 5504, 5760};
    float* s_[9];
    for (int i = 0; i < 9; i++) s_[i] = st + coff[i];
    float* segacc = st + 5888;
    float* means  = st + 6016;
    hipMemsetAsync(st, 0, 6016 * sizeof(float), stream);

    // L0: 7x7 reflect, 3->16 @512, OCB=16 PIXB=2
    conv7k<16, 2, true, false><<<dim3(4 * 1 * 512), dim3(256), 3 * 49 * 16 * 4, stream>>>(
        x_in, W_[0], Bs[0], A, s_[0], 3, 16, 512, 512, 9, 1);
    inorm_relu4<<<dim3(16384), dim3(256), 0, stream>>>((float4*)A, s_[0], 16, 1.f / 262144.f, 4194304);

    // L1: 3x3 s2, 16->32 @512->256
    conv3s2k<16, 2><<<dim3(4 * 2 * 128), dim3(256), 16 * 9 * 16 * 4, stream>>>(
        A, W_[1], Bs[1], Bb, s_[1], 16, 32, 512, 512, 256, 256, 8, 16, 2);
    inorm_relu4<<<dim3(8192), dim3(256), 0, stream>>>((float4*)Bb, s_[1], 14, 1.f / 65536.f, 2097152);

    // L2: 32->64 @256->128
    conv3s2k<16, 2><<<dim3(4 * 4 * 32), dim3(256), 32 * 9 * 16 * 4, stream>>>(
        Bb, W_[2], Bs[2], A, s_[2], 32, 64, 256, 256, 128, 128, 7, 32, 4);
    inorm_relu4<<<dim3(4096), dim3(256), 0, stream>>>((float4*)A, s_[2], 12, 1.f / 16384.f, 1048576);

    // L3: 64->128 @128->64
    conv3s2k<16, 2><<<dim3(4 * 8 * 8), dim3(256), 64 * 9 * 16 * 4, stream>>>(
        A, W_[3], Bs[3], Bb, s_[3], 64, 128, 128, 128, 64, 64, 6, 64, 8);
    inorm_relu4<<<dim3(2048), dim3(256), 0, stream>>>((float4*)Bb, s_[3], 10, 1.f / 4096.f, 524288);

    // L4: 128->256 @64->32 (PIXB=1: only 1024 px/img)
    conv3s2k<16, 1><<<dim3(4 * 16 * 4), dim3(256), 64 * 9 * 16 * 4, stream>>>(
        Bb, W_[4], Bs[4], A, s_[4], 128, 256, 64, 64, 32, 32, 5, 64, 16);
    inorm_relu4<<<dim3(1024), dim3(256), 0, stream>>>((float4*)A, s_[4], 8, 1.f / 1024.f, 262144);

    // L5: deconv 256->128 @32->64
    deconvk<16, 1><<<dim3(4 * 8 * 4 * 4), dim3(256), 64 * 4 * 16 * 4, stream>>>(
        A, W_[5], Bs[5], Bb, s_[5], 256, 128, 32, 32, 5, 64, 8);
    inorm_relu4<<<dim3(2048), dim3(256), 0, stream>>>((float4*)Bb, s_[5], 10, 1.f / 4096.f, 524288);

    // L6: deconv 128->64 @64->128
    deconvk<16, 2><<<dim3(4 * 4 * 4 * 8), dim3(256), 64 * 4 * 16 * 4, stream>>>(
        Bb, W_[6], Bs[6], A, s_[6], 128, 64, 64, 64, 6, 64, 4);
    inorm_relu4<<<dim3(4096), dim3(256), 0, stream>>>((float4*)A, s_[6], 12, 1.f / 16384.f, 1048576);

    // L7: deconv 64->32 @128->256
    deconvk<16, 2><<<dim3(4 * 2 * 4 * 32), dim3(256), 64 * 4 * 16 * 4, stream>>>(
        A, W_[7], Bs[7], Bb, s_[7], 64, 32, 128, 128, 7, 64, 2);
    inorm_relu4<<<dim3(8192), dim3(256), 0, stream>>>((float4*)Bb, s_[7], 14, 1.f / 65536.f, 2097152);

    // L8: deconv 32->16 @256->512
    deconvk<16, 2><<<dim3(4 * 1 * 4 * 128), dim3(256), 32 * 4 * 16 * 4, stream>>>(
        Bb, W_[8], Bs[8], A, s_[8], 32, 16, 256, 256, 8, 32, 1);
    inorm_relu4<<<dim3(16384), dim3(256), 0, stream>>>((float4*)A, s_[8], 16, 1.f / 262144.f, 4194304);

    // L9: 7x7 reflect + tanh, 16->3 @512, OCB=4 (padded)
    conv7k<4, 2, false, true><<<dim3(4 * 1 * 512), dim3(256), 16 * 49 * 4 * 4, stream>>>(
        A, W_[9], Bs[9], Bb, nullptr, 16, 3, 512, 512, 9, 1);

    seg_accum<<<dim3(4096), dim3(256), 0, stream>>>(Bb, inst, segacc);
    seg_final<<<dim3(1), dim3(96), 0, stream>>>(segacc, means);
    seg_scatter<<<dim3(4096), dim3(256), 0, stream>>>(inst, means, out);
}

// Round 3
// 1920.130 us; speedup vs baseline: 3.3507x; 1.0106x over previous
//
#include <hip/hip_runtime.h>
#include <math.h>

#define EPS_F 1e-5f

__device__ __forceinline__ int reflect512(int v) {
    v = v < 0 ? -v : v;
    return v >= 512 ? 1022 - v : v;
}

// ---------------------------------------------------------------------------
// Generic per-block (sum, sumsq) reduction over acc[NPX][OCB] -> atomics.
// ---------------------------------------------------------------------------
template<int OCB, int NPX>
__device__ __forceinline__ void stats_reduce_g(
    float (&a)[NPX][OCB], float* __restrict__ stats, int cbase)
{
    __shared__ float red[4][OCB][2];
    int lane = threadIdx.x & 63, wv = threadIdx.x >> 6;
    #pragma unroll
    for (int oc = 0; oc < OCB; oc++) {
        float s = 0.f, s2 = 0.f;
        #pragma unroll
        for (int u = 0; u < NPX; u++) { float v = a[u][oc]; s += v; s2 = fmaf(v, v, s2); }
        #pragma unroll
        for (int off = 32; off; off >>= 1) {
            s  += __shfl_down(s,  off, 64);
            s2 += __shfl_down(s2, off, 64);
        }
        if (lane == 0) { red[wv][oc][0] = s; red[wv][oc][1] = s2; }
    }
    __syncthreads();
    if ((int)threadIdx.x < OCB) {
        float s = 0.f, s2 = 0.f;
        #pragma unroll
        for (int w = 0; w < 4; w++) { s += red[w][threadIdx.x][0]; s2 += red[w][threadIdx.x][1]; }
        atomicAdd(&stats[2 * (cbase + threadIdx.x)],     s);
        atomicAdd(&stats[2 * (cbase + threadIdx.x) + 1], s2);
    }
}

// ---------------------------------------------------------------------------
// 7x7 stride-1 reflect-pad-3 conv @512x512, LDS-staged input, scalar weights.
// Tile 64 x (4*PIXB). Optional fused input-norm, stats, tanh, seg-accumulate.
// ---------------------------------------------------------------------------
template<int CIN, int COUT, int OCB, int PIXB, int CICH,
         bool NORM, bool STATS, bool SEG, bool TANHA>
__global__ __launch_bounds__(256) void conv7t(
    const float* __restrict__ in, const float* __restrict__ wgt,
    const float* __restrict__ bias, float* __restrict__ out,
    const float* __restrict__ stats_in, float invHWin,
    float* __restrict__ stats_out,
    const int* __restrict__ inst, float* __restrict__ segacc)
{
    constexpr int H = 512, W = 512, HW = H * W;
    constexpr int TH = 4 * PIXB, ROWS = TH + 6, LDSW = 72, LCOLS = 70;
    constexpr int TX = W / 64, TY = H / TH, NG = COUT / OCB;
    constexpr int SLOTS = CICH * ROWS * LCOLS;

    extern __shared__ float lds[];
    __shared__ float mr[CICH][2];
    __shared__ float segl[SEG ? 128 : 1];

    const int tid = threadIdx.x;
    const int lx = tid & 63, wv = tid >> 6;
    int bi = blockIdx.x;
    const int tx = bi % TX; bi /= TX;
    const int ty = bi % TY; bi /= TY;
    const int g  = bi % NG;
    const int b  = bi / NG;

    if constexpr (SEG) { if (tid < 128) segl[tid] = 0.f; }

    float acc[PIXB][OCB];
    #pragma unroll
    for (int oc = 0; oc < OCB; oc++) {
        float bv = bias[g * OCB + oc];
        #pragma unroll
        for (int u = 0; u < PIXB; u++) acc[u][oc] = bv;
    }

    const float* inb = in + (size_t)b * CIN * HW;
    for (int ci0 = 0; ci0 < CIN; ci0 += CICH) {
        if constexpr (NORM) {
            if (tid < CICH) {
                int c = b * CIN + ci0 + tid;
                float s = stats_in[2 * c], s2 = stats_in[2 * c + 1];
                float m = s * invHWin;
                mr[tid][0] = m;
                mr[tid][1] = rsqrtf(fmaf(s2, invHWin, -m * m) + EPS_F);
            }
        }
        __syncthreads();
        for (int e = tid; e < SLOTS; e += 256) {
            int cc = e / (ROWS * LCOLS);
            int rm = e - cc * (ROWS * LCOLS);
            int r  = rm / LCOLS;
            int c  = rm - r * LCOLS;
            int gy = reflect512(ty * TH - 3 + r);
            int gx = reflect512(tx * 64 - 3 + c);
            float x = inb[(size_t)(ci0 + cc) * HW + gy * W + gx];
            if constexpr (NORM) x = fmaxf((x - mr[cc][0]) * mr[cc][1], 0.f);
            lds[cc * (ROWS * LDSW) + r * LDSW + c] = x;
        }
        __syncthreads();
        for (int cc = 0; cc < CICH; cc++) {
            const float* tile = lds + cc * (ROWS * LDSW);
            const float* wp = wgt + ((size_t)(g * OCB) * CIN + ci0 + cc) * 49;
            #pragma unroll
            for (int r = 0; r < PIXB + 6; r++) {
                float v[7];
                #pragma unroll
                for (int k = 0; k < 7; k++)
                    v[k] = tile[(wv * PIXB + r) * LDSW + lx + k];
                #pragma unroll
                for (int ky = 0; ky < 7; ky++) {
                    const int u = r - ky;
                    if (u < 0 || u >= PIXB) continue;
                    #pragma unroll
                    for (int kx = 0; kx < 7; kx++) {
                        #pragma unroll
                        for (int oc = 0; oc < OCB; oc++)
                            acc[u][oc] = fmaf(v[kx],
                                wp[(size_t)oc * (CIN * 49) + ky * 7 + kx], acc[u][oc]);
                    }
                }
            }
        }
    }

    const int rowb = ty * TH + wv * PIXB;
    const int colx = tx * 64 + lx;
    if constexpr (SEG) {
        #pragma unroll
        for (int u = 0; u < PIXB; u++) {
            int lab = inst[(size_t)b * HW + (rowb + u) * W + colx] & 31;
            float t0 = TANHA ? tanhf(acc[u][0]) : acc[u][0];
            float t1 = TANHA ? tanhf(acc[u][1]) : acc[u][1];
            float t2 = TANHA ? tanhf(acc[u][2]) : acc[u][2];
            atomicAdd(&segl[lab * 4 + 0], t0);
            atomicAdd(&segl[lab * 4 + 1], t1);
            atomicAdd(&segl[lab * 4 + 2], t2);
            atomicAdd(&segl[lab * 4 + 3], 1.f);
        }
        __syncthreads();
        if (tid < 128) {
            float v = segl[tid];
            if (v != 0.f) atomicAdd(&segacc[tid], v);
        }
    } else {
        #pragma unroll
        for (int oc = 0; oc < OCB; oc++) {
            float* op = out + (size_t)(b * COUT + g * OCB + oc) * HW;
            #pragma unroll
            for (int u = 0; u < PIXB; u++) {
                float vv = acc[u][oc];
                op[(rowb + u) * W + colx] = TANHA ? tanhf(vv) : vv;
            }
        }
    }
    if constexpr (STATS) stats_reduce_g<OCB, PIXB>(acc, stats_out, b * COUT + g * OCB);
}

// ---------------------------------------------------------------------------
// 3x3 stride-2 zero-pad-1 conv, LDS-staged, fused input-norm + stats.
// Out tile TWO x ((256/TWO)*PIXB).
// ---------------------------------------------------------------------------
template<int CIN, int COUT, int OCB, int TWO, int PIXB, int WIN, int CICH>
__global__ __launch_bounds__(256) void conv3s2t(
    const float* __restrict__ in, const float* __restrict__ wgt,
    const float* __restrict__ bias, float* __restrict__ out,
    const float* __restrict__ stats_in, float invHWin,
    float* __restrict__ stats_out)
{
    constexpr int HIN = WIN, HWIN = WIN * WIN;
    constexpr int WOUT = WIN / 2, HWOUT = WOUT * WOUT;
    constexpr int RG = 256 / TWO, THO = RG * PIXB;
    constexpr int LROWS = 2 * THO + 1, LCOLS = 2 * TWO + 1, LDSW = 2 * TWO + 4;
    constexpr int TX = WOUT / TWO, TY = WOUT / THO, NG = COUT / OCB;
    constexpr int SLOTS = CICH * LROWS * LCOLS;

    extern __shared__ float lds[];
    __shared__ float mr[CICH][2];

    const int tid = threadIdx.x;
    const int lx = tid & (TWO - 1), rg = tid / TWO;
    int bi = blockIdx.x;
    const int tx = bi % TX; bi /= TX;
    const int ty = bi % TY; bi /= TY;
    const int g  = bi % NG;
    const int b  = bi / NG;

    float acc[PIXB][OCB];
    #pragma unroll
    for (int oc = 0; oc < OCB; oc++) {
        float bv = bias[g * OCB + oc];
        #pragma unroll
        for (int u = 0; u < PIXB; u++) acc[u][oc] = bv;
    }

    const float* inb = in + (size_t)b * CIN * HWIN;
    for (int ci0 = 0; ci0 < CIN; ci0 += CICH) {
        if (tid < CICH) {
            int c = b * CIN + ci0 + tid;
            float s = stats_in[2 * c], s2 = stats_in[2 * c + 1];
            float m = s * invHWin;
            mr[tid][0] = m;
            mr[tid][1] = rsqrtf(fmaf(s2, invHWin, -m * m) + EPS_F);
        }
        __syncthreads();
        for (int e = tid; e < SLOTS; e += 256) {
            int cc = e / (LROWS * LCOLS);
            int rm = e - cc * (LROWS * LCOLS);
            int r  = rm / LCOLS;
            int c  = rm - r * LCOLS;
            int gy = 2 * (ty * THO) - 1 + r;
            int gx = 2 * (tx * TWO) - 1 + c;
            float x = 0.f;
            if ((unsigned)gy < (unsigned)HIN && (unsigned)gx < (unsigned)WIN) {
                x = inb[(size_t)(ci0 + cc) * HWIN + gy * WIN + gx];
                x = fmaxf((x - mr[cc][0]) * mr[cc][1], 0.f);
            }
            lds[cc * (LROWS * LDSW) + r * LDSW + c] = x;
        }
        __syncthreads();
        for (int cc = 0; cc < CICH; cc++) {
            const float* tile = lds + cc * (LROWS * LDSW);
            const float* wb = wgt + ((size_t)(g * OCB) * CIN + ci0 + cc) * 9;
            #pragma unroll
            for (int u = 0; u < PIXB; u++) {
                const int lr = 2 * (rg * PIXB + u);
                #pragma unroll
                for (int ky = 0; ky < 3; ky++) {
                    #pragma unroll
                    for (int kx = 0; kx < 3; kx++) {
                        float v = tile[(lr + ky) * LDSW + 2 * lx + kx];
                        #pragma unroll
                        for (int oc = 0; oc < OCB; oc++)
                            acc[u][oc] = fmaf(v,
                                wb[(size_t)oc * (CIN * 9) + ky * 3 + kx], acc[u][oc]);
                    }
                }
            }
        }
    }

    #pragma unroll
    for (int oc = 0; oc < OCB; oc++) {
        float* op = out + (size_t)(b * COUT + g * OCB + oc) * HWOUT;
        #pragma unroll
        for (int u = 0; u < PIXB; u++)
            op[(ty * THO + rg * PIXB + u) * WOUT + tx * TWO + lx] = acc[u][oc];
    }
    stats_reduce_g<OCB, PIXB>(acc, stats_out, b * COUT + g * OCB);
}

// ---------------------------------------------------------------------------
// ConvTranspose2d k=3 s=2 p=1 op=1, weight (Cin,Cout,3,3). Each thread owns
// one input pixel -> 2x2 output quad, gathered from 4 LDS values (9 taps).
// Fused input-norm + stats.
// ---------------------------------------------------------------------------
template<int CIN, int COUT, int OCB, int TWI, int WIN, int CICH>
__global__ __launch_bounds__(256) void deconvt(
    const float* __restrict__ in, const float* __restrict__ wgt,
    const float* __restrict__ bias, float* __restrict__ out,
    const float* __restrict__ stats_in, float invHWin,
    float* __restrict__ stats_out)
{
    constexpr int HIN = WIN, HWIN = WIN * WIN;
    constexpr int WOUT = 2 * WIN, HWOUT = 4 * HWIN;
    constexpr int THI = 256 / TWI;
    constexpr int LROWS = THI + 1, LCOLS = TWI + 1, LDSW = TWI + 4;
    constexpr int TX = WIN / TWI, TY = WIN / THI, NG = COUT / OCB;
    constexpr int SLOTS = CICH * LROWS * LCOLS;

    extern __shared__ float lds[];
    __shared__ float mr[CICH][2];

    const int tid = threadIdx.x;
    const int lx = tid & (TWI - 1), ly = tid / TWI;
    int bi = blockIdx.x;
    const int tx = bi % TX; bi /= TX;
    const int ty = bi % TY; bi /= TY;
    const int g  = bi % NG;
    const int b  = bi / NG;

    float acc[4][OCB];   // [00, 01, 10, 11]
    #pragma unroll
    for (int oc = 0; oc < OCB; oc++) {
        float bv = bias[g * OCB + oc];
        #pragma unroll
        for (int u = 0; u < 4; u++) acc[u][oc] = bv;
    }

    const float* inb = in + (size_t)b * CIN * HWIN;
    for (int ci0 = 0; ci0 < CIN; ci0 += CICH) {
        if (tid < CICH) {
            int c = b * CIN + ci0 + tid;
            float s = stats_in[2 * c], s2 = stats_in[2 * c + 1];
            float m = s * invHWin;
            mr[tid][0] = m;
            mr[tid][1] = rsqrtf(fmaf(s2, invHWin, -m * m) + EPS_F);
        }
        __syncthreads();
        for (int e = tid; e < SLOTS; e += 256) {
            int cc = e / (LROWS * LCOLS);
            int rm = e - cc * (LROWS * LCOLS);
            int r  = rm / LCOLS;
            int c  = rm - r * LCOLS;
            int gy = ty * THI + r;
            int gx = tx * TWI + c;
            float x = 0.f;
            if (gy < HIN && gx < WIN) {
                x = inb[(size_t)(ci0 + cc) * HWIN + gy * WIN + gx];
                x = fmaxf((x - mr[cc][0]) * mr[cc][1], 0.f);
            }
            lds[cc * (LROWS * LDSW) + r * LDSW + c] = x;
        }
        __syncthreads();
        for (int cc = 0; cc < CICH; cc++) {
            const float* base = lds + cc * (LROWS * LDSW) + ly * LDSW + lx;
            float v00 = base[0], v01 = base[1];
            float v10 = base[LDSW], v11 = base[LDSW + 1];
            const float* wb = wgt + ((size_t)(ci0 + cc) * COUT + g * OCB) * 9;
            #pragma unroll
            for (int oc = 0; oc < OCB; oc++) {
                const float* w = wb + oc * 9;
                acc[0][oc] = fmaf(w[4], v00, acc[0][oc]);
                acc[1][oc] = fmaf(w[3], v01, fmaf(w[5], v00, acc[1][oc]));
                acc[2][oc] = fmaf(w[1], v10, fmaf(w[7], v00, acc[2][oc]));
                acc[3][oc] = fmaf(w[0], v11,
                             fmaf(w[2], v10,
                             fmaf(w[6], v01,
                             fmaf(w[8], v00, acc[3][oc]))));
            }
        }
    }

    const int Y0 = 2 * (ty * THI + ly), X0 = 2 * (tx * TWI + lx);
    #pragma unroll
    for (int oc = 0; oc < OCB; oc++) {
        float* op = out + (size_t)(b * COUT + g * OCB + oc) * HWOUT;
        op[(size_t)Y0 * WOUT + X0]           = acc[0][oc];
        op[(size_t)Y0 * WOUT + X0 + 1]       = acc[1][oc];
        op[(size_t)(Y0 + 1) * WOUT + X0]     = acc[2][oc];
        op[(size_t)(Y0 + 1) * WOUT + X0 + 1] = acc[3][oc];
    }
    stats_reduce_g<OCB, 4>(acc, stats_out, b * COUT + g * OCB);
}

// ---------------------------------------------------------------------------
// Segment finalize + scatter.
// ---------------------------------------------------------------------------
#define HW9 262144
__global__ void seg_final(const float* __restrict__ acc, float* __restrict__ means)
{
    int i = threadIdx.x;
    if (i < 96) {
        int s = i / 3, c = i - s * 3;
        means[i] = acc[s * 4 + c] / fmaxf(acc[s * 4 + 3], 1.f);
    }
}

__global__ __launch_bounds__(256) void seg_scatter(
    const int* __restrict__ inst, const float* __restrict__ means,
    float* __restrict__ out)
{
    int p   = blockIdx.x * 256 + threadIdx.x;
    int b   = p >> 18;
    int r   = p & (HW9 - 1);
    int lab = inst[p] & 31;
    float* ob = out + (size_t)b * 3 * HW9;
    ob[r]           = means[lab * 3 + 0];
    ob[HW9 + r]     = means[lab * 3 + 1];
    ob[2 * HW9 + r] = means[lab * 3 + 2];
}

// ---------------------------------------------------------------------------
// Launch
// ---------------------------------------------------------------------------
extern "C" void kernel_launch(void* const* d_in, const int* in_sizes, int n_in,
                              void* d_out, int out_size, void* d_ws, size_t ws_size,
                              hipStream_t stream)
{
    const float* x_in = (const float*)d_in[0];
    const int*   inst = (const int*)d_in[1];
    const float* W_[10];
    const float* Bs[10];
    for (int i = 0; i < 10; i++) {
        W_[i] = (const float*)d_in[2 + 2 * i];
        Bs[i] = (const float*)d_in[3 + 2 * i];
    }
    float* out = (float*)d_out;

    float* A  = (float*)d_ws;
    float* Bb = A + (size_t)16777216;
    float* st = Bb + (size_t)8388608;
    const int coff[9] = {0, 128, 384, 896, 1920, 3968, 4992, 5504, 5760};
    float* s_[9];
    for (int i = 0; i < 9; i++) s_[i] = st + coff[i];
    float* segacc = st + 5888;
    float* means  = st + 6016;
    hipMemsetAsync(st, 0, 6016 * sizeof(float), stream);

    // L0: 7x7 reflect 3->16 @512. Tile 64x8, OCB=16.
    conv7t<3, 16, 16, 2, 3, false, true, false, false>
        <<<dim3(8 * 64 * 1 * 4), dim3(256), 3 * 14 * 72 * 4, stream>>>(
        x_in, W_[0], Bs[0], A, nullptr, 0.f, s_[0], nullptr, nullptr);

    // L1: 3x3 s2 16->32 @512->256. Tile 64x8 out.
    conv3s2t<16, 32, 16, 64, 2, 512, 4>
        <<<dim3(4 * 32 * 2 * 4), dim3(256), 4 * 17 * 132 * 4, stream>>>(
        A, W_[1], Bs[1], Bb, s_[0], 1.f / 262144.f, s_[1]);

    // L2: 32->64 @256->128
    conv3s2t<32, 64, 16, 64, 2, 256, 4>
        <<<dim3(2 * 16 * 4 * 4), dim3(256), 4 * 17 * 132 * 4, stream>>>(
        Bb, W_[2], Bs[2], A, s_[1], 1.f / 65536.f, s_[2]);

    // L3: 64->128 @128->64
    conv3s2t<64, 128, 16, 64, 2, 128, 4>
        <<<dim3(1 * 8 * 8 * 4), dim3(256), 4 * 17 * 132 * 4, stream>>>(
        A, W_[3], Bs[3], Bb, s_[2], 1.f / 16384.f, s_[3]);

    // L4: 128->256 @64->32. Tile 32x8 out.
    conv3s2t<128, 256, 16, 32, 1, 64, 8>
        <<<dim3(1 * 4 * 16 * 4), dim3(256), 8 * 17 * 68 * 4, stream>>>(
        Bb, W_[4], Bs[4], A, s_[3], 1.f / 4096.f, s_[4]);

    // L5: deconv 256->128 @32->64. In-tile 32x8.
    deconvt<256, 128, 8, 32, 32, 16>
        <<<dim3(1 * 4 * 16 * 4), dim3(256), 16 * 9 * 36 * 4, stream>>>(
        A, W_[5], Bs[5], Bb, s_[4], 1.f / 1024.f, s_[5]);

    // L6: deconv 128->64 @64->128. In-tile 64x4.
    deconvt<128, 64, 16, 64, 64, 16>
        <<<dim3(1 * 16 * 4 * 4), dim3(256), 16 * 5 * 68 * 4, stream>>>(
        Bb, W_[6], Bs[6], A, s_[5], 1.f / 4096.f, s_[6]);

    // L7: deconv 64->32 @128->256
    deconvt<64, 32, 16, 64, 128, 16>
        <<<dim3(2 * 32 * 2 * 4), dim3(256), 16 * 5 * 68 * 4, stream>>>(
        A, W_[7], Bs[7], Bb, s_[6], 1.f / 16384.f, s_[7]);

    // L8: deconv 32->16 @256->512
    deconvt<32, 16, 16, 64, 256, 16>
        <<<dim3(4 * 64 * 1 * 4), dim3(256), 16 * 5 * 68 * 4, stream>>>(
        Bb, W_[8], Bs[8], A, s_[7], 1.f / 65536.f, s_[8]);

    // L9: 7x7 reflect 16->3 @512 + tanh + fused segment accumulate.
    // Tile 64x16, OCB=3. Output never materialized.
    conv7t<16, 3, 3, 4, 4, true, false, true, true>
        <<<dim3(8 * 32 * 1 * 4), dim3(256), 4 * 22 * 72 * 4, stream>>>(
        A, W_[9], Bs[9], Bb, s_[8], 1.f / 262144.f, nullptr, inst, segacc);

    seg_final<<<dim3(1), dim3(96), 0, stream>>>(segacc, means);
    seg_scatter<<<dim3(4096), dim3(256), 0, stream>>>(inst, means, out);
}

// Round 5
// 1748.787 us; speedup vs baseline: 3.6789x; 1.0980x over previous
//
#include <hip/hip_runtime.h>
#include <math.h>

#define EPS_F 1e-5f

__device__ __forceinline__ int reflect512(int v) {
    v = v < 0 ? -v : v;
    return v >= 512 ? 1022 - v : v;
}

__device__ __forceinline__ float fsel(const float4& v, int c) {
    return c == 0 ? v.x : c == 1 ? v.y : c == 2 ? v.z : v.w;
}

// ---------------------------------------------------------------------------
// Per-block (sum, sumsq) reduction over float4 acc[NPX][OCB/4] -> atomics.
// ---------------------------------------------------------------------------
template<int OCB, int NPX>
__device__ __forceinline__ void stats_reduce4(
    float4 (&a)[NPX][OCB / 4], float* __restrict__ stats, int cbase)
{
    __shared__ float red[4][OCB][2];
    int lane = threadIdx.x & 63, wv = threadIdx.x >> 6;
    #pragma unroll
    for (int oc = 0; oc < OCB; oc++) {
        float s = 0.f, s2 = 0.f;
        #pragma unroll
        for (int u = 0; u < NPX; u++) {
            float v = fsel(a[u][oc >> 2], oc & 3);
            s += v; s2 = fmaf(v, v, s2);
        }
        #pragma unroll
        for (int off = 32; off; off >>= 1) {
            s  += __shfl_down(s,  off, 64);
            s2 += __shfl_down(s2, off, 64);
        }
        if (lane == 0) { red[wv][oc][0] = s; red[wv][oc][1] = s2; }
    }
    __syncthreads();
    if ((int)threadIdx.x < OCB) {
        float s = 0.f, s2 = 0.f;
        #pragma unroll
        for (int w = 0; w < 4; w++) { s += red[w][threadIdx.x][0]; s2 += red[w][threadIdx.x][1]; }
        atomicAdd(&stats[2 * (cbase + threadIdx.x)],     s);
        atomicAdd(&stats[2 * (cbase + threadIdx.x) + 1], s2);
    }
}

// ---------------------------------------------------------------------------
// 7x7 stride-1 reflect-pad-3 conv @512x512. Input tile + ALL weights in LDS.
// Weights layout [ci][k][OCB] -> float4 wave-uniform broadcast reads.
// NG is ceil(COUT/OCB); padded oc slots are guarded on load/store.
// ---------------------------------------------------------------------------
template<int CIN, int COUT, int OCB, int PIXB, int CICH,
         bool NORM, bool STATS, bool SEG, bool TANHA>
__global__ __launch_bounds__(256) void conv7t(
    const float* __restrict__ in, const float* __restrict__ wgt,
    const float* __restrict__ bias, float* __restrict__ out,
    const float* __restrict__ stats_in, float invHWin,
    float* __restrict__ stats_out,
    const int* __restrict__ inst, float* __restrict__ segacc)
{
    constexpr int H = 512, W = 512, HW = H * W;
    constexpr int TH = 4 * PIXB, ROWS = TH + 6, LDSW = 72, LCOLS = 70;
    constexpr int TX = W / 64, TY = H / TH;
    constexpr int NG = (COUT + OCB - 1) / OCB;     // ceil-div (L9: 3/4 -> 1)
    constexpr int ISLOTS = CICH * ROWS * LCOLS;
    constexpr int NWT = CIN * 49 * OCB;

    extern __shared__ float lds[];
    float* wl = lds + CICH * ROWS * LDSW;          // weights after input tile
    __shared__ float mr[CICH][2];
    __shared__ float segl[SEG ? 128 : 1];

    const int tid = threadIdx.x;
    const int lx = tid & 63, wv = tid >> 6;
    int bi = blockIdx.x;
    const int tx = bi % TX; bi /= TX;
    const int ty = bi % TY; bi /= TY;
    const int g  = bi % NG;
    const int b  = bi / NG;

    if constexpr (SEG) { if (tid < 128) segl[tid] = 0.f; }

    // Stage ALL weights for this oc-group once.
    for (int e = tid; e < NWT; e += 256) {
        int oc = e & (OCB - 1);
        int k  = (e / OCB) % 49;
        int ci = e / (OCB * 49);
        int ocg = g * OCB + oc;
        wl[e] = (ocg < COUT) ? wgt[((size_t)ocg * CIN + ci) * 49 + k] : 0.f;
    }

    float4 acc[PIXB][OCB / 4];
    #pragma unroll
    for (int q = 0; q < OCB / 4; q++) {
        int o = g * OCB + q * 4;
        float4 bq;
        bq.x = (o + 0 < COUT) ? bias[o + 0] : 0.f;
        bq.y = (o + 1 < COUT) ? bias[o + 1] : 0.f;
        bq.z = (o + 2 < COUT) ? bias[o + 2] : 0.f;
        bq.w = (o + 3 < COUT) ? bias[o + 3] : 0.f;
        #pragma unroll
        for (int u = 0; u < PIXB; u++) acc[u][q] = bq;
    }

    const float* inb = in + (size_t)b * CIN * HW;
    for (int ci0 = 0; ci0 < CIN; ci0 += CICH) {
        if constexpr (NORM) {
            if (tid < CICH) {
                int c = b * CIN + ci0 + tid;
                float s = stats_in[2 * c], s2 = stats_in[2 * c + 1];
                float m = s * invHWin;
                mr[tid][0] = m;
                mr[tid][1] = rsqrtf(fmaf(s2, invHWin, -m * m) + EPS_F);
            }
        }
        __syncthreads();
        for (int e = tid; e < ISLOTS; e += 256) {
            int cc = e / (ROWS * LCOLS);
            int rm = e - cc * (ROWS * LCOLS);
            int r  = rm / LCOLS;
            int c  = rm - r * LCOLS;
            int gy = reflect512(ty * TH - 3 + r);
            int gx = reflect512(tx * 64 - 3 + c);
            float x = inb[(size_t)(ci0 + cc) * HW + gy * W + gx];
            if constexpr (NORM) x = fmaxf((x - mr[cc][0]) * mr[cc][1], 0.f);
            lds[cc * (ROWS * LDSW) + r * LDSW + c] = x;
        }
        __syncthreads();
        for (int cc = 0; cc < CICH; cc++) {
            const float* tile = lds + cc * (ROWS * LDSW);
            const float4* wq = (const float4*)wl + (size_t)(ci0 + cc) * 49 * (OCB / 4);
            #pragma unroll
            for (int r = 0; r < PIXB + 6; r++) {
                float v[7];
                #pragma unroll
                for (int k = 0; k < 7; k++)
                    v[k] = tile[(wv * PIXB + r) * LDSW + lx + k];
                #pragma unroll
                for (int ky = 0; ky < 7; ky++) {
                    const int u = r - ky;
                    if (u < 0 || u >= PIXB) continue;
                    #pragma unroll
                    for (int kx = 0; kx < 7; kx++) {
                        #pragma unroll
                        for (int q = 0; q < OCB / 4; q++) {
                            float4 w = wq[(ky * 7 + kx) * (OCB / 4) + q];
                            acc[u][q].x = fmaf(v[kx], w.x, acc[u][q].x);
                            acc[u][q].y = fmaf(v[kx], w.y, acc[u][q].y);
                            acc[u][q].z = fmaf(v[kx], w.z, acc[u][q].z);
                            acc[u][q].w = fmaf(v[kx], w.w, acc[u][q].w);
                        }
                    }
                }
            }
        }
        __syncthreads();
    }

    const int rowb = ty * TH + wv * PIXB;
    const int colx = tx * 64 + lx;
    if constexpr (SEG) {
        #pragma unroll
        for (int u = 0; u < PIXB; u++) {
            int lab = inst[(size_t)b * HW + (rowb + u) * W + colx] & 31;
            float t0 = TANHA ? tanhf(acc[u][0].x) : acc[u][0].x;
            float t1 = TANHA ? tanhf(acc[u][0].y) : acc[u][0].y;
            float t2 = TANHA ? tanhf(acc[u][0].z) : acc[u][0].z;
            atomicAdd(&segl[lab * 4 + 0], t0);
            atomicAdd(&segl[lab * 4 + 1], t1);
            atomicAdd(&segl[lab * 4 + 2], t2);
            atomicAdd(&segl[lab * 4 + 3], 1.f);
        }
        __syncthreads();
        if (tid < 128) {
            float v = segl[tid];
            if (v != 0.f) atomicAdd(&segacc[tid], v);
        }
    } else {
        #pragma unroll
        for (int q = 0; q < OCB / 4; q++) {
            #pragma unroll
            for (int c = 0; c < 4; c++) {
                int ocg = g * OCB + q * 4 + c;
                if (ocg < COUT) {
                    float* op = out + (size_t)(b * COUT + ocg) * HW;
                    #pragma unroll
                    for (int u = 0; u < PIXB; u++) {
                        float vv = fsel(acc[u][q], c);
                        op[(rowb + u) * W + colx] = TANHA ? tanhf(vv) : vv;
                    }
                }
            }
        }
    }
    if constexpr (STATS) stats_reduce4<OCB, PIXB>(acc, stats_out, b * COUT + g * OCB);
}

// ---------------------------------------------------------------------------
// 3x3 stride-2 zero-pad-1 conv. Input tile + per-chunk weights in LDS.
// ---------------------------------------------------------------------------
template<int CIN, int COUT, int OCB, int TWO, int PIXB, int WIN, int CICH>
__global__ __launch_bounds__(256) void conv3s2t(
    const float* __restrict__ in, const float* __restrict__ wgt,
    const float* __restrict__ bias, float* __restrict__ out,
    const float* __restrict__ stats_in, float invHWin,
    float* __restrict__ stats_out)
{
    constexpr int HIN = WIN, HWIN = WIN * WIN;
    constexpr int WOUT = WIN / 2, HWOUT = WOUT * WOUT;
    constexpr int RG = 256 / TWO, THO = RG * PIXB;
    constexpr int LROWS = 2 * THO + 1, LCOLS = 2 * TWO + 1, LDSW = 2 * TWO + 4;
    constexpr int TX = WOUT / TWO, TY = WOUT / THO, NG = COUT / OCB;
    constexpr int ISLOTS = CICH * LROWS * LCOLS;
    constexpr int WSLOTS = CICH * 9 * OCB;

    extern __shared__ float lds[];
    float* wl = lds + CICH * LROWS * LDSW;
    __shared__ float mr[CICH][2];

    const int tid = threadIdx.x;
    const int lx = tid & (TWO - 1), rg = tid / TWO;
    int bi = blockIdx.x;
    const int tx = bi % TX; bi /= TX;
    const int ty = bi % TY; bi /= TY;
    const int g  = bi % NG;
    const int b  = bi / NG;

    float4 acc[PIXB][OCB / 4];
    #pragma unroll
    for (int q = 0; q < OCB / 4; q++) {
        int o = g * OCB + q * 4;
        float4 bq = { bias[o], bias[o + 1], bias[o + 2], bias[o + 3] };
        #pragma unroll
        for (int u = 0; u < PIXB; u++) acc[u][q] = bq;
    }

    const float* inb = in + (size_t)b * CIN * HWIN;
    for (int ci0 = 0; ci0 < CIN; ci0 += CICH) {
        if (tid < CICH) {
            int c = b * CIN + ci0 + tid;
            float s = stats_in[2 * c], s2 = stats_in[2 * c + 1];
            float m = s * invHWin;
            mr[tid][0] = m;
            mr[tid][1] = rsqrtf(fmaf(s2, invHWin, -m * m) + EPS_F);
        }
        __syncthreads();
        for (int e = tid; e < ISLOTS; e += 256) {
            int cc = e / (LROWS * LCOLS);
            int rm = e - cc * (LROWS * LCOLS);
            int r  = rm / LCOLS;
            int c  = rm - r * LCOLS;
            int gy = 2 * (ty * THO) - 1 + r;
            int gx = 2 * (tx * TWO) - 1 + c;
            float x = 0.f;
            if ((unsigned)gy < (unsigned)HIN && (unsigned)gx < (unsigned)WIN) {
                x = inb[(size_t)(ci0 + cc) * HWIN + gy * WIN + gx];
                x = fmaxf((x - mr[cc][0]) * mr[cc][1], 0.f);
            }
            lds[cc * (LROWS * LDSW) + r * LDSW + c] = x;
        }
        for (int e = tid; e < WSLOTS; e += 256) {
            int oc = e & (OCB - 1);
            int k  = (e / OCB) % 9;
            int cc = e / (OCB * 9);
            wl[e] = wgt[((size_t)(g * OCB + oc) * CIN + ci0 + cc) * 9 + k];
        }
        __syncthreads();
        for (int cc = 0; cc < CICH; cc++) {
            const float* tile = lds + cc * (LROWS * LDSW);
            const float4* wq = (const float4*)wl + cc * 9 * (OCB / 4);
            #pragma unroll
            for (int u = 0; u < PIXB; u++) {
                const int lr = 2 * (rg * PIXB + u);
                #pragma unroll
                for (int ky = 0; ky < 3; ky++) {
                    #pragma unroll
                    for (int kx = 0; kx < 3; kx++) {
                        float v = tile[(lr + ky) * LDSW + 2 * lx + kx];
                        #pragma unroll
                        for (int q = 0; q < OCB / 4; q++) {
                            float4 w = wq[(ky * 3 + kx) * (OCB / 4) + q];
                            acc[u][q].x = fmaf(v, w.x, acc[u][q].x);
                            acc[u][q].y = fmaf(v, w.y, acc[u][q].y);
                            acc[u][q].z = fmaf(v, w.z, acc[u][q].z);
                            acc[u][q].w = fmaf(v, w.w, acc[u][q].w);
                        }
                    }
                }
            }
        }
        __syncthreads();
    }

    #pragma unroll
    for (int q = 0; q < OCB / 4; q++) {
        #pragma unroll
        for (int c = 0; c < 4; c++) {
            float* op = out + (size_t)(b * COUT + g * OCB + q * 4 + c) * HWOUT;
            #pragma unroll
            for (int u = 0; u < PIXB; u++)
                op[(ty * THO + rg * PIXB + u) * WOUT + tx * TWO + lx] = fsel(acc[u][q], c);
        }
    }
    stats_reduce4<OCB, PIXB>(acc, stats_out, b * COUT + g * OCB);
}

// ---------------------------------------------------------------------------
// ConvTranspose2d k=3 s=2 p=1 op=1, weight (Cin,Cout,3,3). Thread owns one
// input pixel -> 2x2 output quad. Input tile + per-chunk weights in LDS.
// ---------------------------------------------------------------------------
template<int CIN, int COUT, int OCB, int TWI, int WIN, int CICH>
__global__ __launch_bounds__(256) void deconvt(
    const float* __restrict__ in, const float* __restrict__ wgt,
    const float* __restrict__ bias, float* __restrict__ out,
    const float* __restrict__ stats_in, float invHWin,
    float* __restrict__ stats_out)
{
    constexpr int HIN = WIN, HWIN = WIN * WIN;
    constexpr int WOUT = 2 * WIN, HWOUT = 4 * HWIN;
    constexpr int THI = 256 / TWI;
    constexpr int LROWS = THI + 1, LCOLS = TWI + 1, LDSW = TWI + 4;
    constexpr int TX = WIN / TWI, TY = WIN / THI, NG = COUT / OCB;
    constexpr int ISLOTS = CICH * LROWS * LCOLS;
    constexpr int WSLOTS = CICH * 9 * OCB;

    extern __shared__ float lds[];
    float* wl = lds + CICH * LROWS * LDSW;
    __shared__ float mr[CICH][2];

    const int tid = threadIdx.x;
    const int lx = tid & (TWI - 1), ly = tid / TWI;
    int bi = blockIdx.x;
    const int tx = bi % TX; bi /= TX;
    const int ty = bi % TY; bi /= TY;
    const int g  = bi % NG;
    const int b  = bi / NG;

    float4 acc[4][OCB / 4];   // quad order: 00, 01, 10, 11
    #pragma unroll
    for (int q = 0; q < OCB / 4; q++) {
        int o = g * OCB + q * 4;
        float4 bq = { bias[o], bias[o + 1], bias[o + 2], bias[o + 3] };
        #pragma unroll
        for (int u = 0; u < 4; u++) acc[u][q] = bq;
    }

    const float* inb = in + (size_t)b * CIN * HWIN;
    for (int ci0 = 0; ci0 < CIN; ci0 += CICH) {
        if (tid < CICH) {
            int c = b * CIN + ci0 + tid;
            float s = stats_in[2 * c], s2 = stats_in[2 * c + 1];
            float m = s * invHWin;
            mr[tid][0] = m;
            mr[tid][1] = rsqrtf(fmaf(s2, invHWin, -m * m) + EPS_F);
        }
        __syncthreads();
        for (int e = tid; e < ISLOTS; e += 256) {
            int cc = e / (LROWS * LCOLS);
            int rm = e - cc * (LROWS * LCOLS);
            int r  = rm / LCOLS;
            int c  = rm - r * LCOLS;
            int gy = ty * THI + r;
            int gx = tx * TWI + c;
            float x = 0.f;
            if (gy < HIN && gx < WIN) {
                x = inb[(size_t)(ci0 + cc) * HWIN + gy * WIN + gx];
                x = fmaxf((x - mr[cc][0]) * mr[cc][1], 0.f);
            }
            lds[cc * (LROWS * LDSW) + r * LDSW + c] = x;
        }
        for (int e = tid; e < WSLOTS; e += 256) {
            int oc = e & (OCB - 1);
            int k  = (e / OCB) % 9;
            int cc = e / (OCB * 9);
            wl[e] = wgt[((size_t)(ci0 + cc) * COUT + g * OCB + oc) * 9 + k];
        }
        __syncthreads();
        for (int cc = 0; cc < CICH; cc++) {
            const float* base = lds + cc * (LROWS * LDSW) + ly * LDSW + lx;
            float v00 = base[0], v01 = base[1];
            float v10 = base[LDSW], v11 = base[LDSW + 1];
            const float4* wq = (const float4*)wl + cc * 9 * (OCB / 4);
            #pragma unroll
            for (int q = 0; q < OCB / 4; q++) {
                float4 w;
                #define DFMA(u, vv) \
                    acc[u][q].x = fmaf(w.x, vv, acc[u][q].x); \
                    acc[u][q].y = fmaf(w.y, vv, acc[u][q].y); \
                    acc[u][q].z = fmaf(w.z, vv, acc[u][q].z); \
                    acc[u][q].w = fmaf(w.w, vv, acc[u][q].w);
                w = wq[0 * (OCB / 4) + q]; DFMA(3, v11)
                w = wq[1 * (OCB / 4) + q]; DFMA(2, v10)
                w = wq[2 * (OCB / 4) + q]; DFMA(3, v10)
                w = wq[3 * (OCB / 4) + q]; DFMA(1, v01)
                w = wq[4 * (OCB / 4) + q]; DFMA(0, v00)
                w = wq[5 * (OCB / 4) + q]; DFMA(1, v00)
                w = wq[6 * (OCB / 4) + q]; DFMA(3, v01)
                w = wq[7 * (OCB / 4) + q]; DFMA(2, v00)
                w = wq[8 * (OCB / 4) + q]; DFMA(3, v00)
                #undef DFMA
            }
        }
        __syncthreads();
    }

    const int Y0 = 2 * (ty * THI + ly), X0 = 2 * (tx * TWI + lx);
    #pragma unroll
    for (int q = 0; q < OCB / 4; q++) {
        #pragma unroll
        for (int c = 0; c < 4; c++) {
            float* op = out + (size_t)(b * COUT + g * OCB + q * 4 + c) * HWOUT;
            op[(size_t)Y0 * WOUT + X0]           = fsel(acc[0][q], c);
            op[(size_t)Y0 * WOUT + X0 + 1]       = fsel(acc[1][q], c);
            op[(size_t)(Y0 + 1) * WOUT + X0]     = fsel(acc[2][q], c);
            op[(size_t)(Y0 + 1) * WOUT + X0 + 1] = fsel(acc[3][q], c);
        }
    }
    stats_reduce4<OCB, 4>(acc, stats_out, b * COUT + g * OCB);
}

// ---------------------------------------------------------------------------
// Segment finalize + scatter.
// ---------------------------------------------------------------------------
#define HW9 262144
__global__ void seg_final(const float* __restrict__ acc, float* __restrict__ means)
{
    int i = threadIdx.x;
    if (i < 96) {
        int s = i / 3, c = i - s * 3;
        means[i] = acc[s * 4 + c] / fmaxf(acc[s * 4 + 3], 1.f);
    }
}

__global__ __launch_bounds__(256) void seg_scatter(
    const int* __restrict__ inst, const float* __restrict__ means,
    float* __restrict__ out)
{
    int p   = blockIdx.x * 256 + threadIdx.x;
    int b   = p >> 18;
    int r   = p & (HW9 - 1);
    int lab = inst[p] & 31;
    float* ob = out + (size_t)b * 3 * HW9;
    ob[r]           = means[lab * 3 + 0];
    ob[HW9 + r]     = means[lab * 3 + 1];
    ob[2 * HW9 + r] = means[lab * 3 + 2];
}

// ---------------------------------------------------------------------------
// Launch
// ---------------------------------------------------------------------------
extern "C" void kernel_launch(void* const* d_in, const int* in_sizes, int n_in,
                              void* d_out, int out_size, void* d_ws, size_t ws_size,
                              hipStream_t stream)
{
    const float* x_in = (const float*)d_in[0];
    const int*   inst = (const int*)d_in[1];
    const float* W_[10];
    const float* Bs[10];
    for (int i = 0; i < 10; i++) {
        W_[i] = (const float*)d_in[2 + 2 * i];
        Bs[i] = (const float*)d_in[3 + 2 * i];
    }
    float* out = (float*)d_out;

    float* A  = (float*)d_ws;
    float* Bb = A + (size_t)16777216;
    float* st = Bb + (size_t)8388608;
    const int coff[9] = {0, 128, 384, 896, 1920, 3968, 4992, 5504, 5760};
    float* s_[9];
    for (int i = 0; i < 9; i++) s_[i] = st + coff[i];
    float* segacc = st + 5888;
    float* means  = st + 6016;
    hipMemsetAsync(st, 0, 6016 * sizeof(float), stream);

    // L0: 7x7 reflect 3->16 @512. LDS = input 3*14*72 + weights 3*49*16.
    conv7t<3, 16, 16, 2, 3, false, true, false, false>
        <<<dim3(8 * 64 * 1 * 4), dim3(256), (3 * 14 * 72 + 3 * 49 * 16) * 4, stream>>>(
        x_in, W_[0], Bs[0], A, nullptr, 0.f, s_[0], nullptr, nullptr);

    // L1: 3x3 s2 16->32 @512->256.
    conv3s2t<16, 32, 16, 64, 2, 512, 4>
        <<<dim3(4 * 32 * 2 * 4), dim3(256), (4 * 17 * 132 + 4 * 9 * 16) * 4, stream>>>(
        A, W_[1], Bs[1], Bb, s_[0], 1.f / 262144.f, s_[1]);

    // L2: 32->64 @256->128
    conv3s2t<32, 64, 16, 64, 2, 256, 4>
        <<<dim3(2 * 16 * 4 * 4), dim3(256), (4 * 17 * 132 + 4 * 9 * 16) * 4, stream>>>(
        Bb, W_[2], Bs[2], A, s_[1], 1.f / 65536.f, s_[2]);

    // L3: 64->128 @128->64
    conv3s2t<64, 128, 16, 64, 2, 128, 4>
        <<<dim3(1 * 8 * 8 * 4), dim3(256), (4 * 17 * 132 + 4 * 9 * 16) * 4, stream>>>(
        A, W_[3], Bs[3], Bb, s_[2], 1.f / 16384.f, s_[3]);

    // L4: 128->256 @64->32. TWO=32, PIXB=1, CICH=8.
    conv3s2t<128, 256, 16, 32, 1, 64, 8>
        <<<dim3(1 * 4 * 16 * 4), dim3(256), (8 * 17 * 68 + 8 * 9 * 16) * 4, stream>>>(
        Bb, W_[4], Bs[4], A, s_[3], 1.f / 4096.f, s_[4]);

    // L5: deconv 256->128 @32->64. OCB=8 -> 256 blocks.
    deconvt<256, 128, 8, 32, 32, 16>
        <<<dim3(1 * 4 * 16 * 4), dim3(256), (16 * 9 * 36 + 16 * 9 * 8) * 4, stream>>>(
        A, W_[5], Bs[5], Bb, s_[4], 1.f / 1024.f, s_[5]);

    // L6: deconv 128->64 @64->128.
    deconvt<128, 64, 16, 64, 64, 16>
        <<<dim3(1 * 16 * 4 * 4), dim3(256), (16 * 5 * 68 + 16 * 9 * 16) * 4, stream>>>(
        Bb, W_[6], Bs[6], A, s_[5], 1.f / 4096.f, s_[6]);

    // L7: deconv 64->32 @128->256
    deconvt<64, 32, 16, 64, 128, 16>
        <<<dim3(2 * 32 * 2 * 4), dim3(256), (16 * 5 * 68 + 16 * 9 * 16) * 4, stream>>>(
        A, W_[7], Bs[7], Bb, s_[6], 1.f / 16384.f, s_[7]);

    // L8: deconv 32->16 @256->512
    deconvt<32, 16, 16, 64, 256, 16>
        <<<dim3(4 * 64 * 1 * 4), dim3(256), (16 * 5 * 68 + 16 * 9 * 16) * 4, stream>>>(
        Bb, W_[8], Bs[8], A, s_[7], 1.f / 65536.f, s_[8]);

    // L9: 7x7 reflect 16->3 @512 + tanh + fused segment accumulate (OCB=4 padded, NG=1).
    conv7t<16, 3, 4, 4, 4, true, false, true, true>
        <<<dim3(8 * 32 * 1 * 4), dim3(256), (4 * 22 * 72 + 16 * 49 * 4) * 4, stream>>>(
        A, W_[9], Bs[9], Bb, s_[8], 1.f / 262144.f, nullptr, inst, segacc);

    seg_final<<<dim3(1), dim3(96), 0, stream>>>(segacc, means);
    seg_scatter<<<dim3(4096), dim3(256), 0, stream>>>(inst, means, out);
}

// Round 6
// 1633.658 us; speedup vs baseline: 3.9382x; 1.0705x over previous
//
#include <hip/hip_runtime.h>
#include <math.h>

#define EPS_F 1e-5f

__device__ __forceinline__ int reflect512(int v) {
    v = v < 0 ? -v : v;
    return v >= 512 ? 1022 - v : v;
}

__device__ __forceinline__ float fsel(const float4& v, int c) {
    return c == 0 ? v.x : c == 1 ? v.y : c == 2 ? v.z : v.w;
}

// ---------------------------------------------------------------------------
// Per-block (sum, sumsq) reduction over float4 acc[NPX][OCB/4] -> atomics.
// ---------------------------------------------------------------------------
template<int OCB, int NPX>
__device__ __forceinline__ void stats_reduce4(
    float4 (&a)[NPX][OCB / 4], float* __restrict__ stats, int cbase)
{
    __shared__ float red[4][OCB][2];
    int lane = threadIdx.x & 63, wv = threadIdx.x >> 6;
    #pragma unroll
    for (int oc = 0; oc < OCB; oc++) {
        float s = 0.f, s2 = 0.f;
        #pragma unroll
        for (int u = 0; u < NPX; u++) {
            float v = fsel(a[u][oc >> 2], oc & 3);
            s += v; s2 = fmaf(v, v, s2);
        }
        #pragma unroll
        for (int off = 32; off; off >>= 1) {
            s  += __shfl_down(s,  off, 64);
            s2 += __shfl_down(s2, off, 64);
        }
        if (lane == 0) { red[wv][oc][0] = s; red[wv][oc][1] = s2; }
    }
    __syncthreads();
    if ((int)threadIdx.x < OCB) {
        float s = 0.f, s2 = 0.f;
        #pragma unroll
        for (int w = 0; w < 4; w++) { s += red[w][threadIdx.x][0]; s2 += red[w][threadIdx.x][1]; }
        atomicAdd(&stats[2 * (cbase + threadIdx.x)],     s);
        atomicAdd(&stats[2 * (cbase + threadIdx.x) + 1], s2);
    }
}

// ---------------------------------------------------------------------------
// 7x7 stride-1 reflect-pad-3 conv @512x512. Input tile + ALL weights in LDS.
// Weights layout [ci][k][OCB] -> float4 wave-uniform broadcast reads.
// NG is ceil(COUT/OCB); padded oc slots are guarded on load/store.
// ---------------------------------------------------------------------------
template<int CIN, int COUT, int OCB, int PIXB, int CICH,
         bool NORM, bool STATS, bool SEG, bool TANHA>
__global__ __launch_bounds__(256) void conv7t(
    const float* __restrict__ in, const float* __restrict__ wgt,
    const float* __restrict__ bias, float* __restrict__ out,
    const float* __restrict__ stats_in, float invHWin,
    float* __restrict__ stats_out,
    const int* __restrict__ inst, float* __restrict__ segacc)
{
    constexpr int H = 512, W = 512, HW = H * W;
    constexpr int TH = 4 * PIXB, ROWS = TH + 6, LDSW = 72, LCOLS = 70;
    constexpr int TX = W / 64, TY = H / TH;
    constexpr int NG = (COUT + OCB - 1) / OCB;
    constexpr int ISLOTS = CICH * ROWS * LCOLS;
    constexpr int NWT = CIN * 49 * OCB;

    extern __shared__ float lds[];
    float* wl = lds + CICH * ROWS * LDSW;
    __shared__ float mr[CICH][2];
    __shared__ float segl[SEG ? 128 : 1];

    const int tid = threadIdx.x;
    const int lx = tid & 63, wv = tid >> 6;
    int bi = blockIdx.x;
    const int tx = bi % TX; bi /= TX;
    const int ty = bi % TY; bi /= TY;
    const int g  = bi % NG;
    const int b  = bi / NG;

    if constexpr (SEG) { if (tid < 128) segl[tid] = 0.f; }

    for (int e = tid; e < NWT; e += 256) {
        int oc = e & (OCB - 1);
        int k  = (e / OCB) % 49;
        int ci = e / (OCB * 49);
        int ocg = g * OCB + oc;
        wl[e] = (ocg < COUT) ? wgt[((size_t)ocg * CIN + ci) * 49 + k] : 0.f;
    }

    float4 acc[PIXB][OCB / 4];
    #pragma unroll
    for (int q = 0; q < OCB / 4; q++) {
        int o = g * OCB + q * 4;
        float4 bq;
        bq.x = (o + 0 < COUT) ? bias[o + 0] : 0.f;
        bq.y = (o + 1 < COUT) ? bias[o + 1] : 0.f;
        bq.z = (o + 2 < COUT) ? bias[o + 2] : 0.f;
        bq.w = (o + 3 < COUT) ? bias[o + 3] : 0.f;
        #pragma unroll
        for (int u = 0; u < PIXB; u++) acc[u][q] = bq;
    }

    const float* inb = in + (size_t)b * CIN * HW;
    for (int ci0 = 0; ci0 < CIN; ci0 += CICH) {
        if constexpr (NORM) {
            if (tid < CICH) {
                int c = b * CIN + ci0 + tid;
                float s = stats_in[2 * c], s2 = stats_in[2 * c + 1];
                float m = s * invHWin;
                mr[tid][0] = m;
                mr[tid][1] = rsqrtf(fmaf(s2, invHWin, -m * m) + EPS_F);
            }
        }
        __syncthreads();
        for (int e = tid; e < ISLOTS; e += 256) {
            int cc = e / (ROWS * LCOLS);
            int rm = e - cc * (ROWS * LCOLS);
            int r  = rm / LCOLS;
            int c  = rm - r * LCOLS;
            int gy = reflect512(ty * TH - 3 + r);
            int gx = reflect512(tx * 64 - 3 + c);
            float x = inb[(size_t)(ci0 + cc) * HW + gy * W + gx];
            if constexpr (NORM) x = fmaxf((x - mr[cc][0]) * mr[cc][1], 0.f);
            lds[cc * (ROWS * LDSW) + r * LDSW + c] = x;
        }
        __syncthreads();
        for (int cc = 0; cc < CICH; cc++) {
            const float* tile = lds + cc * (ROWS * LDSW);
            const float4* wq = (const float4*)wl + (size_t)(ci0 + cc) * 49 * (OCB / 4);
            #pragma unroll
            for (int r = 0; r < PIXB + 6; r++) {
                float v[7];
                #pragma unroll
                for (int k = 0; k < 7; k++)
                    v[k] = tile[(wv * PIXB + r) * LDSW + lx + k];
                #pragma unroll
                for (int ky = 0; ky < 7; ky++) {
                    const int u = r - ky;
                    if (u < 0 || u >= PIXB) continue;
                    #pragma unroll
                    for (int kx = 0; kx < 7; kx++) {
                        #pragma unroll
                        for (int q = 0; q < OCB / 4; q++) {
                            float4 w = wq[(ky * 7 + kx) * (OCB / 4) + q];
                            acc[u][q].x = fmaf(v[kx], w.x, acc[u][q].x);
                            acc[u][q].y = fmaf(v[kx], w.y, acc[u][q].y);
                            acc[u][q].z = fmaf(v[kx], w.z, acc[u][q].z);
                            acc[u][q].w = fmaf(v[kx], w.w, acc[u][q].w);
                        }
                    }
                }
            }
        }
        __syncthreads();
    }

    const int rowb = ty * TH + wv * PIXB;
    const int colx = tx * 64 + lx;
    if constexpr (SEG) {
        #pragma unroll
        for (int u = 0; u < PIXB; u++) {
            int lab = inst[(size_t)b * HW + (rowb + u) * W + colx] & 31;
            float t0 = TANHA ? tanhf(acc[u][0].x) : acc[u][0].x;
            float t1 = TANHA ? tanhf(acc[u][0].y) : acc[u][0].y;
            float t2 = TANHA ? tanhf(acc[u][0].z) : acc[u][0].z;
            atomicAdd(&segl[lab * 4 + 0], t0);
            atomicAdd(&segl[lab * 4 + 1], t1);
            atomicAdd(&segl[lab * 4 + 2], t2);
            atomicAdd(&segl[lab * 4 + 3], 1.f);
        }
        __syncthreads();
        if (tid < 128) {
            float v = segl[tid];
            if (v != 0.f) atomicAdd(&segacc[tid], v);
        }
    } else {
        #pragma unroll
        for (int q = 0; q < OCB / 4; q++) {
            #pragma unroll
            for (int c = 0; c < 4; c++) {
                int ocg = g * OCB + q * 4 + c;
                if (ocg < COUT) {
                    float* op = out + (size_t)(b * COUT + ocg) * HW;
                    #pragma unroll
                    for (int u = 0; u < PIXB; u++) {
                        float vv = fsel(acc[u][q], c);
                        op[(rowb + u) * W + colx] = TANHA ? tanhf(vv) : vv;
                    }
                }
            }
        }
    }
    if constexpr (STATS) stats_reduce4<OCB, PIXB>(acc, stats_out, b * COUT + g * OCB);
}

// ---------------------------------------------------------------------------
// 3x3 stride-2 zero-pad-1 conv. Input tile + per-chunk weights in LDS.
// ---------------------------------------------------------------------------
template<int CIN, int COUT, int OCB, int TWO, int PIXB, int WIN, int CICH>
__global__ __launch_bounds__(256) void conv3s2t(
    const float* __restrict__ in, const float* __restrict__ wgt,
    const float* __restrict__ bias, float* __restrict__ out,
    const float* __restrict__ stats_in, float invHWin,
    float* __restrict__ stats_out)
{
    constexpr int HIN = WIN, HWIN = WIN * WIN;
    constexpr int WOUT = WIN / 2, HWOUT = WOUT * WOUT;
    constexpr int RG = 256 / TWO, THO = RG * PIXB;
    constexpr int LROWS = 2 * THO + 1, LCOLS = 2 * TWO + 1, LDSW = 2 * TWO + 4;
    constexpr int TX = WOUT / TWO, TY = WOUT / THO, NG = COUT / OCB;
    constexpr int ISLOTS = CICH * LROWS * LCOLS;
    constexpr int WSLOTS = CICH * 9 * OCB;

    extern __shared__ float lds[];
    float* wl = lds + CICH * LROWS * LDSW;
    __shared__ float mr[CICH][2];

    const int tid = threadIdx.x;
    const int lx = tid & (TWO - 1), rg = tid / TWO;
    int bi = blockIdx.x;
    const int tx = bi % TX; bi /= TX;
    const int ty = bi % TY; bi /= TY;
    const int g  = bi % NG;
    const int b  = bi / NG;

    float4 acc[PIXB][OCB / 4];
    #pragma unroll
    for (int q = 0; q < OCB / 4; q++) {
        int o = g * OCB + q * 4;
        float4 bq = { bias[o], bias[o + 1], bias[o + 2], bias[o + 3] };
        #pragma unroll
        for (int u = 0; u < PIXB; u++) acc[u][q] = bq;
    }

    const float* inb = in + (size_t)b * CIN * HWIN;
    for (int ci0 = 0; ci0 < CIN; ci0 += CICH) {
        if (tid < CICH) {
            int c = b * CIN + ci0 + tid;
            float s = stats_in[2 * c], s2 = stats_in[2 * c + 1];
            float m = s * invHWin;
            mr[tid][0] = m;
            mr[tid][1] = rsqrtf(fmaf(s2, invHWin, -m * m) + EPS_F);
        }
        __syncthreads();
        for (int e = tid; e < ISLOTS; e += 256) {
            int cc = e / (LROWS * LCOLS);
            int rm = e - cc * (LROWS * LCOLS);
            int r  = rm / LCOLS;
            int c  = rm - r * LCOLS;
            int gy = 2 * (ty * THO) - 1 + r;
            int gx = 2 * (tx * TWO) - 1 + c;
            float x = 0.f;
            if ((unsigned)gy < (unsigned)HIN && (unsigned)gx < (unsigned)WIN) {
                x = inb[(size_t)(ci0 + cc) * HWIN + gy * WIN + gx];
                x = fmaxf((x - mr[cc][0]) * mr[cc][1], 0.f);
            }
            lds[cc * (LROWS * LDSW) + r * LDSW + c] = x;
        }
        for (int e = tid; e < WSLOTS; e += 256) {
            int oc = e & (OCB - 1);
            int k  = (e / OCB) % 9;
            int cc = e / (OCB * 9);
            wl[e] = wgt[((size_t)(g * OCB + oc) * CIN + ci0 + cc) * 9 + k];
        }
        __syncthreads();
        for (int cc = 0; cc < CICH; cc++) {
            const float* tile = lds + cc * (LROWS * LDSW);
            const float4* wq = (const float4*)wl + cc * 9 * (OCB / 4);
            #pragma unroll
            for (int u = 0; u < PIXB; u++) {
                const int lr = 2 * (rg * PIXB + u);
                #pragma unroll
                for (int ky = 0; ky < 3; ky++) {
                    #pragma unroll
                    for (int kx = 0; kx < 3; kx++) {
                        float v = tile[(lr + ky) * LDSW + 2 * lx + kx];
                        #pragma unroll
                        for (int q = 0; q < OCB / 4; q++) {
                            float4 w = wq[(ky * 3 + kx) * (OCB / 4) + q];
                            acc[u][q].x = fmaf(v, w.x, acc[u][q].x);
                            acc[u][q].y = fmaf(v, w.y, acc[u][q].y);
                            acc[u][q].z = fmaf(v, w.z, acc[u][q].z);
                            acc[u][q].w = fmaf(v, w.w, acc[u][q].w);
                        }
                    }
                }
            }
        }
        __syncthreads();
    }

    #pragma unroll
    for (int q = 0; q < OCB / 4; q++) {
        #pragma unroll
        for (int c = 0; c < 4; c++) {
            float* op = out + (size_t)(b * COUT + g * OCB + q * 4 + c) * HWOUT;
            #pragma unroll
            for (int u = 0; u < PIXB; u++)
                op[(ty * THO + rg * PIXB + u) * WOUT + tx * TWO + lx] = fsel(acc[u][q], c);
        }
    }
    stats_reduce4<OCB, PIXB>(acc, stats_out, b * COUT + g * OCB);
}

// ---------------------------------------------------------------------------
// ConvTranspose2d k=3 s=2 p=1 op=1, weight (Cin,Cout,3,3). Thread owns one
// input pixel -> 2x2 output quad. Input tile + per-chunk weights in LDS.
// ---------------------------------------------------------------------------
template<int CIN, int COUT, int OCB, int TWI, int WIN, int CICH>
__global__ __launch_bounds__(256) void deconvt(
    const float* __restrict__ in, const float* __restrict__ wgt,
    const float* __restrict__ bias, float* __restrict__ out,
    const float* __restrict__ stats_in, float invHWin,
    float* __restrict__ stats_out)
{
    constexpr int HIN = WIN, HWIN = WIN * WIN;
    constexpr int WOUT = 2 * WIN, HWOUT = 4 * HWIN;
    constexpr int THI = 256 / TWI;
    constexpr int LROWS = THI + 1, LCOLS = TWI + 1, LDSW = TWI + 4;
    constexpr int TX = WIN / TWI, TY = WIN / THI, NG = COUT / OCB;
    constexpr int ISLOTS = CICH * LROWS * LCOLS;
    constexpr int WSLOTS = CICH * 9 * OCB;

    extern __shared__ float lds[];
    float* wl = lds + CICH * LROWS * LDSW;
    __shared__ float mr[CICH][2];

    const int tid = threadIdx.x;
    const int lx = tid & (TWI - 1), ly = tid / TWI;
    int bi = blockIdx.x;
    const int tx = bi % TX; bi /= TX;
    const int ty = bi % TY; bi /= TY;
    const int g  = bi % NG;
    const int b  = bi / NG;

    float4 acc[4][OCB / 4];   // quad order: 00, 01, 10, 11
    #pragma unroll
    for (int q = 0; q < OCB / 4; q++) {
        int o = g * OCB + q * 4;
        float4 bq = { bias[o], bias[o + 1], bias[o + 2], bias[o + 3] };
        #pragma unroll
        for (int u = 0; u < 4; u++) acc[u][q] = bq;
    }

    const float* inb = in + (size_t)b * CIN * HWIN;
    for (int ci0 = 0; ci0 < CIN; ci0 += CICH) {
        if (tid < CICH) {
            int c = b * CIN + ci0 + tid;
            float s = stats_in[2 * c], s2 = stats_in[2 * c + 1];
            float m = s * invHWin;
            mr[tid][0] = m;
            mr[tid][1] = rsqrtf(fmaf(s2, invHWin, -m * m) + EPS_F);
        }
        __syncthreads();
        for (int e = tid; e < ISLOTS; e += 256) {
            int cc = e / (LROWS * LCOLS);
            int rm = e - cc * (LROWS * LCOLS);
            int r  = rm / LCOLS;
            int c  = rm - r * LCOLS;
            int gy = ty * THI + r;
            int gx = tx * TWI + c;
            float x = 0.f;
            if (gy < HIN && gx < WIN) {
                x = inb[(size_t)(ci0 + cc) * HWIN + gy * WIN + gx];
                x = fmaxf((x - mr[cc][0]) * mr[cc][1], 0.f);
            }
            lds[cc * (LROWS * LDSW) + r * LDSW + c] = x;
        }
        for (int e = tid; e < WSLOTS; e += 256) {
            int oc = e & (OCB - 1);
            int k  = (e / OCB) % 9;
            int cc = e / (OCB * 9);
            wl[e] = wgt[((size_t)(ci0 + cc) * COUT + g * OCB + oc) * 9 + k];
        }
        __syncthreads();
        for (int cc = 0; cc < CICH; cc++) {
            const float* base = lds + cc * (LROWS * LDSW) + ly * LDSW + lx;
            float v00 = base[0], v01 = base[1];
            float v10 = base[LDSW], v11 = base[LDSW + 1];
            const float4* wq = (const float4*)wl + cc * 9 * (OCB / 4);
            #pragma unroll
            for (int q = 0; q < OCB / 4; q++) {
                float4 w;
                #define DFMA(u, vv) \
                    acc[u][q].x = fmaf(w.x, vv, acc[u][q].x); \
                    acc[u][q].y = fmaf(w.y, vv, acc[u][q].y); \
                    acc[u][q].z = fmaf(w.z, vv, acc[u][q].z); \
                    acc[u][q].w = fmaf(w.w, vv, acc[u][q].w);
                w = wq[0 * (OCB / 4) + q]; DFMA(3, v11)
                w = wq[1 * (OCB / 4) + q]; DFMA(2, v10)
                w = wq[2 * (OCB / 4) + q]; DFMA(3, v10)
                w = wq[3 * (OCB / 4) + q]; DFMA(1, v01)
                w = wq[4 * (OCB / 4) + q]; DFMA(0, v00)
                w = wq[5 * (OCB / 4) + q]; DFMA(1, v00)
                w = wq[6 * (OCB / 4) + q]; DFMA(3, v01)
                w = wq[7 * (OCB / 4) + q]; DFMA(2, v00)
                w = wq[8 * (OCB / 4) + q]; DFMA(3, v00)
                #undef DFMA
            }
        }
        __syncthreads();
    }

    const int Y0 = 2 * (ty * THI + ly), X0 = 2 * (tx * TWI + lx);
    #pragma unroll
    for (int q = 0; q < OCB / 4; q++) {
        #pragma unroll
        for (int c = 0; c < 4; c++) {
            float* op = out + (size_t)(b * COUT + g * OCB + q * 4 + c) * HWOUT;
            op[(size_t)Y0 * WOUT + X0]           = fsel(acc[0][q], c);
            op[(size_t)Y0 * WOUT + X0 + 1]       = fsel(acc[1][q], c);
            op[(size_t)(Y0 + 1) * WOUT + X0]     = fsel(acc[2][q], c);
            op[(size_t)(Y0 + 1) * WOUT + X0 + 1] = fsel(acc[3][q], c);
        }
    }
    stats_reduce4<OCB, 4>(acc, stats_out, b * COUT + g * OCB);
}

// ---------------------------------------------------------------------------
// Segment finalize + scatter.
// ---------------------------------------------------------------------------
#define HW9 262144
__global__ void seg_final(const float* __restrict__ acc, float* __restrict__ means)
{
    int i = threadIdx.x;
    if (i < 96) {
        int s = i / 3, c = i - s * 3;
        means[i] = acc[s * 4 + c] / fmaxf(acc[s * 4 + 3], 1.f);
    }
}

__global__ __launch_bounds__(256) void seg_scatter(
    const int* __restrict__ inst, const float* __restrict__ means,
    float* __restrict__ out)
{
    int p   = blockIdx.x * 256 + threadIdx.x;
    int b   = p >> 18;
    int r   = p & (HW9 - 1);
    int lab = inst[p] & 31;
    float* ob = out + (size_t)b * 3 * HW9;
    ob[r]           = means[lab * 3 + 0];
    ob[HW9 + r]     = means[lab * 3 + 1];
    ob[2 * HW9 + r] = means[lab * 3 + 2];
}

// ---------------------------------------------------------------------------
// Launch.  Occupancy plan: every mid layer >= 512 blocks (>=2 blocks/CU),
// LDS/block <= ~78 KB so 2 blocks/CU always fit.
// ---------------------------------------------------------------------------
extern "C" void kernel_launch(void* const* d_in, const int* in_sizes, int n_in,
                              void* d_out, int out_size, void* d_ws, size_t ws_size,
                              hipStream_t stream)
{
    const float* x_in = (const float*)d_in[0];
    const int*   inst = (const int*)d_in[1];
    const float* W_[10];
    const float* Bs[10];
    for (int i = 0; i < 10; i++) {
        W_[i] = (const float*)d_in[2 + 2 * i];
        Bs[i] = (const float*)d_in[3 + 2 * i];
    }
    float* out = (float*)d_out;

    float* A  = (float*)d_ws;
    float* Bb = A + (size_t)16777216;
    float* st = Bb + (size_t)8388608;
    const int coff[9] = {0, 128, 384, 896, 1920, 3968, 4992, 5504, 5760};
    float* s_[9];
    for (int i = 0; i < 9; i++) s_[i] = st + coff[i];
    float* segacc = st + 5888;
    float* means  = st + 6016;
    hipMemsetAsync(st, 0, 6016 * sizeof(float), stream);

    // L0: 7x7 reflect 3->16 @512. grid 8192.
    conv7t<3, 16, 16, 2, 3, false, true, false, false>
        <<<dim3(8 * 64 * 1 * 4), dim3(256), (3 * 14 * 72 + 3 * 49 * 16) * 4, stream>>>(
        x_in, W_[0], Bs[0], A, nullptr, 0.f, s_[0], nullptr, nullptr);

    // L1: 3x3 s2 16->32 @512->256. OCB=8 -> grid 4*32*4*4 = 2048 (LDS-capped 4/CU).
    conv3s2t<16, 32, 8, 64, 2, 512, 4>
        <<<dim3(4 * 32 * 4 * 4), dim3(256), (4 * 17 * 132 + 4 * 9 * 8) * 4, stream>>>(
        A, W_[1], Bs[1], Bb, s_[0], 1.f / 262144.f, s_[1]);

    // L2: 32->64 @256->128. OCB=8 -> grid 2*16*8*4 = 1024 (4/CU).
    conv3s2t<32, 64, 8, 64, 2, 256, 4>
        <<<dim3(2 * 16 * 8 * 4), dim3(256), (4 * 17 * 132 + 4 * 9 * 8) * 4, stream>>>(
        Bb, W_[2], Bs[2], A, s_[1], 1.f / 65536.f, s_[2]);

    // L3: 64->128 @128->64. OCB=8, CICH=8 -> grid 1*8*16*4 = 512 (2/CU, 74 KB LDS).
    conv3s2t<64, 128, 8, 64, 2, 128, 8>
        <<<dim3(1 * 8 * 16 * 4), dim3(256), (8 * 17 * 132 + 8 * 9 * 8) * 4, stream>>>(
        A, W_[3], Bs[3], Bb, s_[2], 1.f / 16384.f, s_[3]);

    // L4: 128->256 @64->32. OCB=8, CICH=16 -> grid 1*4*32*4 = 512 (2/CU, 78.6 KB LDS).
    conv3s2t<128, 256, 8, 32, 1, 64, 16>
        <<<dim3(1 * 4 * 32 * 4), dim3(256), (16 * 17 * 68 + 16 * 9 * 8) * 4, stream>>>(
        Bb, W_[4], Bs[4], A, s_[3], 1.f / 4096.f, s_[4]);

    // L5: deconv 256->128 @32->64. OCB=4, CICH=32 -> grid 1*4*32*4 = 512 (2/CU, 46 KB).
    deconvt<256, 128, 4, 32, 32, 32>
        <<<dim3(1 * 4 * 32 * 4), dim3(256), (32 * 9 * 36 + 32 * 9 * 4) * 4, stream>>>(
        A, W_[5], Bs[5], Bb, s_[4], 1.f / 1024.f, s_[5]);

    // L6: deconv 128->64 @64->128. OCB=8, CICH=32 -> grid 1*16*8*4 = 512 (2/CU, 52.7 KB).
    deconvt<128, 64, 8, 64, 64, 32>
        <<<dim3(1 * 16 * 8 * 4), dim3(256), (32 * 5 * 68 + 32 * 9 * 8) * 4, stream>>>(
        Bb, W_[6], Bs[6], A, s_[5], 1.f / 4096.f, s_[6]);

    // L7: deconv 64->32 @128->256. OCB=8, CICH=16 -> grid 2*32*4*4 = 1024 (4/CU, 26.4 KB).
    deconvt<64, 32, 8, 64, 128, 16>
        <<<dim3(2 * 32 * 4 * 4), dim3(256), (16 * 5 * 68 + 16 * 9 * 8) * 4, stream>>>(
        A, W_[7], Bs[7], Bb, s_[6], 1.f / 16384.f, s_[7]);

    // L8: deconv 32->16 @256->512. grid 1024 (4/CU, 31 KB).
    deconvt<32, 16, 16, 64, 256, 16>
        <<<dim3(4 * 64 * 1 * 4), dim3(256), (16 * 5 * 68 + 16 * 9 * 16) * 4, stream>>>(
        Bb, W_[8], Bs[8], A, s_[7], 1.f / 65536.f, s_[8]);

    // L9: 7x7 reflect 16->3 @512 + tanh + fused segment accumulate (OCB=4 padded, NG=1).
    conv7t<16, 3, 4, 4, 4, true, false, true, true>
        <<<dim3(8 * 32 * 1 * 4), dim3(256), (4 * 22 * 72 + 16 * 49 * 4) * 4, stream>>>(
        A, W_[9], Bs[9], Bb, s_[8], 1.f / 262144.f, nullptr, inst, segacc);

    seg_final<<<dim3(1), dim3(96), 0, stream>>>(segacc, means);
    seg_scatter<<<dim3(4096), dim3(256), 0, stream>>>(inst, means, out);
}

// Round 7
// 982.282 us; speedup vs baseline: 6.5497x; 1.6631x over previous
//
#include <hip/hip_runtime.h>
#include <math.h>

#define EPS_F 1e-5f

typedef __attribute__((ext_vector_type(8))) short short8;
typedef __attribute__((ext_vector_type(4))) float f32x4;

__device__ __forceinline__ int reflect512(int v) {
    v = v < 0 ? -v : v;
    return v >= 512 ? 1022 - v : v;
}

__device__ __forceinline__ float fsel(const float4& v, int c) {
    return c == 0 ? v.x : c == 1 ? v.y : c == 2 ? v.z : v.w;
}

// float -> bf16 bits, round-to-nearest-even
__device__ __forceinline__ ushort f2bf(float f) {
    union { float f; unsigned u; } v; v.f = f;
    unsigned r = v.u + 0x7FFFu + ((v.u >> 16) & 1u);
    return (ushort)(r >> 16);
}

// ---------------------------------------------------------------------------
// Per-block (sum, sumsq) reduction over float4 acc[NPX][OCB/4] -> atomics.
// (used by the fp32 conv7t kernels)
// ---------------------------------------------------------------------------
template<int OCB, int NPX>
__device__ __forceinline__ void stats_reduce4(
    float4 (&a)[NPX][OCB / 4], float* __restrict__ stats, int cbase)
{
    __shared__ float red[4][OCB][2];
    int lane = threadIdx.x & 63, wv = threadIdx.x >> 6;
    #pragma unroll
    for (int oc = 0; oc < OCB; oc++) {
        float s = 0.f, s2 = 0.f;
        #pragma unroll
        for (int u = 0; u < NPX; u++) {
            float v = fsel(a[u][oc >> 2], oc & 3);
            s += v; s2 = fmaf(v, v, s2);
        }
        #pragma unroll
        for (int off = 32; off; off >>= 1) {
            s  += __shfl_down(s,  off, 64);
            s2 += __shfl_down(s2, off, 64);
        }
        if (lane == 0) { red[wv][oc][0] = s; red[wv][oc][1] = s2; }
    }
    __syncthreads();
    if ((int)threadIdx.x < OCB) {
        float s = 0.f, s2 = 0.f;
        #pragma unroll
        for (int w = 0; w < 4; w++) { s += red[w][threadIdx.x][0]; s2 += red[w][threadIdx.x][1]; }
        atomicAdd(&stats[2 * (cbase + threadIdx.x)],     s);
        atomicAdd(&stats[2 * (cbase + threadIdx.x) + 1], s2);
    }
}

// ---------------------------------------------------------------------------
// 7x7 stride-1 reflect-pad-3 conv @512x512 (fp32 direct, L0/L9 only).
// ---------------------------------------------------------------------------
template<int CIN, int COUT, int OCB, int PIXB, int CICH,
         bool NORM, bool STATS, bool SEG, bool TANHA>
__global__ __launch_bounds__(256) void conv7t(
    const float* __restrict__ in, const float* __restrict__ wgt,
    const float* __restrict__ bias, float* __restrict__ out,
    const float* __restrict__ stats_in, float invHWin,
    float* __restrict__ stats_out,
    const int* __restrict__ inst, float* __restrict__ segacc)
{
    constexpr int H = 512, W = 512, HW = H * W;
    constexpr int TH = 4 * PIXB, ROWS = TH + 6, LDSW = 72, LCOLS = 70;
    constexpr int TX = W / 64, TY = H / TH;
    constexpr int NG = (COUT + OCB - 1) / OCB;
    constexpr int ISLOTS = CICH * ROWS * LCOLS;
    constexpr int NWT = CIN * 49 * OCB;

    extern __shared__ float lds[];
    float* wl = lds + CICH * ROWS * LDSW;
    __shared__ float mr[CICH][2];
    __shared__ float segl[SEG ? 128 : 1];

    const int tid = threadIdx.x;
    const int lx = tid & 63, wv = tid >> 6;
    int bi = blockIdx.x;
    const int tx = bi % TX; bi /= TX;
    const int ty = bi % TY; bi /= TY;
    const int g  = bi % NG;
    const int b  = bi / NG;

    if constexpr (SEG) { if (tid < 128) segl[tid] = 0.f; }

    for (int e = tid; e < NWT; e += 256) {
        int oc = e & (OCB - 1);
        int k  = (e / OCB) % 49;
        int ci = e / (OCB * 49);
        int ocg = g * OCB + oc;
        wl[e] = (ocg < COUT) ? wgt[((size_t)ocg * CIN + ci) * 49 + k] : 0.f;
    }

    float4 acc[PIXB][OCB / 4];
    #pragma unroll
    for (int q = 0; q < OCB / 4; q++) {
        int o = g * OCB + q * 4;
        float4 bq;
        bq.x = (o + 0 < COUT) ? bias[o + 0] : 0.f;
        bq.y = (o + 1 < COUT) ? bias[o + 1] : 0.f;
        bq.z = (o + 2 < COUT) ? bias[o + 2] : 0.f;
        bq.w = (o + 3 < COUT) ? bias[o + 3] : 0.f;
        #pragma unroll
        for (int u = 0; u < PIXB; u++) acc[u][q] = bq;
    }

    const float* inb = in + (size_t)b * CIN * HW;
    for (int ci0 = 0; ci0 < CIN; ci0 += CICH) {
        if constexpr (NORM) {
            if (tid < CICH) {
                int c = b * CIN + ci0 + tid;
                float s = stats_in[2 * c], s2 = stats_in[2 * c + 1];
                float m = s * invHWin;
                mr[tid][0] = m;
                mr[tid][1] = rsqrtf(fmaf(s2, invHWin, -m * m) + EPS_F);
            }
        }
        __syncthreads();
        for (int e = tid; e < ISLOTS; e += 256) {
            int cc = e / (ROWS * LCOLS);
            int rm = e - cc * (ROWS * LCOLS);
            int r  = rm / LCOLS;
            int c  = rm - r * LCOLS;
            int gy = reflect512(ty * TH - 3 + r);
            int gx = reflect512(tx * 64 - 3 + c);
            float x = inb[(size_t)(ci0 + cc) * HW + gy * W + gx];
            if constexpr (NORM) x = fmaxf((x - mr[cc][0]) * mr[cc][1], 0.f);
            lds[cc * (ROWS * LDSW) + r * LDSW + c] = x;
        }
        __syncthreads();
        for (int cc = 0; cc < CICH; cc++) {
            const float* tile = lds + cc * (ROWS * LDSW);
            const float4* wq = (const float4*)wl + (size_t)(ci0 + cc) * 49 * (OCB / 4);
            #pragma unroll
            for (int r = 0; r < PIXB + 6; r++) {
                float v[7];
                #pragma unroll
                for (int k = 0; k < 7; k++)
                    v[k] = tile[(wv * PIXB + r) * LDSW + lx + k];
                #pragma unroll
                for (int ky = 0; ky < 7; ky++) {
                    const int u = r - ky;
                    if (u < 0 || u >= PIXB) continue;
                    #pragma unroll
                    for (int kx = 0; kx < 7; kx++) {
                        #pragma unroll
                        for (int q = 0; q < OCB / 4; q++) {
                            float4 w = wq[(ky * 7 + kx) * (OCB / 4) + q];
                            acc[u][q].x = fmaf(v[kx], w.x, acc[u][q].x);
                            acc[u][q].y = fmaf(v[kx], w.y, acc[u][q].y);
                            acc[u][q].z = fmaf(v[kx], w.z, acc[u][q].z);
                            acc[u][q].w = fmaf(v[kx], w.w, acc[u][q].w);
                        }
                    }
                }
            }
        }
        __syncthreads();
    }

    const int rowb = ty * TH + wv * PIXB;
    const int colx = tx * 64 + lx;
    if constexpr (SEG) {
        #pragma unroll
        for (int u = 0; u < PIXB; u++) {
            int lab = inst[(size_t)b * HW + (rowb + u) * W + colx] & 31;
            float t0 = TANHA ? tanhf(acc[u][0].x) : acc[u][0].x;
            float t1 = TANHA ? tanhf(acc[u][0].y) : acc[u][0].y;
            float t2 = TANHA ? tanhf(acc[u][0].z) : acc[u][0].z;
            atomicAdd(&segl[lab * 4 + 0], t0);
            atomicAdd(&segl[lab * 4 + 1], t1);
            atomicAdd(&segl[lab * 4 + 2], t2);
            atomicAdd(&segl[lab * 4 + 3], 1.f);
        }
        __syncthreads();
        if (tid < 128) {
            float v = segl[tid];
            if (v != 0.f) atomicAdd(&segacc[tid], v);
        }
    } else {
        #pragma unroll
        for (int q = 0; q < OCB / 4; q++) {
            #pragma unroll
            for (int c = 0; c < 4; c++) {
                int ocg = g * OCB + q * 4 + c;
                if (ocg < COUT) {
                    float* op = out + (size_t)(b * COUT + ocg) * HW;
                    #pragma unroll
                    for (int u = 0; u < PIXB; u++) {
                        float vv = fsel(acc[u][q], c);
                        op[(rowb + u) * W + colx] = TANHA ? tanhf(vv) : vv;
                    }
                }
            }
        }
    }
    if constexpr (STATS) stats_reduce4<OCB, PIXB>(acc, stats_out, b * COUT + g * OCB);
}

// ---------------------------------------------------------------------------
// Weight prep: fp32 conv(OIHW)/deconv(IOHW) -> bf16 [tap][oc][ci(pad32)].
// ---------------------------------------------------------------------------
template<int CIN, int COUT, bool DEC>
__global__ __launch_bounds__(256) void wprep(
    const float* __restrict__ w, ushort* __restrict__ dst)
{
    constexpr int CIP = ((CIN + 31) / 32) * 32;
    int i = blockIdx.x * 256 + threadIdx.x;
    if (i >= 9 * COUT * CIP) return;
    int ci = i % CIP;
    int oc = (i / CIP) % COUT;
    int t  = i / (CIP * COUT);
    float x = 0.f;
    if (ci < CIN)
        x = DEC ? w[((size_t)ci * COUT + oc) * 9 + t]
                : w[((size_t)oc * CIN + ci) * 9 + t];
    dst[i] = f2bf(x);
}

// ---------------------------------------------------------------------------
// Unified MFMA implicit-GEMM conv (MODE 0: 3x3 s2 p1 conv) / deconv
// (MODE 1: ConvTranspose2d k3 s2 p1 op1). bf16 inputs/weights, fp32 acc.
// Fused input instance-norm+ReLU (at LDS staging) and output stats.
// Block = 4 waves. Wave: n-subtile = wv%NWN (16 oc), m-group = wv/NWN.
// A-frag: A[m=lane&15][k=quad*8+j]; B-frag: B[k][n=lane&15];
// C: col(n)=lane&15, row(m)=quad*4+reg   [HW-verified layouts].
// ---------------------------------------------------------------------------
template<int CIN, int COUT, int WIN, int MODE, int NWN, int MSUB>
__global__ __launch_bounds__(256) void mfconv(
    const float* __restrict__ in, const ushort* __restrict__ wbf,
    const float* __restrict__ bias, float* __restrict__ out,
    const float* __restrict__ stats_in, float invHWin,
    float* __restrict__ stats_out)
{
    constexpr int HIN = WIN, HWIN = WIN * WIN;
    constexpr int WOUT = (MODE == 0) ? (WIN / 2) : (WIN * 2);
    constexpr int HWOUT = WOUT * WOUT;
    constexpr int NMG = 4 / NWN;
    constexpr int NOC = NWN * 16;
    constexpr int MPX = NMG * MSUB * 16;   // block pixel count (out px conv / in px deconv)
    constexpr int TLW = MPX;
    constexpr int SPAN = (MODE == 0) ? (WIN / 2) : WIN;
    constexpr int XC = SPAN / TLW;
    constexpr int YS = SPAN;
    constexpr int NG = COUT / NOC;
    constexpr int NR = (MODE == 0) ? 3 : 2;
    constexpr int NC = (MODE == 0) ? (2 * TLW + 1) : (TLW + 1);
    constexpr int NPIX = NR * NC;
    constexpr int CIP = ((CIN + 31) / 32) * 32;
    constexpr int NQ = (MODE == 0) ? 1 : 4;

    // deconv tap -> (quad, dy, dx); t is ky*3+kx of the torch weight.
    constexpr int TDY[9] = {1,1,1,0,0,0,0,0,0};
    constexpr int TDX[9] = {1,0,0,1,0,0,1,0,0};
    constexpr int TQ [9] = {3,2,3,1,0,1,3,2,3};

    extern __shared__ ushort sm[];
    ushort* sa = sm;                 // A tile: [kq][NPIX][8] bf16
    ushort* sw = sm + 32 * NPIX;     // W tile: [t][kq][NOC][8] bf16
    __shared__ float mr[32][2];
    __shared__ float sred[4][16][2];

    const int tid = threadIdx.x;
    const int lane = tid & 63, wv = tid >> 6;
    const int ln = lane & 15, kq = lane >> 4;
    const int wn = wv % NWN, wm = wv / NWN;

    int bi = blockIdx.x;
    const int xc = bi % XC; bi /= XC;
    const int y  = bi % YS; bi /= YS;
    const int g  = bi % NG;
    const int b  = bi / NG;

    const int ocg = g * NOC + wn * 16 + ln;
    const float b0 = bias[ocg];
    f32x4 acc[NQ][MSUB];
    #pragma unroll
    for (int q = 0; q < NQ; q++)
        #pragma unroll
        for (int s = 0; s < MSUB; s++)
            acc[q][s] = (f32x4){b0, b0, b0, b0};

    const float* inb = in + (size_t)b * CIN * HWIN;

    for (int c0 = 0; c0 < CIP; c0 += 32) {
        __syncthreads();                       // previous tile fully consumed
        if (tid < 32) {
            int cg = c0 + tid;
            float m = 0.f, r = 0.f;
            if (cg < CIN) {
                int c = b * CIN + cg;
                float s1 = stats_in[2 * c], s2 = stats_in[2 * c + 1];
                m = s1 * invHWin;
                r = rsqrtf(fmaf(s2, invHWin, -m * m) + EPS_F);
            }
            mr[tid][0] = m; mr[tid][1] = r;
        }
        // weights (no mr dependency)
        for (int e = tid; e < 9 * NOC * 32; e += 256) {
            int ck = e & 31;
            int oc = (e >> 5) % NOC;
            int t  = e / (32 * NOC);
            ushort wv2 = wbf[((size_t)t * COUT + g * NOC + oc) * CIP + c0 + ck];
            sw[t * (NOC * 32) + (ck >> 3) * (NOC * 8) + oc * 8 + (ck & 7)] = wv2;
        }
        __syncthreads();                       // mr visible
        // input tile: norm+relu+bf16, channel-pairs packed as one u32 write
        for (int e = tid; e < NPIX * 16; e += 256) {
            int ckp = e / NPIX;
            int pix = e - ckp * NPIX;
            int r = pix / NC, c = pix - r * NC;
            int gy, gx;
            if (MODE == 0) { gy = 2 * y - 1 + r; gx = 2 * (xc * TLW) - 1 + c; }
            else           { gy = y + r;         gx = xc * TLW + c; }
            int cg = c0 + 2 * ckp;
            float x0 = 0.f, x1 = 0.f;
            if ((unsigned)gy < (unsigned)HIN && (unsigned)gx < (unsigned)WIN) {
                const float* p = inb + (size_t)cg * HWIN + gy * WIN + gx;
                if (cg < CIN)     x0 = fmaxf((p[0]    - mr[2*ckp][0])   * mr[2*ckp][1],   0.f);
                if (cg + 1 < CIN) x1 = fmaxf((p[HWIN] - mr[2*ckp+1][0]) * mr[2*ckp+1][1], 0.f);
            }
            unsigned pk = (unsigned)f2bf(x0) | ((unsigned)f2bf(x1) << 16);
            *(unsigned*)&sa[((ckp >> 2) * NPIX + pix) * 8 + ((2 * ckp) & 7)] = pk;
        }
        __syncthreads();                       // tiles visible
        const int mb = wm * MSUB * 16 + ln;
        #pragma unroll
        for (int t = 0; t < 9; t++) {
            short8 bfr = *(const short8*)&sw[t * (NOC * 32) + kq * (NOC * 8) + (wn * 16 + ln) * 8];
            #pragma unroll
            for (int s = 0; s < MSUB; s++) {
                int m = mb + s * 16;
                int pix = (MODE == 0) ? ((t / 3) * NC + 2 * m + (t % 3))
                                      : (TDY[t] * NC + m + TDX[t]);
                short8 afr = *(const short8*)&sa[(kq * NPIX + pix) * 8];
                constexpr int qd0 = 0;
                int qd = (MODE == 0) ? qd0 : TQ[t];
                acc[qd][s] = __builtin_amdgcn_mfma_f32_16x16x32_bf16(afr, bfr, acc[qd][s], 0, 0, 0);
            }
        }
    }

    // epilogue: stores. C layout: oc = lane&15 (col), pixel m = kq*4+reg (row).
    float* ob = out + ((size_t)b * COUT + ocg) * HWOUT;
    if (MODE == 0) {
        const int ox0 = xc * TLW;
        #pragma unroll
        for (int s = 0; s < MSUB; s++) {
            int mrow = wm * MSUB * 16 + s * 16 + kq * 4;
            #pragma unroll
            for (int rg = 0; rg < 4; rg++)
                ob[y * WOUT + ox0 + mrow + rg] = acc[0][s][rg];
        }
    } else {
        const int ix0 = xc * TLW;
        #pragma unroll
        for (int q = 0; q < 4; q++) {
            int dy = q >> 1, dx = q & 1;
            int row = (2 * y + dy) * WOUT + dx;
            #pragma unroll
            for (int s = 0; s < MSUB; s++) {
                int mpx = wm * MSUB * 16 + s * 16 + kq * 4;
                #pragma unroll
                for (int rg = 0; rg < 4; rg++)
                    ob[row + 2 * (ix0 + mpx + rg)] = acc[q][s][rg];
            }
        }
    }

    // stats: per-lane partial over its pixels, reduce lanes sharing oc.
    float s1 = 0.f, s2 = 0.f;
    #pragma unroll
    for (int q = 0; q < NQ; q++)
        #pragma unroll
        for (int s = 0; s < MSUB; s++)
            #pragma unroll
            for (int rg = 0; rg < 4; rg++) {
                float v = acc[q][s][rg];
                s1 += v; s2 = fmaf(v, v, s2);
            }
    s1 += __shfl_xor(s1, 16); s2 += __shfl_xor(s2, 16);
    s1 += __shfl_xor(s1, 32); s2 += __shfl_xor(s2, 32);
    if (lane < 16) { sred[wv][lane][0] = s1; sred[wv][lane][1] = s2; }
    __syncthreads();
    if (tid < NOC) {
        int wnn = tid >> 4, oc = tid & 15;
        float t1 = 0.f, t2 = 0.f;
        #pragma unroll
        for (int k = 0; k < NMG; k++) {
            t1 += sred[wnn + k * NWN][oc][0];
            t2 += sred[wnn + k * NWN][oc][1];
        }
        int cix = b * COUT + g * NOC + wnn * 16 + oc;
        atomicAdd(&stats_out[2 * cix],     t1);
        atomicAdd(&stats_out[2 * cix + 1], t2);
    }
}

// ---------------------------------------------------------------------------
// Segment finalize + scatter.
// ---------------------------------------------------------------------------
#define HW9 262144
__global__ void seg_final(const float* __restrict__ acc, float* __restrict__ means)
{
    int i = threadIdx.x;
    if (i < 96) {
        int s = i / 3, c = i - s * 3;
        means[i] = acc[s * 4 + c] / fmaxf(acc[s * 4 + 3], 1.f);
    }
}

__global__ __launch_bounds__(256) void seg_scatter(
    const int* __restrict__ inst, const float* __restrict__ means,
    float* __restrict__ out)
{
    int p   = blockIdx.x * 256 + threadIdx.x;
    int b   = p >> 18;
    int r   = p & (HW9 - 1);
    int lab = inst[p] & 31;
    float* ob = out + (size_t)b * 3 * HW9;
    ob[r]           = means[lab * 3 + 0];
    ob[HW9 + r]     = means[lab * 3 + 1];
    ob[2 * HW9 + r] = means[lab * 3 + 2];
}

// ---------------------------------------------------------------------------
// Launch.
// ---------------------------------------------------------------------------
extern "C" void kernel_launch(void* const* d_in, const int* in_sizes, int n_in,
                              void* d_out, int out_size, void* d_ws, size_t ws_size,
                              hipStream_t stream)
{
    const float* x_in = (const float*)d_in[0];
    const int*   inst = (const int*)d_in[1];
    const float* W_[10];
    const float* Bs[10];
    for (int i = 0; i < 10; i++) {
        W_[i] = (const float*)d_in[2 + 2 * i];
        Bs[i] = (const float*)d_in[3 + 2 * i];
    }
    float* out = (float*)d_out;

    float* A  = (float*)d_ws;
    float* Bb = A + (size_t)16777216;
    float* st = Bb + (size_t)8388608;
    const int coff[9] = {0, 128, 384, 896, 1920, 3968, 4992, 5504, 5760};
    float* s_[9];
    for (int i = 0; i < 9; i++) s_[i] = st + coff[i];
    float* segacc = st + 5888;
    float* means  = st + 6016;
    // bf16 weight tensors [t][oc][ci(pad32)], after the stats region.
    ushort* wb = (ushort*)(st + 8192);
    const size_t OW1 = 0, OW2 = 9216, OW3 = 27648, OW4 = 101376,
                 OW5 = 396288, OW6 = 691200, OW7 = 764928, OW8 = 783360;

    hipMemsetAsync(st, 0, 6016 * sizeof(float), stream);

    // Weight prep (bf16 repack), before everything.
    wprep<16,  32,  false><<<dim3((9*32*32   + 255)/256), dim3(256), 0, stream>>>(W_[1], wb + OW1);
    wprep<32,  64,  false><<<dim3((9*64*32   + 255)/256), dim3(256), 0, stream>>>(W_[2], wb + OW2);
    wprep<64,  128, false><<<dim3((9*128*64  + 255)/256), dim3(256), 0, stream>>>(W_[3], wb + OW3);
    wprep<128, 256, false><<<dim3((9*256*128 + 255)/256), dim3(256), 0, stream>>>(W_[4], wb + OW4);
    wprep<256, 128, true ><<<dim3((9*128*256 + 255)/256), dim3(256), 0, stream>>>(W_[5], wb + OW5);
    wprep<128, 64,  true ><<<dim3((9*64*128  + 255)/256), dim3(256), 0, stream>>>(W_[6], wb + OW6);
    wprep<64,  32,  true ><<<dim3((9*32*64   + 255)/256), dim3(256), 0, stream>>>(W_[7], wb + OW7);
    wprep<32,  16,  true ><<<dim3((9*16*32   + 255)/256), dim3(256), 0, stream>>>(W_[8], wb + OW8);

    // L0: 7x7 reflect 3->16 @512 (fp32 direct + stats).
    conv7t<3, 16, 16, 2, 3, false, true, false, false>
        <<<dim3(8 * 64 * 1 * 4), dim3(256), (3 * 14 * 72 + 3 * 49 * 16) * 4, stream>>>(
        x_in, W_[0], Bs[0], A, nullptr, 0.f, s_[0], nullptr, nullptr);

    // L1: conv s2 16->32 @512->256. NWN=2, MSUB=2 -> M=64, grid 4096.
    mfconv<16, 32, 512, 0, 2, 2><<<dim3(4096), dim3(256), 43200, stream>>>(
        A, wb + OW1, Bs[1], Bb, s_[0], 1.f / 262144.f, s_[1]);

    // L2: conv s2 32->64 @256->128. grid 2048.
    mfconv<32, 64, 256, 0, 4, 2><<<dim3(2048), dim3(256), 49344, stream>>>(
        Bb, wb + OW2, Bs[2], A, s_[1], 1.f / 65536.f, s_[2]);

    // L3: conv s2 64->128 @128->64. grid 1024.
    mfconv<64, 128, 128, 0, 4, 2><<<dim3(1024), dim3(256), 49344, stream>>>(
        A, wb + OW3, Bs[3], Bb, s_[2], 1.f / 16384.f, s_[3]);

    // L4: conv s2 128->256 @64->32. grid 512.
    mfconv<128, 256, 64, 0, 4, 2><<<dim3(512), dim3(256), 49344, stream>>>(
        Bb, wb + OW4, Bs[4], A, s_[3], 1.f / 4096.f, s_[4]);

    // L5: deconv 256->128 @32->64. MSUB=1, grid 512.
    mfconv<256, 128, 32, 1, 4, 1><<<dim3(512), dim3(256), 39040, stream>>>(
        A, wb + OW5, Bs[5], Bb, s_[4], 1.f / 1024.f, s_[5]);

    // L6: deconv 128->64 @64->128. grid 512.
    mfconv<128, 64, 64, 1, 4, 2><<<dim3(512), dim3(256), 41088, stream>>>(
        Bb, wb + OW6, Bs[6], A, s_[5], 1.f / 4096.f, s_[6]);

    // L7: deconv 64->32 @128->256. NWN=2, grid 1024.
    mfconv<64, 32, 128, 1, 2, 2><<<dim3(1024), dim3(256), 26752, stream>>>(
        A, wb + OW7, Bs[7], Bb, s_[6], 1.f / 16384.f, s_[7]);

    // L8: deconv 32->16 @256->512. NWN=1, grid 2048.
    mfconv<32, 16, 256, 1, 1, 2><<<dim3(2048), dim3(256), 25728, stream>>>(
        Bb, wb + OW8, Bs[8], A, s_[7], 1.f / 65536.f, s_[8]);

    // L9: 7x7 reflect 16->3 @512 + tanh + fused segment accumulate (fp32).
    conv7t<16, 3, 4, 4, 4, true, false, true, true>
        <<<dim3(8 * 32 * 1 * 4), dim3(256), (4 * 22 * 72 + 16 * 49 * 4) * 4, stream>>>(
        A, W_[9], Bs[9], Bb, s_[8], 1.f / 262144.f, nullptr, inst, segacc);

    seg_final<<<dim3(1), dim3(96), 0, stream>>>(segacc, means);
    seg_scatter<<<dim3(4096), dim3(256), 0, stream>>>(inst, means, out);
}

// Round 8
// 787.805 us; speedup vs baseline: 8.1666x; 1.2469x over previous
//
#include <hip/hip_runtime.h>
#include <math.h>

#define EPS_F 1e-5f

typedef __attribute__((ext_vector_type(8))) short short8;
typedef __attribute__((ext_vector_type(4))) float f32x4;

__device__ __forceinline__ int reflect512(int v) {
    v = v < 0 ? -v : v;
    return v >= 512 ? 1022 - v : v;
}

__device__ __forceinline__ float fsel(const float4& v, int c) {
    return c == 0 ? v.x : c == 1 ? v.y : c == 2 ? v.z : v.w;
}

// float -> bf16 bits, round-to-nearest-even
__device__ __forceinline__ ushort f2bf(float f) {
    union { float f; unsigned u; } v; v.f = f;
    unsigned r = v.u + 0x7FFFu + ((v.u >> 16) & 1u);
    return (ushort)(r >> 16);
}

// ---------------------------------------------------------------------------
// fp32 stats reduction (for conv7t / L0 only).
// ---------------------------------------------------------------------------
template<int OCB, int NPX>
__device__ __forceinline__ void stats_reduce4(
    float4 (&a)[NPX][OCB / 4], float* __restrict__ stats, int cbase)
{
    __shared__ float red[4][OCB][2];
    int lane = threadIdx.x & 63, wv = threadIdx.x >> 6;
    #pragma unroll
    for (int oc = 0; oc < OCB; oc++) {
        float s = 0.f, s2 = 0.f;
        #pragma unroll
        for (int u = 0; u < NPX; u++) {
            float v = fsel(a[u][oc >> 2], oc & 3);
            s += v; s2 = fmaf(v, v, s2);
        }
        #pragma unroll
        for (int off = 32; off; off >>= 1) {
            s  += __shfl_down(s,  off, 64);
            s2 += __shfl_down(s2, off, 64);
        }
        if (lane == 0) { red[wv][oc][0] = s; red[wv][oc][1] = s2; }
    }
    __syncthreads();
    if ((int)threadIdx.x < OCB) {
        float s = 0.f, s2 = 0.f;
        #pragma unroll
        for (int w = 0; w < 4; w++) { s += red[w][threadIdx.x][0]; s2 += red[w][threadIdx.x][1]; }
        atomicAdd(&stats[2 * (cbase + threadIdx.x)],     s);
        atomicAdd(&stats[2 * (cbase + threadIdx.x) + 1], s2);
    }
}

// ---------------------------------------------------------------------------
// 7x7 reflect conv fp32 direct — used for L0 only (Cin=3 not MFMA-friendly).
// ---------------------------------------------------------------------------
template<int CIN, int COUT, int OCB, int PIXB, int CICH>
__global__ __launch_bounds__(256) void conv7t(
    const float* __restrict__ in, const float* __restrict__ wgt,
    const float* __restrict__ bias, float* __restrict__ out,
    float* __restrict__ stats_out)
{
    constexpr int H = 512, W = 512, HW = H * W;
    constexpr int TH = 4 * PIXB, ROWS = TH + 6, LDSW = 72, LCOLS = 70;
    constexpr int TX = W / 64, TY = H / TH;
    constexpr int NG = (COUT + OCB - 1) / OCB;
    constexpr int ISLOTS = CICH * ROWS * LCOLS;
    constexpr int NWT = CIN * 49 * OCB;

    extern __shared__ float lds[];
    float* wl = lds + CICH * ROWS * LDSW;

    const int tid = threadIdx.x;
    const int lx = tid & 63, wv = tid >> 6;
    int bi = blockIdx.x;
    const int tx = bi % TX; bi /= TX;
    const int ty = bi % TY; bi /= TY;
    const int g  = bi % NG;
    const int b  = bi / NG;

    for (int e = tid; e < NWT; e += 256) {
        int oc = e & (OCB - 1);
        int k  = (e / OCB) % 49;
        int ci = e / (OCB * 49);
        int ocg = g * OCB + oc;
        wl[e] = (ocg < COUT) ? wgt[((size_t)ocg * CIN + ci) * 49 + k] : 0.f;
    }

    float4 acc[PIXB][OCB / 4];
    #pragma unroll
    for (int q = 0; q < OCB / 4; q++) {
        int o = g * OCB + q * 4;
        float4 bq = { bias[o], bias[o + 1], bias[o + 2], bias[o + 3] };
        #pragma unroll
        for (int u = 0; u < PIXB; u++) acc[u][q] = bq;
    }

    const float* inb = in + (size_t)b * CIN * HW;
    for (int ci0 = 0; ci0 < CIN; ci0 += CICH) {
        __syncthreads();
        for (int e = tid; e < ISLOTS; e += 256) {
            int cc = e / (ROWS * LCOLS);
            int rm = e - cc * (ROWS * LCOLS);
            int r  = rm / LCOLS;
            int c  = rm - r * LCOLS;
            int gy = reflect512(ty * TH - 3 + r);
            int gx = reflect512(tx * 64 - 3 + c);
            lds[cc * (ROWS * LDSW) + r * LDSW + c] = inb[(size_t)(ci0 + cc) * HW + gy * W + gx];
        }
        __syncthreads();
        for (int cc = 0; cc < CICH; cc++) {
            const float* tile = lds + cc * (ROWS * LDSW);
            const float4* wq = (const float4*)wl + (size_t)(ci0 + cc) * 49 * (OCB / 4);
            #pragma unroll
            for (int r = 0; r < PIXB + 6; r++) {
                float v[7];
                #pragma unroll
                for (int k = 0; k < 7; k++)
                    v[k] = tile[(wv * PIXB + r) * LDSW + lx + k];
                #pragma unroll
                for (int ky = 0; ky < 7; ky++) {
                    const int u = r - ky;
                    if (u < 0 || u >= PIXB) continue;
                    #pragma unroll
                    for (int kx = 0; kx < 7; kx++) {
                        #pragma unroll
                        for (int q = 0; q < OCB / 4; q++) {
                            float4 w = wq[(ky * 7 + kx) * (OCB / 4) + q];
                            acc[u][q].x = fmaf(v[kx], w.x, acc[u][q].x);
                            acc[u][q].y = fmaf(v[kx], w.y, acc[u][q].y);
                            acc[u][q].z = fmaf(v[kx], w.z, acc[u][q].z);
                            acc[u][q].w = fmaf(v[kx], w.w, acc[u][q].w);
                        }
                    }
                }
            }
        }
    }

    const int rowb = ty * TH + wv * PIXB;
    const int colx = tx * 64 + lx;
    #pragma unroll
    for (int q = 0; q < OCB / 4; q++) {
        #pragma unroll
        for (int c = 0; c < 4; c++) {
            int ocg = g * OCB + q * 4 + c;
            if (ocg < COUT) {
                float* op = out + (size_t)(b * COUT + ocg) * HW;
                #pragma unroll
                for (int u = 0; u < PIXB; u++)
                    op[(rowb + u) * W + colx] = fsel(acc[u][q], c);
            }
        }
    }
    stats_reduce4<OCB, PIXB>(acc, stats_out, b * COUT + g * OCB);
}

// ---------------------------------------------------------------------------
// Weight prep: fp32 conv(OIHW)/deconv(IOHW) -> bf16 [tap][oc][ci(pad32)].
// ---------------------------------------------------------------------------
template<int CIN, int COUT, bool DEC>
__global__ __launch_bounds__(256) void wprep(
    const float* __restrict__ w, ushort* __restrict__ dst)
{
    constexpr int CIP = ((CIN + 31) / 32) * 32;
    int i = blockIdx.x * 256 + threadIdx.x;
    if (i >= 9 * COUT * CIP) return;
    int ci = i % CIP;
    int oc = (i / CIP) % COUT;
    int t  = i / (CIP * COUT);
    float x = 0.f;
    if (ci < CIN)
        x = DEC ? w[((size_t)ci * COUT + oc) * 9 + t]
                : w[((size_t)oc * CIN + ci) * 9 + t];
    dst[i] = f2bf(x);
}

// ---------------------------------------------------------------------------
// MFMA implicit-GEMM conv (MODE 0: 3x3 s2 p1) / deconv (MODE 1: k3 s2 p1 op1).
// A-tile (RT x CT block of out/in pixels + halo) in LDS, bf16, with fused
// input instance-norm+ReLU. B-fragments loaded DIRECTLY from global
// [tap][oc][ci] bf16 (L1/L2-resident) — no weight LDS staging.
// Frag layouts (HW-verified): A[m=ln][k=kq*8+j]; B[k][n=ln];
// C: col(n)=ln, row(m)=kq*4+reg.
// ---------------------------------------------------------------------------
template<int CIN, int COUT, int WIN, int MODE, int NWN, int MSUB, int RT, int CT>
__global__ __launch_bounds__(256) void mfconv(
    const float* __restrict__ in, const ushort* __restrict__ wbf,
    const float* __restrict__ bias, float* __restrict__ out,
    const float* __restrict__ stats_in, float invHWin,
    float* __restrict__ stats_out)
{
    constexpr int HWIN = WIN * WIN;
    constexpr int WOUT = (MODE == 0) ? (WIN / 2) : (WIN * 2);
    constexpr int HWOUT = WOUT * WOUT;
    constexpr int NMG = 4 / NWN;
    constexpr int NOC = NWN * 16;
    constexpr int M = NMG * MSUB * 16;
    static_assert(M == RT * CT, "tile mismatch");
    constexpr int SPAN = (MODE == 0) ? WOUT : WIN;
    constexpr int XC = SPAN / CT, YC = SPAN / RT;
    constexpr int NG = COUT / NOC;
    constexpr int NR = (MODE == 0) ? (2 * RT + 1) : (RT + 1);
    constexpr int NCO = (MODE == 0) ? (2 * CT + 1) : (CT + 1);
    constexpr int NPIX = NR * NCO;
    constexpr int CIP = ((CIN + 31) / 32) * 32;
    constexpr int NQ = (MODE == 0) ? 1 : 4;

    constexpr int TDY[9] = {1,1,1,0,0,0,0,0,0};
    constexpr int TDX[9] = {1,0,0,1,0,0,1,0,0};
    constexpr int TQ [9] = {3,2,3,1,0,1,3,2,3};

    extern __shared__ ushort sa[];        // [4][NR][NCO][8] bf16
    __shared__ float mrall[CIN][2];
    __shared__ float sred[4][16][2];

    const int tid = threadIdx.x;
    const int lane = tid & 63, wv = tid >> 6;
    const int ln = lane & 15, kq = lane >> 4;
    const int wn = wv % NWN, wm = wv / NWN;

    int bi = blockIdx.x;
    const int xc = bi % XC; bi /= XC;
    const int yc = bi % YC; bi /= YC;
    const int g  = bi % NG;
    const int b  = bi / NG;

    const int ocg = g * NOC + wn * 16 + ln;
    const float b0 = bias[ocg];
    f32x4 acc[NQ][MSUB];
    #pragma unroll
    for (int q = 0; q < NQ; q++)
        #pragma unroll
        for (int s = 0; s < MSUB; s++)
            acc[q][s] = (f32x4){b0, b0, b0, b0};

    // all-channel norm params once
    for (int e = tid; e < CIN; e += 256) {
        int c = b * CIN + e;
        float s1 = stats_in[2 * c], s2 = stats_in[2 * c + 1];
        float m = s1 * invHWin;
        mrall[e][0] = m;
        mrall[e][1] = rsqrtf(fmaf(s2, invHWin, -m * m) + EPS_F);
    }

    const float* inb = in + (size_t)b * CIN * HWIN;

    for (int c0 = 0; c0 < CIP; c0 += 32) {
        __syncthreads();   // prev tile consumed (and mrall visible on iter 0)
        for (int e = tid; e < NPIX * 16; e += 256) {
            int cp  = e / NPIX;
            int pix = e - cp * NPIX;
            int pr = pix / NCO, pc = pix - pr * NCO;
            int gy, gx;
            if (MODE == 0) { gy = 2 * (yc * RT) - 1 + pr; gx = 2 * (xc * CT) - 1 + pc; }
            else           { gy = yc * RT + pr;           gx = xc * CT + pc; }
            int cg = c0 + 2 * cp;
            float x0 = 0.f, x1 = 0.f;
            if ((unsigned)gy < (unsigned)WIN && (unsigned)gx < (unsigned)WIN) {
                const float* p = inb + (size_t)cg * HWIN + gy * WIN + gx;
                if (cg < CIN)     x0 = fmaxf((p[0]    - mrall[cg][0])   * mrall[cg][1],   0.f);
                if (cg + 1 < CIN) x1 = fmaxf((p[HWIN] - mrall[cg+1][0]) * mrall[cg+1][1], 0.f);
            }
            unsigned pk = (unsigned)f2bf(x0) | ((unsigned)f2bf(x1) << 16);
            *(unsigned*)&sa[((cp >> 2) * (NR * NCO) + pix) * 8 + ((2 * cp) & 7)] = pk;
        }
        __syncthreads();
        #pragma unroll
        for (int t = 0; t < 9; t++) {
            short8 bfr = *(const short8*)&wbf[((size_t)t * COUT + ocg) * CIP + c0 + kq * 8];
            #pragma unroll
            for (int s = 0; s < MSUB; s++) {
                const int mb = wm * MSUB * 16 + s * 16;
                const int r = mb / CT, cb = mb % CT;
                int pr, pc;
                if (MODE == 0) { pr = t / 3 + 2 * r; pc = 2 * (cb + ln) + t % 3; }
                else           { pr = TDY[t] + r;    pc = cb + ln + TDX[t]; }
                short8 afr = *(const short8*)&sa[((kq * NR + pr) * NCO + pc) * 8];
                int qd = (MODE == 0) ? 0 : TQ[t];
                acc[qd][s] = __builtin_amdgcn_mfma_f32_16x16x32_bf16(afr, bfr, acc[qd][s], 0, 0, 0);
            }
        }
    }

    float* ob = out + ((size_t)b * COUT + ocg) * HWOUT;
    if (MODE == 0) {
        #pragma unroll
        for (int s = 0; s < MSUB; s++) {
            const int mb = wm * MSUB * 16 + s * 16 + kq * 4;
            const int r = mb / CT, cb = mb % CT;
            const int base = (yc * RT + r) * WOUT + xc * CT + cb;
            #pragma unroll
            for (int rg = 0; rg < 4; rg++)
                ob[base + rg] = acc[0][s][rg];
        }
    } else {
        #pragma unroll
        for (int q = 0; q < 4; q++) {
            const int dy = q >> 1, dx = q & 1;
            #pragma unroll
            for (int s = 0; s < MSUB; s++) {
                const int mb = wm * MSUB * 16 + s * 16 + kq * 4;
                const int r = mb / CT, cb = mb % CT;
                const int base = (2 * (yc * RT + r) + dy) * WOUT + 2 * (xc * CT + cb) + dx;
                #pragma unroll
                for (int rg = 0; rg < 4; rg++)
                    ob[base + 2 * rg] = acc[q][s][rg];
            }
        }
    }

    float s1 = 0.f, s2 = 0.f;
    #pragma unroll
    for (int q = 0; q < NQ; q++)
        #pragma unroll
        for (int s = 0; s < MSUB; s++)
            #pragma unroll
            for (int rg = 0; rg < 4; rg++) {
                float v = acc[q][s][rg];
                s1 += v; s2 = fmaf(v, v, s2);
            }
    s1 += __shfl_xor(s1, 16); s2 += __shfl_xor(s2, 16);
    s1 += __shfl_xor(s1, 32); s2 += __shfl_xor(s2, 32);
    if (lane < 16) { sred[wv][lane][0] = s1; sred[wv][lane][1] = s2; }
    __syncthreads();
    if (tid < NOC) {
        int wnn = tid >> 4, oc = tid & 15;
        float t1 = 0.f, t2 = 0.f;
        #pragma unroll
        for (int k = 0; k < NMG; k++) {
            t1 += sred[wnn + k * NWN][oc][0];
            t2 += sred[wnn + k * NWN][oc][1];
        }
        int cix = b * COUT + g * NOC + wnn * 16 + oc;
        atomicAdd(&stats_out[2 * cix],     t1);
        atomicAdd(&stats_out[2 * cix + 1], t2);
    }
}

// ---------------------------------------------------------------------------
// L9: 7x7 reflect conv 16->3 @512 via MFMA (N padded to 16), fused input
// norm+ReLU, tanh, and segment accumulation. A-tile + weights staged ONCE.
// K = 49 taps x 16 ch = 784 -> 25 chunks of 32 (tap-pairs; tap 49 zero-pad).
// ---------------------------------------------------------------------------
__global__ __launch_bounds__(256) void conv7m(
    const float* __restrict__ in, const float* __restrict__ w9,
    const float* __restrict__ bias,
    const float* __restrict__ stats_in, float invHWin,
    const int* __restrict__ inst, float* __restrict__ segacc)
{
    constexpr int W = 512, HW = 512 * 512;
    __shared__ ushort sa[2 * 14 * 70 * 8];    // [h][row14][col70][8ci]
    __shared__ ushort sw[25 * 4 * 16 * 8];    // [chunk][kq][oc16][8]
    __shared__ float mr[16][2];
    __shared__ float segl[128];

    const int tid = threadIdx.x;
    const int lane = tid & 63, wv = tid >> 6;
    const int ln = lane & 15, kq = lane >> 4;

    int bi = blockIdx.x;
    const int xc = bi & 7;          // 8 col tiles of 64
    const int yr = (bi >> 3) & 63;  // 64 row tiles of 8
    const int b  = bi >> 9;
    const int y0 = yr * 8, x0 = xc * 64;

    if (tid < 128) segl[tid] = 0.f;
    if (tid < 16) {
        int c = b * 16 + tid;
        float s1 = stats_in[2 * c], s2 = stats_in[2 * c + 1];
        float m = s1 * invHWin;
        mr[tid][0] = m;
        mr[tid][1] = rsqrtf(fmaf(s2, invHWin, -m * m) + EPS_F);
    }
    // weights: 12800 el, fp32->bf16 on the fly (2352-float source, L1-hot)
    for (int e = tid; e < 12800; e += 256) {
        int j  = e & 7;
        int oc = (e >> 3) & 15;
        int kqe = (e >> 7) & 3;
        int cn = e >> 9;
        int k = cn * 32 + kqe * 8 + j;
        int t = k >> 4, ci = k & 15;
        float v = (t < 49 && oc < 3) ? w9[((size_t)oc * 16 + ci) * 49 + t] : 0.f;
        sw[e] = f2bf(v);
    }
    __syncthreads();   // mr visible
    // A-tile: 14 x 70 x 16ch, norm+relu, bf16 pack
    const float* inb = in + (size_t)b * 16 * HW;
    for (int e = tid; e < 980 * 8; e += 256) {
        int cp  = e / 980;
        int pix = e - cp * 980;
        int pr = pix / 70, pc = pix - pr * 70;
        int gy = reflect512(y0 - 3 + pr);
        int gx = reflect512(x0 - 3 + pc);
        int ci0 = 2 * cp;
        const float* p = inb + (size_t)ci0 * HW + gy * W + gx;
        float v0 = fmaxf((p[0]  - mr[ci0][0])   * mr[ci0][1],   0.f);
        float v1 = fmaxf((p[HW] - mr[ci0+1][0]) * mr[ci0+1][1], 0.f);
        unsigned pk = (unsigned)f2bf(v0) | ((unsigned)f2bf(v1) << 16);
        *(unsigned*)&sa[(((cp >> 2) * 14 + pr) * 70 + pc) * 8 + (ci0 & 7)] = pk;
    }
    __syncthreads();   // tiles visible

    const float b0 = (ln < 3) ? bias[ln] : 0.f;
    f32x4 acc[8];
    #pragma unroll
    for (int s = 0; s < 8; s++) acc[s] = (f32x4){b0, b0, b0, b0};

    const int tl = kq >> 1, h = kq & 1;
    for (int cn = 0; cn < 25; cn++) {
        short8 bfr = *(const short8*)&sw[((cn * 4 + kq) * 16 + ln) * 8];
        int t = 2 * cn + tl; t = t > 48 ? 48 : t;
        const int ty = t / 7, tx = t - ty * 7;
        #pragma unroll
        for (int s = 0; s < 8; s++) {
            int m = wv * 128 + s * 16 + ln;
            int r = m >> 6, c = m & 63;
            short8 afr = *(const short8*)&sa[((h * 14 + r + ty) * 70 + c + tx) * 8];
            acc[s] = __builtin_amdgcn_mfma_f32_16x16x32_bf16(afr, bfr, acc[s], 0, 0, 0);
        }
    }

    // fused tanh + segment accumulate. C: col(oc)=ln, row m = kq*4+reg.
    if (ln < 3) {
        const int* ib = inst + ((size_t)b << 18);
        #pragma unroll
        for (int s = 0; s < 8; s++) {
            #pragma unroll
            for (int rg = 0; rg < 4; rg++) {
                int m = wv * 128 + s * 16 + kq * 4 + rg;
                int r = m >> 6, c = m & 63;
                int lab = ib[(y0 + r) * W + x0 + c] & 31;
                float val = tanhf(acc[s][rg]);
                atomicAdd(&segl[lab * 4 + ln], val);
                if (ln == 0) atomicAdd(&segl[lab * 4 + 3], 1.f);
            }
        }
    }
    __syncthreads();
    if (tid < 128) {
        float v = segl[tid];
        if (v != 0.f) atomicAdd(&segacc[tid], v);
    }
}

// ---------------------------------------------------------------------------
// Segment finalize + scatter.
// ---------------------------------------------------------------------------
#define HW9 262144
__global__ void seg_final(const float* __restrict__ acc, float* __restrict__ means)
{
    int i = threadIdx.x;
    if (i < 96) {
        int s = i / 3, c = i - s * 3;
        means[i] = acc[s * 4 + c] / fmaxf(acc[s * 4 + 3], 1.f);
    }
}

__global__ __launch_bounds__(256) void seg_scatter(
    const int* __restrict__ inst, const float* __restrict__ means,
    float* __restrict__ out)
{
    int p   = blockIdx.x * 256 + threadIdx.x;
    int b   = p >> 18;
    int r   = p & (HW9 - 1);
    int lab = inst[p] & 31;
    float* ob = out + (size_t)b * 3 * HW9;
    ob[r]           = means[lab * 3 + 0];
    ob[HW9 + r]     = means[lab * 3 + 1];
    ob[2 * HW9 + r] = means[lab * 3 + 2];
}

// ---------------------------------------------------------------------------
// Launch.
// ---------------------------------------------------------------------------
extern "C" void kernel_launch(void* const* d_in, const int* in_sizes, int n_in,
                              void* d_out, int out_size, void* d_ws, size_t ws_size,
                              hipStream_t stream)
{
    const float* x_in = (const float*)d_in[0];
    const int*   inst = (const int*)d_in[1];
    const float* W_[10];
    const float* Bs[10];
    for (int i = 0; i < 10; i++) {
        W_[i] = (const float*)d_in[2 + 2 * i];
        Bs[i] = (const float*)d_in[3 + 2 * i];
    }
    float* out = (float*)d_out;

    float* A  = (float*)d_ws;
    float* Bb = A + (size_t)16777216;
    float* st = Bb + (size_t)8388608;
    const int coff[9] = {0, 128, 384, 896, 1920, 3968, 4992, 5504, 5760};
    float* s_[9];
    for (int i = 0; i < 9; i++) s_[i] = st + coff[i];
    float* segacc = st + 5888;
    float* means  = st + 6016;
    ushort* wb = (ushort*)(st + 8192);
    const size_t OW1 = 0, OW2 = 9216, OW3 = 27648, OW4 = 101376,
                 OW5 = 396288, OW6 = 691200, OW7 = 764928, OW8 = 783360;

    hipMemsetAsync(st, 0, 6016 * sizeof(float), stream);

    wprep<16,  32,  false><<<dim3((9*32*32   + 255)/256), dim3(256), 0, stream>>>(W_[1], wb + OW1);
    wprep<32,  64,  false><<<dim3((9*64*32   + 255)/256), dim3(256), 0, stream>>>(W_[2], wb + OW2);
    wprep<64,  128, false><<<dim3((9*128*64  + 255)/256), dim3(256), 0, stream>>>(W_[3], wb + OW3);
    wprep<128, 256, false><<<dim3((9*256*128 + 255)/256), dim3(256), 0, stream>>>(W_[4], wb + OW4);
    wprep<256, 128, true ><<<dim3((9*128*256 + 255)/256), dim3(256), 0, stream>>>(W_[5], wb + OW5);
    wprep<128, 64,  true ><<<dim3((9*64*128  + 255)/256), dim3(256), 0, stream>>>(W_[6], wb + OW6);
    wprep<64,  32,  true ><<<dim3((9*32*64   + 255)/256), dim3(256), 0, stream>>>(W_[7], wb + OW7);
    wprep<32,  16,  true ><<<dim3((9*16*32   + 255)/256), dim3(256), 0, stream>>>(W_[8], wb + OW8);

    // L0: 7x7 reflect 3->16 @512 (fp32 direct + stats).
    conv7t<3, 16, 16, 2, 3>
        <<<dim3(8 * 64 * 1 * 4), dim3(256), (3 * 14 * 72 + 3 * 49 * 16) * 4, stream>>>(
        x_in, W_[0], Bs[0], A, s_[0]);

    // L1: conv 16->32 @512->256. NWN=2 MSUB=4 RT=4 CT=32. grid 2048.
    mfconv<16, 32, 512, 0, 2, 4, 4, 32><<<dim3(2048), dim3(256), 37440, stream>>>(
        A, wb + OW1, Bs[1], Bb, s_[0], 1.f / 262144.f, s_[1]);

    // L2: conv 32->64 @256->128. grid 1024.
    mfconv<32, 64, 256, 0, 2, 4, 4, 32><<<dim3(1024), dim3(256), 37440, stream>>>(
        Bb, wb + OW2, Bs[2], A, s_[1], 1.f / 65536.f, s_[2]);

    // L3: conv 64->128 @128->64. grid 512.
    mfconv<64, 128, 128, 0, 2, 4, 4, 32><<<dim3(512), dim3(256), 37440, stream>>>(
        A, wb + OW3, Bs[3], Bb, s_[2], 1.f / 16384.f, s_[3]);

    // L4: conv 128->256 @64->32. NWN=2 MSUB=2 RT=2 CT=32. grid 512.
    mfconv<128, 256, 64, 0, 2, 2, 2, 32><<<dim3(512), dim3(256), 20800, stream>>>(
        Bb, wb + OW4, Bs[4], A, s_[3], 1.f / 4096.f, s_[4]);

    // L5: deconv 256->128 @32->64. NWN=1 MSUB=1 RT=2 CT=32. grid 512.
    mfconv<256, 128, 32, 1, 1, 1, 2, 32><<<dim3(512), dim3(256), 6336, stream>>>(
        A, wb + OW5, Bs[5], Bb, s_[4], 1.f / 1024.f, s_[5]);

    // L6: deconv 128->64 @64->128. NWN=2 MSUB=2 RT=2 CT=32. grid 512.
    mfconv<128, 64, 64, 1, 2, 2, 2, 32><<<dim3(512), dim3(256), 6336, stream>>>(
        Bb, wb + OW6, Bs[6], A, s_[5], 1.f / 4096.f, s_[6]);

    // L7: deconv 64->32 @128->256. grid 1024.
    mfconv<64, 32, 128, 1, 2, 2, 2, 32><<<dim3(1024), dim3(256), 6336, stream>>>(
        A, wb + OW7, Bs[7], Bb, s_[6], 1.f / 16384.f, s_[7]);

    // L8: deconv 32->16 @256->512. NWN=1 MSUB=1 RT=2 CT=32. grid 4096.
    mfconv<32, 16, 256, 1, 1, 1, 2, 32><<<dim3(4096), dim3(256), 6336, stream>>>(
        Bb, wb + OW8, Bs[8], A, s_[7], 1.f / 65536.f, s_[8]);

    // L9: 7x7 16->3 @512 MFMA + tanh + seg. grid 2048.
    conv7m<<<dim3(2048), dim3(256), 0, stream>>>(
        A, W_[9], Bs[9], s_[8], 1.f / 262144.f, inst, segacc);

    seg_final<<<dim3(1), dim3(96), 0, stream>>>(segacc, means);
    seg_scatter<<<dim3(4096), dim3(256), 0, stream>>>(inst, means, out);
}

// Round 9
// 616.516 us; speedup vs baseline: 10.4356x; 1.2778x over previous
//
#include <hip/hip_runtime.h>
#include <math.h>

#define EPS_F 1e-5f

typedef __attribute__((ext_vector_type(8))) short short8;
typedef __attribute__((ext_vector_type(4))) float f32x4;
typedef __attribute__((ext_vector_type(8))) unsigned short ushort8;
typedef __attribute__((ext_vector_type(4))) unsigned short ushort4v;

__device__ __forceinline__ int reflect512(int v) {
    v = v < 0 ? -v : v;
    return v >= 512 ? 1022 - v : v;
}

// float -> bf16 bits, round-to-nearest-even
__device__ __forceinline__ ushort f2bf(float f) {
    union { float f; unsigned u; } v; v.f = f;
    unsigned r = v.u + 0x7FFFu + ((v.u >> 16) & 1u);
    return (ushort)(r >> 16);
}
__device__ __forceinline__ float bf2f(ushort u) {
    union { unsigned u; float f; } v; v.u = (unsigned)u << 16;
    return v.f;
}

// ---------------------------------------------------------------------------
// Weight prep: fp32 conv(OIHW)/deconv(IOHW) -> bf16 [tap][oc][ci(pad32)].
// ---------------------------------------------------------------------------
template<int CIN, int COUT, bool DEC>
__global__ __launch_bounds__(256) void wprep(
    const float* __restrict__ w, ushort* __restrict__ dst)
{
    constexpr int CIP = ((CIN + 31) / 32) * 32;
    int i = blockIdx.x * 256 + threadIdx.x;
    if (i >= 9 * COUT * CIP) return;
    int ci = i % CIP;
    int oc = (i / CIP) % COUT;
    int t  = i / (CIP * COUT);
    float x = 0.f;
    if (ci < CIN)
        x = DEC ? w[((size_t)ci * COUT + oc) * 9 + t]
                : w[((size_t)oc * CIN + ci) * 9 + t];
    dst[i] = f2bf(x);
}

// ---------------------------------------------------------------------------
// MFMA implicit-GEMM conv (MODE 0: 3x3 s2 p1) / deconv (MODE 1: k3 s2 p1 op1).
// bf16 activations in/out. A-tile staged pixel-major (thread = (pix, ch-octet)
// -> 8 planar bf16 loads -> one contiguous b128 LDS write, conflict-free),
// fused input instance-norm+ReLU. B-frags direct from global bf16 [t][oc][ci].
// Frag layouts (HW-verified): A[m=ln][k=kq*8+j]; B[k][n=ln]; C col=ln, row=kq*4+reg.
// ---------------------------------------------------------------------------
template<int CIN, int COUT, int WIN, int MODE, int NWN, int MSUB, int RT, int CT>
__global__ __launch_bounds__(256) void mfconv(
    const ushort* __restrict__ in, const ushort* __restrict__ wbf,
    const float* __restrict__ bias, ushort* __restrict__ out,
    const float* __restrict__ stats_in, float invHWin,
    float* __restrict__ stats_out)
{
    constexpr int HWIN = WIN * WIN;
    constexpr int WOUT = (MODE == 0) ? (WIN / 2) : (WIN * 2);
    constexpr int HWOUT = WOUT * WOUT;
    constexpr int NMG = 4 / NWN;
    constexpr int NOC = NWN * 16;
    constexpr int M = NMG * MSUB * 16;
    static_assert(M == RT * CT, "tile mismatch");
    constexpr int SPAN = (MODE == 0) ? WOUT : WIN;
    constexpr int XC = SPAN / CT, YC = SPAN / RT;
    constexpr int NG = COUT / NOC;
    constexpr int NR = (MODE == 0) ? (2 * RT + 1) : (RT + 1);
    constexpr int NCO = (MODE == 0) ? (2 * CT + 1) : (CT + 1);
    constexpr int NPIX = NR * NCO;
    constexpr int CIP = ((CIN + 31) / 32) * 32;
    constexpr int NQ = (MODE == 0) ? 1 : 4;

    constexpr int TDY[9] = {1,1,1,0,0,0,0,0,0};
    constexpr int TDX[9] = {1,0,0,1,0,0,1,0,0};
    constexpr int TQ [9] = {3,2,3,1,0,1,3,2,3};

    extern __shared__ ushort sa[];        // [4 ch-octets][NPIX][8] bf16
    __shared__ float mrall[CIN][2];
    __shared__ float sred[4][16][2];

    const int tid = threadIdx.x;
    const int lane = tid & 63, wv = tid >> 6;
    const int ln = lane & 15, kq = lane >> 4;
    const int wn = wv % NWN, wm = wv / NWN;

    int bi = blockIdx.x;
    const int xc = bi % XC; bi /= XC;
    const int yc = bi % YC; bi /= YC;
    const int g  = bi % NG;
    const int b  = bi / NG;

    const int ocg = g * NOC + wn * 16 + ln;
    const float b0 = bias[ocg];
    f32x4 acc[NQ][MSUB];
    #pragma unroll
    for (int q = 0; q < NQ; q++)
        #pragma unroll
        for (int s = 0; s < MSUB; s++)
            acc[q][s] = (f32x4){b0, b0, b0, b0};

    for (int e = tid; e < CIN; e += 256) {
        int c = b * CIN + e;
        float s1 = stats_in[2 * c], s2 = stats_in[2 * c + 1];
        float m = s1 * invHWin;
        mrall[e][0] = m;
        mrall[e][1] = rsqrtf(fmaf(s2, invHWin, -m * m) + EPS_F);
    }

    const ushort* inb = in + (size_t)b * CIN * HWIN;

    for (int c0 = 0; c0 < CIP; c0 += 32) {
        __syncthreads();   // prev tile consumed; mrall visible on iter 0
        for (int e = tid; e < 4 * NPIX; e += 256) {
            int grp = e / NPIX;
            int pix = e - grp * NPIX;
            int pr = pix / NCO, pc = pix - pr * NCO;
            int gy, gx;
            if (MODE == 0) { gy = 2 * (yc * RT) - 1 + pr; gx = 2 * (xc * CT) - 1 + pc; }
            else           { gy = yc * RT + pr;           gx = xc * CT + pc; }
            int cg0 = c0 + grp * 8;
            ushort8 pk;
            #pragma unroll
            for (int j = 0; j < 8; j++) pk[j] = 0;
            if ((unsigned)gy < (unsigned)WIN && (unsigned)gx < (unsigned)WIN && cg0 < CIN) {
                const ushort* p = inb + (size_t)cg0 * HWIN + gy * WIN + gx;
                #pragma unroll
                for (int j = 0; j < 8; j++) {
                    float x = bf2f(p[(size_t)j * HWIN]);
                    x = fmaxf((x - mrall[cg0 + j][0]) * mrall[cg0 + j][1], 0.f);
                    pk[j] = f2bf(x);
                }
            }
            *(ushort8*)&sa[((size_t)grp * NPIX + pix) * 8] = pk;
        }
        __syncthreads();
        #pragma unroll
        for (int t = 0; t < 9; t++) {
            short8 bfr = *(const short8*)&wbf[((size_t)t * COUT + ocg) * CIP + c0 + kq * 8];
            #pragma unroll
            for (int s = 0; s < MSUB; s++) {
                const int mb = wm * MSUB * 16 + s * 16;
                const int r = mb / CT, cb = mb % CT;
                int pr, pc;
                if (MODE == 0) { pr = t / 3 + 2 * r; pc = 2 * (cb + ln) + t % 3; }
                else           { pr = TDY[t] + r;    pc = cb + ln + TDX[t]; }
                short8 afr = *(const short8*)&sa[((kq * NR + pr) * NCO + pc) * 8];
                int qd = (MODE == 0) ? 0 : TQ[t];
                acc[qd][s] = __builtin_amdgcn_mfma_f32_16x16x32_bf16(afr, bfr, acc[qd][s], 0, 0, 0);
            }
        }
    }

    ushort* ob = out + ((size_t)b * COUT + ocg) * HWOUT;
    if (MODE == 0) {
        #pragma unroll
        for (int s = 0; s < MSUB; s++) {
            const int mb = wm * MSUB * 16 + s * 16 + kq * 4;
            const int r = mb / CT, cb = mb % CT;
            ushort4v pk;
            #pragma unroll
            for (int rg = 0; rg < 4; rg++) pk[rg] = f2bf(acc[0][s][rg]);
            *(ushort4v*)&ob[(yc * RT + r) * WOUT + xc * CT + cb] = pk;
        }
    } else {
        #pragma unroll
        for (int dy = 0; dy < 2; dy++) {
            #pragma unroll
            for (int s = 0; s < MSUB; s++) {
                const int mb = wm * MSUB * 16 + s * 16 + kq * 4;
                const int r = mb / CT, cb = mb % CT;
                ushort8 pk;
                #pragma unroll
                for (int rg = 0; rg < 4; rg++) {
                    pk[2 * rg]     = f2bf(acc[2 * dy][s][rg]);
                    pk[2 * rg + 1] = f2bf(acc[2 * dy + 1][s][rg]);
                }
                *(ushort8*)&ob[(2 * (yc * RT + r) + dy) * WOUT + 2 * (xc * CT + cb)] = pk;
            }
        }
    }

    float s1 = 0.f, s2 = 0.f;
    #pragma unroll
    for (int q = 0; q < NQ; q++)
        #pragma unroll
        for (int s = 0; s < MSUB; s++)
            #pragma unroll
            for (int rg = 0; rg < 4; rg++) {
                float v = acc[q][s][rg];
                s1 += v; s2 = fmaf(v, v, s2);
            }
    s1 += __shfl_xor(s1, 16); s2 += __shfl_xor(s2, 16);
    s1 += __shfl_xor(s1, 32); s2 += __shfl_xor(s2, 32);
    if (lane < 16) { sred[wv][lane][0] = s1; sred[wv][lane][1] = s2; }
    __syncthreads();
    if (tid < NOC) {
        int wnn = tid >> 4, oc = tid & 15;
        float t1 = 0.f, t2 = 0.f;
        #pragma unroll
        for (int k = 0; k < NMG; k++) {
            t1 += sred[wnn + k * NWN][oc][0];
            t2 += sred[wnn + k * NWN][oc][1];
        }
        int cix = b * COUT + g * NOC + wnn * 16 + oc;
        atomicAdd(&stats_out[2 * cix],     t1);
        atomicAdd(&stats_out[2 * cix + 1], t2);
    }
}

// ---------------------------------------------------------------------------
// 7x7 reflect conv @512 via MFMA: unified L0/L9.
// K = 49 taps x (8*NCH8) padded ch; NCHUNK chunks of 32.
// L0: CINR=3 (pad 8), fp32 raw input, bf16 out + stats.
// L9: CINR=16, bf16 normed input, fused tanh + segment accumulate.
// Tile: 64x64 out pixels per block, all 16 N-cols (oc) per wave.
// ---------------------------------------------------------------------------
template<int CINR, int COUTR, bool BFIN, bool SEG>
__global__ __launch_bounds__(256) void conv7x(
    const float* __restrict__ inf, const ushort* __restrict__ inb16,
    const float* __restrict__ w7, const float* __restrict__ bias,
    ushort* __restrict__ out,
    const float* __restrict__ stats_in, float invHWin,
    float* __restrict__ stats_out,
    const int* __restrict__ inst, float* __restrict__ segacc)
{
    constexpr int W = 512, HW = 512 * 512;
    constexpr int NCH8 = (CINR + 7) / 8;
    constexpr int TPC = 4 / NCH8;                    // taps per chunk
    constexpr int NCHUNK = (49 + TPC - 1) / TPC;     // 13 or 25

    __shared__ ushort sa[NCH8 * 980 * 8];            // [h][14][70][8]
    __shared__ ushort sw[NCHUNK * 4 * 16 * 8];       // [cn][kq][oc16][8]
    __shared__ float mr[16][2];
    __shared__ float segl[SEG ? 128 : 1];
    __shared__ float sred[4][16][2];

    const int tid = threadIdx.x;
    const int lane = tid & 63, wv = tid >> 6;
    const int ln = lane & 15, kq = lane >> 4;

    int bi = blockIdx.x;
    const int xc = bi & 7;
    const int yr = (bi >> 3) & 63;
    const int b  = bi >> 9;
    const int y0 = yr * 8, x0 = xc * 64;

    if constexpr (SEG) { if (tid < 128) segl[tid] = 0.f; }
    if constexpr (BFIN) {
        if (tid < CINR) {
            int c = b * CINR + tid;
            float s1 = stats_in[2 * c], s2 = stats_in[2 * c + 1];
            float m = s1 * invHWin;
            mr[tid][0] = m;
            mr[tid][1] = rsqrtf(fmaf(s2, invHWin, -m * m) + EPS_F);
        }
    }
    // weights -> bf16 LDS (tiny fp32 source, L1-hot)
    for (int e = tid; e < NCHUNK * 512; e += 256) {
        int j  = e & 7;
        int oc = (e >> 3) & 15;
        int kqe = (e >> 7) & 3;
        int cn = e >> 9;
        int k = cn * 32 + kqe * 8 + j;
        int t = k / (8 * NCH8), ci = k % (8 * NCH8);
        float v = (t < 49 && oc < COUTR && ci < CINR)
                  ? w7[((size_t)oc * CINR + ci) * 49 + t] : 0.f;
        sw[e] = f2bf(v);
    }
    __syncthreads();
    // A-tile: 14x70 pixels, NCH8 channel-octets; pixel-major conflict-free.
    for (int e = tid; e < NCH8 * 980; e += 256) {
        int h = e / 980;
        int pix = e - h * 980;
        int pr = pix / 70, pc = pix - pr * 70;
        int gy = reflect512(y0 - 3 + pr);
        int gx = reflect512(x0 - 3 + pc);
        ushort8 pk;
        #pragma unroll
        for (int j = 0; j < 8; j++) pk[j] = 0;
        if constexpr (BFIN) {
            const ushort* p = inb16 + ((size_t)(b * CINR + h * 8)) * HW + gy * W + gx;
            #pragma unroll
            for (int j = 0; j < 8; j++) {
                float x = bf2f(p[(size_t)j * HW]);
                x = fmaxf((x - mr[h * 8 + j][0]) * mr[h * 8 + j][1], 0.f);
                pk[j] = f2bf(x);
            }
        } else {
            const float* p = inf + ((size_t)(b * CINR)) * HW + gy * W + gx;
            #pragma unroll
            for (int j = 0; j < CINR; j++) pk[j] = f2bf(p[(size_t)j * HW]);
        }
        *(ushort8*)&sa[(size_t)e * 8] = pk;
    }
    __syncthreads();

    const float b0 = (ln < COUTR) ? bias[ln] : 0.f;
    f32x4 acc[8];
    #pragma unroll
    for (int s = 0; s < 8; s++) acc[s] = (f32x4){b0, b0, b0, b0};

    for (int cn = 0; cn < NCHUNK; cn++) {
        short8 bfr = *(const short8*)&sw[((cn * 4 + kq) * 16 + ln) * 8];
        int t = cn * TPC + kq / NCH8;
        int h = (NCH8 == 2) ? (kq & 1) : 0;
        t = t > 48 ? 48 : t;
        const int ty = t / 7, tx = t - ty * 7;
        #pragma unroll
        for (int s = 0; s < 8; s++) {
            int m = wv * 128 + s * 16 + ln;
            int r = m >> 6, c = m & 63;
            short8 afr = *(const short8*)&sa[((h * 14 + r + ty) * 70 + c + tx) * 8];
            acc[s] = __builtin_amdgcn_mfma_f32_16x16x32_bf16(afr, bfr, acc[s], 0, 0, 0);
        }
    }

    if constexpr (SEG) {
        // tanh + segment accumulate. C: col(oc)=ln, pixel m = kq*4+reg.
        if (ln < 3) {
            const int* ib = inst + ((size_t)b << 18);
            #pragma unroll
            for (int s = 0; s < 8; s++) {
                #pragma unroll
                for (int rg = 0; rg < 4; rg++) {
                    int m = wv * 128 + s * 16 + kq * 4 + rg;
                    int r = m >> 6, c = m & 63;
                    int lab = ib[(y0 + r) * W + x0 + c] & 31;
                    float val = tanhf(acc[s][rg]);
                    atomicAdd(&segl[lab * 4 + ln], val);
                    if (ln == 0) atomicAdd(&segl[lab * 4 + 3], 1.f);
                }
            }
        }
        __syncthreads();
        if (tid < 128) {
            float v = segl[tid];
            if (v != 0.f) atomicAdd(&segacc[tid], v);
        }
    } else {
        // bf16 store + stats. oc = ln plane.
        ushort* ob = out + ((size_t)(b * 16 + ln)) * HW;
        float s1 = 0.f, s2 = 0.f;
        #pragma unroll
        for (int s = 0; s < 8; s++) {
            int m0 = wv * 128 + s * 16 + kq * 4;
            int r = m0 >> 6, c = m0 & 63;
            ushort4v pk;
            #pragma unroll
            for (int rg = 0; rg < 4; rg++) {
                float v = acc[s][rg];
                pk[rg] = f2bf(v);
                s1 += v; s2 = fmaf(v, v, s2);
            }
            *(ushort4v*)&ob[(y0 + r) * W + x0 + c] = pk;
        }
        s1 += __shfl_xor(s1, 16); s2 += __shfl_xor(s2, 16);
        s1 += __shfl_xor(s1, 32); s2 += __shfl_xor(s2, 32);
        if (lane < 16) { sred[wv][lane][0] = s1; sred[wv][lane][1] = s2; }
        __syncthreads();
        if (tid < 16) {
            float t1 = 0.f, t2 = 0.f;
            #pragma unroll
            for (int k = 0; k < 4; k++) { t1 += sred[k][tid][0]; t2 += sred[k][tid][1]; }
            int cix = b * 16 + tid;
            atomicAdd(&stats_out[2 * cix],     t1);
            atomicAdd(&stats_out[2 * cix + 1], t2);
        }
    }
}

// ---------------------------------------------------------------------------
// Segment finalize + scatter.
// ---------------------------------------------------------------------------
#define HW9 262144
__global__ void seg_final(const float* __restrict__ acc, float* __restrict__ means)
{
    int i = threadIdx.x;
    if (i < 96) {
        int s = i / 3, c = i - s * 3;
        means[i] = acc[s * 4 + c] / fmaxf(acc[s * 4 + 3], 1.f);
    }
}

__global__ __launch_bounds__(256) void seg_scatter(
    const int* __restrict__ inst, const float* __restrict__ means,
    float* __restrict__ out)
{
    int p   = blockIdx.x * 256 + threadIdx.x;
    int b   = p >> 18;
    int r   = p & (HW9 - 1);
    int lab = inst[p] & 31;
    float* ob = out + (size_t)b * 3 * HW9;
    ob[r]           = means[lab * 3 + 0];
    ob[HW9 + r]     = means[lab * 3 + 1];
    ob[2 * HW9 + r] = means[lab * 3 + 2];
}

// ---------------------------------------------------------------------------
// Launch.
// ---------------------------------------------------------------------------
extern "C" void kernel_launch(void* const* d_in, const int* in_sizes, int n_in,
                              void* d_out, int out_size, void* d_ws, size_t ws_size,
                              hipStream_t stream)
{
    const float* x_in = (const float*)d_in[0];
    const int*   inst = (const int*)d_in[1];
    const float* W_[10];
    const float* Bs[10];
    for (int i = 0; i < 10; i++) {
        W_[i] = (const float*)d_in[2 + 2 * i];
        Bs[i] = (const float*)d_in[3 + 2 * i];
    }
    float* out = (float*)d_out;

    // bf16 activation ping-pong + fp32 stats + bf16 weights.
    ushort* Ab  = (ushort*)d_ws;            // 16,777,216 el (33.5 MB)
    ushort* Bb2 = Ab + (size_t)16777216;    //  8,388,608 el (16.8 MB)
    float*  st  = (float*)(Bb2 + (size_t)8388608);
    const int coff[9] = {0, 128, 384, 896, 1920, 3968, 4992, 5504, 5760};
    float* s_[9];
    for (int i = 0; i < 9; i++) s_[i] = st + coff[i];
    float* segacc = st + 5888;
    float* means  = st + 6016;
    ushort* wb = (ushort*)(st + 8192);
    const size_t OW1 = 0, OW2 = 9216, OW3 = 27648, OW4 = 101376,
                 OW5 = 396288, OW6 = 691200, OW7 = 764928, OW8 = 783360;

    hipMemsetAsync(st, 0, 6016 * sizeof(float), stream);

    wprep<16,  32,  false><<<dim3((9*32*32   + 255)/256), dim3(256), 0, stream>>>(W_[1], wb + OW1);
    wprep<32,  64,  false><<<dim3((9*64*32   + 255)/256), dim3(256), 0, stream>>>(W_[2], wb + OW2);
    wprep<64,  128, false><<<dim3((9*128*64  + 255)/256), dim3(256), 0, stream>>>(W_[3], wb + OW3);
    wprep<128, 256, false><<<dim3((9*256*128 + 255)/256), dim3(256), 0, stream>>>(W_[4], wb + OW4);
    wprep<256, 128, true ><<<dim3((9*128*256 + 255)/256), dim3(256), 0, stream>>>(W_[5], wb + OW5);
    wprep<128, 64,  true ><<<dim3((9*64*128  + 255)/256), dim3(256), 0, stream>>>(W_[6], wb + OW6);
    wprep<64,  32,  true ><<<dim3((9*32*64   + 255)/256), dim3(256), 0, stream>>>(W_[7], wb + OW7);
    wprep<32,  16,  true ><<<dim3((9*16*32   + 255)/256), dim3(256), 0, stream>>>(W_[8], wb + OW8);

    // L0: 7x7 3->16 @512 MFMA, raw fp32 input, bf16 out + stats. grid 2048.
    conv7x<3, 16, false, false><<<dim3(2048), dim3(256), 0, stream>>>(
        x_in, nullptr, W_[0], Bs[0], Ab, nullptr, 0.f, s_[0], nullptr, nullptr);

    // L1: conv 16->32 @512->256.
    mfconv<16, 32, 512, 0, 2, 4, 4, 32><<<dim3(2048), dim3(256), 37440, stream>>>(
        Ab, wb + OW1, Bs[1], Bb2, s_[0], 1.f / 262144.f, s_[1]);

    // L2: conv 32->64 @256->128.
    mfconv<32, 64, 256, 0, 2, 4, 4, 32><<<dim3(1024), dim3(256), 37440, stream>>>(
        Bb2, wb + OW2, Bs[2], Ab, s_[1], 1.f / 65536.f, s_[2]);

    // L3: conv 64->128 @128->64.
    mfconv<64, 128, 128, 0, 2, 4, 4, 32><<<dim3(512), dim3(256), 37440, stream>>>(
        Ab, wb + OW3, Bs[3], Bb2, s_[2], 1.f / 16384.f, s_[3]);

    // L4: conv 128->256 @64->32.
    mfconv<128, 256, 64, 0, 2, 2, 2, 32><<<dim3(512), dim3(256), 20800, stream>>>(
        Bb2, wb + OW4, Bs[4], Ab, s_[3], 1.f / 4096.f, s_[4]);

    // L5: deconv 256->128 @32->64.
    mfconv<256, 128, 32, 1, 1, 1, 2, 32><<<dim3(512), dim3(256), 6336, stream>>>(
        Ab, wb + OW5, Bs[5], Bb2, s_[4], 1.f / 1024.f, s_[5]);

    // L6: deconv 128->64 @64->128.
    mfconv<128, 64, 64, 1, 2, 2, 2, 32><<<dim3(512), dim3(256), 6336, stream>>>(
        Bb2, wb + OW6, Bs[6], Ab, s_[5], 1.f / 4096.f, s_[6]);

    // L7: deconv 64->32 @128->256.
    mfconv<64, 32, 128, 1, 2, 2, 2, 32><<<dim3(1024), dim3(256), 6336, stream>>>(
        Ab, wb + OW7, Bs[7], Bb2, s_[6], 1.f / 16384.f, s_[7]);

    // L8: deconv 32->16 @256->512.
    mfconv<32, 16, 256, 1, 1, 1, 2, 32><<<dim3(4096), dim3(256), 6336, stream>>>(
        Bb2, wb + OW8, Bs[8], Ab, s_[7], 1.f / 65536.f, s_[8]);

    // L9: 7x7 16->3 @512 MFMA + norm-in + tanh + seg. grid 2048.
    conv7x<16, 3, true, true><<<dim3(2048), dim3(256), 0, stream>>>(
        nullptr, Ab, W_[9], Bs[9], nullptr, s_[8], 1.f / 262144.f, nullptr, inst, segacc);

    seg_final<<<dim3(1), dim3(96), 0, stream>>>(segacc, means);
    seg_scatter<<<dim3(4096), dim3(256), 0, stream>>>(inst, means, out);
}

// Round 10
// 556.215 us; speedup vs baseline: 11.5669x; 1.1084x over previous
//
#include <hip/hip_runtime.h>
#include <math.h>

#define EPS_F 1e-5f

typedef __attribute__((ext_vector_type(8))) short short8;
typedef __attribute__((ext_vector_type(4))) float f32x4;
typedef __attribute__((ext_vector_type(8))) unsigned short ushort8;

__device__ __forceinline__ int reflect512(int v) {
    v = v < 0 ? -v : v;
    return v >= 512 ? 1022 - v : v;
}

// float -> bf16 bits, round-to-nearest-even
__device__ __forceinline__ ushort f2bf(float f) {
    union { float f; unsigned u; } v; v.f = f;
    unsigned r = v.u + 0x7FFFu + ((v.u >> 16) & 1u);
    return (ushort)(r >> 16);
}
__device__ __forceinline__ float bf2f(ushort u) {
    union { unsigned u; float f; } v; v.u = (unsigned)u << 16;
    return v.f;
}

// ---------------------------------------------------------------------------
// Weight prep (mid layers): fp32 conv(OIHW)/deconv(IOHW) -> bf16
// [tap][oc][ci(pad32)].
// ---------------------------------------------------------------------------
template<int CIN, int COUT, bool DEC>
__global__ __launch_bounds__(256) void wprep(
    const float* __restrict__ w, ushort* __restrict__ dst)
{
    constexpr int CIP = ((CIN + 31) / 32) * 32;
    int i = blockIdx.x * 256 + threadIdx.x;
    if (i >= 9 * COUT * CIP) return;
    int ci = i % CIP;
    int oc = (i / CIP) % COUT;
    int t  = i / (CIP * COUT);
    float x = 0.f;
    if (ci < CIN)
        x = DEC ? w[((size_t)ci * COUT + oc) * 9 + t]
                : w[((size_t)oc * CIN + ci) * 9 + t];
    dst[i] = f2bf(x);
}

// Weight prep for 7x7 layers: dst [chunk][kq][oc16][8] bf16.
// L0: k = tap*8 + ci(8, CIN=3 pad);  L9: k = tap*16 + ci(16).
template<bool L9>
__global__ __launch_bounds__(256) void wprep7(
    const float* __restrict__ w, ushort* __restrict__ dst)
{
    constexpr int NCHUNK = L9 ? 25 : 13;
    constexpr int CINR   = L9 ? 16 : 3;
    constexpr int COUTR  = L9 ? 3  : 16;
    int i = blockIdx.x * 256 + threadIdx.x;
    if (i >= NCHUNK * 512) return;
    int j   = i & 7;
    int oc  = (i >> 3) & 15;
    int kqe = (i >> 7) & 3;
    int cn  = i >> 9;
    int k = cn * 32 + kqe * 8 + j;
    int t, ci;
    if (L9) { t = k >> 4; ci = k & 15; } else { t = k >> 3; ci = k & 7; }
    float x = (t < 49 && oc < COUTR && ci < CINR)
              ? w[((size_t)oc * CINR + ci) * 49 + t] : 0.f;
    dst[i] = f2bf(x);
}

// ---------------------------------------------------------------------------
// MFMA implicit-GEMM conv (MODE 0: 3x3 s2 p1) / deconv (MODE 1: k3 s2 p1 op1).
// NHWC bf16 activations: in [b][pix][CIN], out [b][pix][COUT].
// A-tile in LDS [pix][36] (72 B row stride: bank-stride 2 -> conflict-free);
// staging = one 16 B NHWC load + reg-preloaded norm per ch-octet.
// B-frags direct from global [t][oc][ci(pad32)] bf16.
// Frags (HW-verified): A[m=ln][k=kq*8+j]; B[k][n=ln]; C col=ln,row=kq*4+reg.
// ---------------------------------------------------------------------------
template<int CIN, int COUT, int WIN, int MODE, int NWN, int MSUB, int RT, int CT>
__global__ __launch_bounds__(256) void mfconv(
    const ushort* __restrict__ in, const ushort* __restrict__ wbf,
    const float* __restrict__ bias, ushort* __restrict__ out,
    const float* __restrict__ stats_in, float invHWin,
    float* __restrict__ stats_out)
{
    constexpr int HWIN = WIN * WIN;
    constexpr int WOUT = (MODE == 0) ? (WIN / 2) : (WIN * 2);
    constexpr int HWOUT = WOUT * WOUT;
    constexpr int NMG = 4 / NWN;
    constexpr int NOC = NWN * 16;
    constexpr int M = NMG * MSUB * 16;
    static_assert(M == RT * CT, "tile mismatch");
    constexpr int SPAN = (MODE == 0) ? WOUT : WIN;
    constexpr int XC = SPAN / CT, YC = SPAN / RT;
    constexpr int NG = COUT / NOC;
    constexpr int NR = (MODE == 0) ? (2 * RT + 1) : (RT + 1);
    constexpr int NCO = (MODE == 0) ? (2 * CT + 1) : (CT + 1);
    constexpr int NPIX = NR * NCO;
    constexpr int CIP = ((CIN + 31) / 32) * 32;
    constexpr int NQ = (MODE == 0) ? 1 : 4;
    constexpr int LPW = 36;   // LDS row stride (ushorts)

    constexpr int TDY[9] = {1,1,1,0,0,0,0,0,0};
    constexpr int TDX[9] = {1,0,0,1,0,0,1,0,0};
    constexpr int TQ [9] = {3,2,3,1,0,1,3,2,3};

    extern __shared__ ushort sa[];        // [NPIX][36]
    __shared__ float mrall[CIP][2];
    __shared__ float sred[4][16][2];

    const int tid = threadIdx.x;
    const int lane = tid & 63, wv = tid >> 6;
    const int ln = lane & 15, kq = lane >> 4;
    const int wn = wv % NWN, wm = wv / NWN;
    const int grp = tid & 3;              // fixed channel-octet per thread

    int bi = blockIdx.x;
    const int xc = bi % XC; bi /= XC;
    const int yc = bi % YC; bi /= YC;
    const int g  = bi % NG;
    const int b  = bi / NG;

    const int ocg = g * NOC + wn * 16 + ln;
    const float b0 = bias[ocg];
    f32x4 acc[NQ][MSUB];
    #pragma unroll
    for (int q = 0; q < NQ; q++)
        #pragma unroll
        for (int s = 0; s < MSUB; s++)
            acc[q][s] = (f32x4){b0, b0, b0, b0};

    for (int e = tid; e < CIP; e += 256) {
        float m = 0.f, r = 0.f;
        if (e < CIN) {
            int c = b * CIN + e;
            float s1 = stats_in[2 * c], s2 = stats_in[2 * c + 1];
            m = s1 * invHWin;
            r = rsqrtf(fmaf(s2, invHWin, -m * m) + EPS_F);
        }
        mrall[e][0] = m; mrall[e][1] = r;
    }

    const ushort* inb = in + (size_t)b * HWIN * CIN;

    for (int c0 = 0; c0 < CIP; c0 += 32) {
        __syncthreads();   // prev tile consumed; mrall visible on iter 0
        const int ch0 = c0 + 8 * grp;
        float m8[8], r8[8];
        #pragma unroll
        for (int j = 0; j < 8; j++) { m8[j] = mrall[ch0 + j][0]; r8[j] = mrall[ch0 + j][1]; }
        for (int pix = tid >> 2; pix < NPIX; pix += 64) {
            int pr = pix / NCO, pc = pix - pr * NCO;
            int gy, gx;
            if (MODE == 0) { gy = 2 * (yc * RT) - 1 + pr; gx = 2 * (xc * CT) - 1 + pc; }
            else           { gy = yc * RT + pr;           gx = xc * CT + pc; }
            ushort8 pk;
            #pragma unroll
            for (int j = 0; j < 8; j++) pk[j] = 0;
            if ((unsigned)gy < (unsigned)WIN && (unsigned)gx < (unsigned)WIN && ch0 < CIN) {
                ushort8 raw = *(const ushort8*)(inb + (size_t)(gy * WIN + gx) * CIN + ch0);
                #pragma unroll
                for (int j = 0; j < 8; j++) {
                    float x = bf2f(raw[j]);
                    pk[j] = f2bf(fmaxf((x - m8[j]) * r8[j], 0.f));
                }
            }
            *(ushort8*)&sa[pix * LPW + grp * 8] = pk;
        }
        __syncthreads();
        #pragma unroll
        for (int t = 0; t < 9; t++) {
            short8 bfr = *(const short8*)&wbf[((size_t)t * COUT + ocg) * CIP + c0 + kq * 8];
            #pragma unroll
            for (int s = 0; s < MSUB; s++) {
                const int mb = wm * MSUB * 16 + s * 16;
                const int r = mb / CT, cb = mb % CT;
                int pix;
                if (MODE == 0) pix = (t / 3 + 2 * r) * NCO + 2 * (cb + ln) + t % 3;
                else           pix = (TDY[t] + r) * NCO + cb + ln + TDX[t];
                short8 afr = *(const short8*)&sa[pix * LPW + kq * 8];
                int qd = (MODE == 0) ? 0 : TQ[t];
                acc[qd][s] = __builtin_amdgcn_mfma_f32_16x16x32_bf16(afr, bfr, acc[qd][s], 0, 0, 0);
            }
        }
    }

    // NHWC epilogue: lane ln = oc (2 B stores, oc-contiguous across lanes).
    ushort* ob = out + (size_t)b * HWOUT * COUT + ocg;
    if (MODE == 0) {
        #pragma unroll
        for (int s = 0; s < MSUB; s++) {
            #pragma unroll
            for (int rg = 0; rg < 4; rg++) {
                const int m = wm * MSUB * 16 + s * 16 + kq * 4 + rg;
                const int r = m / CT, c = m % CT;
                const int opix = (yc * RT + r) * WOUT + xc * CT + c;
                ob[(size_t)opix * COUT] = f2bf(acc[0][s][rg]);
            }
        }
    } else {
        #pragma unroll
        for (int q = 0; q < 4; q++) {
            const int dy = q >> 1, dx = q & 1;
            #pragma unroll
            for (int s = 0; s < MSUB; s++) {
                #pragma unroll
                for (int rg = 0; rg < 4; rg++) {
                    const int m = wm * MSUB * 16 + s * 16 + kq * 4 + rg;
                    const int r = m / CT, c = m % CT;
                    const int opix = (2 * (yc * RT + r) + dy) * WOUT + 2 * (xc * CT + c) + dx;
                    ob[(size_t)opix * COUT] = f2bf(acc[q][s][rg]);
                }
            }
        }
    }

    float s1 = 0.f, s2 = 0.f;
    #pragma unroll
    for (int q = 0; q < NQ; q++)
        #pragma unroll
        for (int s = 0; s < MSUB; s++)
            #pragma unroll
            for (int rg = 0; rg < 4; rg++) {
                float v = acc[q][s][rg];
                s1 += v; s2 = fmaf(v, v, s2);
            }
    s1 += __shfl_xor(s1, 16); s2 += __shfl_xor(s2, 16);
    s1 += __shfl_xor(s1, 32); s2 += __shfl_xor(s2, 32);
    if (lane < 16) { sred[wv][lane][0] = s1; sred[wv][lane][1] = s2; }
    __syncthreads();
    if (tid < NOC) {
        int wnn = tid >> 4, oc = tid & 15;
        float t1 = 0.f, t2 = 0.f;
        #pragma unroll
        for (int k = 0; k < NMG; k++) {
            t1 += sred[wnn + k * NWN][oc][0];
            t2 += sred[wnn + k * NWN][oc][1];
        }
        int cix = b * COUT + g * NOC + wnn * 16 + oc;
        atomicAdd(&stats_out[2 * cix],     t1);
        atomicAdd(&stats_out[2 * cix + 1], t2);
    }
}

// ---------------------------------------------------------------------------
// 7x7 reflect conv @512 via MFMA. Tile: 8x64 out pixels per block.
// L0 (BFIN=false): fp32 NCHW input (3 ch), NHWC bf16 out + stats.
// L9 (BFIN=true, SEG): NHWC bf16 input (16 ch), fused norm+tanh+seg.
// Weights pre-packed in global [chunk][kq][oc16][8].
// ---------------------------------------------------------------------------
template<bool BFIN, bool SEG>
__global__ __launch_bounds__(256) void conv7x(
    const float* __restrict__ inf, const ushort* __restrict__ inb16,
    const ushort* __restrict__ wpk, const float* __restrict__ bias,
    ushort* __restrict__ out,
    const float* __restrict__ stats_in, float invHWin,
    float* __restrict__ stats_out,
    const int* __restrict__ inst, float* __restrict__ segacc)
{
    constexpr int W = 512, HW = 512 * 512;
    constexpr int NCHUNK = BFIN ? 25 : 13;
    constexpr int STR = BFIN ? 18 : 12;     // LDS row stride (ushorts)

    __shared__ ushort sa[980 * STR];
    __shared__ float mr[16][2];
    __shared__ float segl[SEG ? 128 : 1];
    __shared__ float sred[4][16][2];

    const int tid = threadIdx.x;
    const int lane = tid & 63, wv = tid >> 6;
    const int ln = lane & 15, kq = lane >> 4;

    int bi = blockIdx.x;
    const int xc = bi & 7;
    const int yr = (bi >> 3) & 63;
    const int b  = bi >> 9;
    const int y0 = yr * 8, x0 = xc * 64;

    if constexpr (SEG) { if (tid < 128) segl[tid] = 0.f; }
    if constexpr (BFIN) {
        if (tid < 16) {
            int c = b * 16 + tid;
            float s1 = stats_in[2 * c], s2 = stats_in[2 * c + 1];
            float m = s1 * invHWin;
            mr[tid][0] = m;
            mr[tid][1] = rsqrtf(fmaf(s2, invHWin, -m * m) + EPS_F);
        }
        __syncthreads();
        const int h = tid & 1;
        float m8[8], r8[8];
        #pragma unroll
        for (int j = 0; j < 8; j++) { m8[j] = mr[8 * h + j][0]; r8[j] = mr[8 * h + j][1]; }
        const ushort* inb = inb16 + (size_t)b * HW * 16;
        for (int pix = tid >> 1; pix < 980; pix += 128) {
            int pr = pix / 70, pc = pix - pr * 70;
            int gy = reflect512(y0 - 3 + pr);
            int gx = reflect512(x0 - 3 + pc);
            ushort8 raw = *(const ushort8*)(inb + (size_t)(gy * W + gx) * 16 + 8 * h);
            ushort8 pk;
            #pragma unroll
            for (int j = 0; j < 8; j++) {
                float x = bf2f(raw[j]);
                pk[j] = f2bf(fmaxf((x - m8[j]) * r8[j], 0.f));
            }
            *(ushort8*)&sa[pix * STR + 8 * h] = pk;
        }
    } else {
        const float* p0 = inf + (size_t)b * 3 * HW;
        for (int pix = tid; pix < 980; pix += 256) {
            int pr = pix / 70, pc = pix - pr * 70;
            int gy = reflect512(y0 - 3 + pr);
            int gx = reflect512(x0 - 3 + pc);
            const float* p = p0 + gy * W + gx;
            ushort8 pk;
            #pragma unroll
            for (int j = 0; j < 8; j++) pk[j] = 0;
            pk[0] = f2bf(p[0]); pk[1] = f2bf(p[HW]); pk[2] = f2bf(p[2 * (size_t)HW]);
            *(ushort8*)&sa[pix * STR] = pk;
        }
    }
    __syncthreads();

    const float b0 = (ln < (BFIN ? 3 : 16)) ? bias[ln] : 0.f;
    f32x4 acc[8];
    #pragma unroll
    for (int s = 0; s < 8; s++) acc[s] = (f32x4){b0, b0, b0, b0};

    for (int cn = 0; cn < NCHUNK; cn++) {
        short8 bfr = *(const short8*)&wpk[((size_t)(cn * 4 + kq) * 16 + ln) * 8];
        int t, off;
        if constexpr (BFIN) { t = 2 * cn + (kq >> 1); off = (kq & 1) * 8; }
        else                { t = 4 * cn + kq;        off = 0; }
        t = t > 48 ? 48 : t;
        const int ty = t / 7, tx = t - ty * 7;
        #pragma unroll
        for (int s = 0; s < 8; s++) {
            int m = wv * 128 + s * 16 + ln;
            int r = m >> 6, c = m & 63;
            short8 afr = *(const short8*)&sa[((r + ty) * 70 + c + tx) * STR + off];
            acc[s] = __builtin_amdgcn_mfma_f32_16x16x32_bf16(afr, bfr, acc[s], 0, 0, 0);
        }
    }

    if constexpr (SEG) {
        if (ln < 3) {
            const int* ib = inst + ((size_t)b << 18);
            #pragma unroll
            for (int s = 0; s < 8; s++) {
                #pragma unroll
                for (int rg = 0; rg < 4; rg++) {
                    int m = wv * 128 + s * 16 + kq * 4 + rg;
                    int r = m >> 6, c = m & 63;
                    int lab = ib[(y0 + r) * W + x0 + c] & 31;
                    float val = tanhf(acc[s][rg]);
                    atomicAdd(&segl[lab * 4 + ln], val);
                    if (ln == 0) atomicAdd(&segl[lab * 4 + 3], 1.f);
                }
            }
        }
        __syncthreads();
        if (tid < 128) {
            float v = segl[tid];
            if (v != 0.f) atomicAdd(&segacc[tid], v);
        }
    } else {
        // NHWC store: lane ln = oc plane of 16.
        ushort* ob = out + (size_t)b * HW * 16 + ln;
        float s1 = 0.f, s2 = 0.f;
        #pragma unroll
        for (int s = 0; s < 8; s++) {
            #pragma unroll
            for (int rg = 0; rg < 4; rg++) {
                int m = wv * 128 + s * 16 + kq * 4 + rg;
                int r = m >> 6, c = m & 63;
                float v = acc[s][rg];
                ob[(size_t)((y0 + r) * W + x0 + c) * 16] = f2bf(v);
                s1 += v; s2 = fmaf(v, v, s2);
            }
        }
        s1 += __shfl_xor(s1, 16); s2 += __shfl_xor(s2, 16);
        s1 += __shfl_xor(s1, 32); s2 += __shfl_xor(s2, 32);
        if (lane < 16) { sred[wv][lane][0] = s1; sred[wv][lane][1] = s2; }
        __syncthreads();
        if (tid < 16) {
            float t1 = 0.f, t2 = 0.f;
            #pragma unroll
            for (int k = 0; k < 4; k++) { t1 += sred[k][tid][0]; t2 += sred[k][tid][1]; }
            int cix = b * 16 + tid;
            atomicAdd(&stats_out[2 * cix],     t1);
            atomicAdd(&stats_out[2 * cix + 1], t2);
        }
    }
}

// ---------------------------------------------------------------------------
// Segment finalize + scatter.
// ---------------------------------------------------------------------------
#define HW9 262144
__global__ void seg_final(const float* __restrict__ acc, float* __restrict__ means)
{
    int i = threadIdx.x;
    if (i < 96) {
        int s = i / 3, c = i - s * 3;
        means[i] = acc[s * 4 + c] / fmaxf(acc[s * 4 + 3], 1.f);
    }
}

__global__ __launch_bounds__(256) void seg_scatter(
    const int* __restrict__ inst, const float* __restrict__ means,
    float* __restrict__ out)
{
    int p   = blockIdx.x * 256 + threadIdx.x;
    int b   = p >> 18;
    int r   = p & (HW9 - 1);
    int lab = inst[p] & 31;
    float* ob = out + (size_t)b * 3 * HW9;
    ob[r]           = means[lab * 3 + 0];
    ob[HW9 + r]     = means[lab * 3 + 1];
    ob[2 * HW9 + r] = means[lab * 3 + 2];
}

// ---------------------------------------------------------------------------
// Launch.
// ---------------------------------------------------------------------------
extern "C" void kernel_launch(void* const* d_in, const int* in_sizes, int n_in,
                              void* d_out, int out_size, void* d_ws, size_t ws_size,
                              hipStream_t stream)
{
    const float* x_in = (const float*)d_in[0];
    const int*   inst = (const int*)d_in[1];
    const float* W_[10];
    const float* Bs[10];
    for (int i = 0; i < 10; i++) {
        W_[i] = (const float*)d_in[2 + 2 * i];
        Bs[i] = (const float*)d_in[3 + 2 * i];
    }
    float* out = (float*)d_out;

    // NHWC bf16 activation ping-pong + fp32 stats + bf16 weights.
    ushort* Ab  = (ushort*)d_ws;            // 16,777,216 el
    ushort* Bb2 = Ab + (size_t)16777216;    //  8,388,608 el
    float*  st  = (float*)(Bb2 + (size_t)8388608);
    const int coff[9] = {0, 128, 384, 896, 1920, 3968, 4992, 5504, 5760};
    float* s_[9];
    for (int i = 0; i < 9; i++) s_[i] = st + coff[i];
    float* segacc = st + 5888;
    float* means  = st + 6016;
    ushort* wb = (ushort*)(st + 8192);
    const size_t OW1 = 0, OW2 = 9216, OW3 = 27648, OW4 = 101376,
                 OW5 = 396288, OW6 = 691200, OW7 = 764928, OW8 = 783360;
    ushort* wb0 = wb + 790000;
    ushort* wb9 = wb0 + 6656;

    hipMemsetAsync(st, 0, 6016 * sizeof(float), stream);

    wprep<16,  32,  false><<<dim3((9*32*32   + 255)/256), dim3(256), 0, stream>>>(W_[1], wb + OW1);
    wprep<32,  64,  false><<<dim3((9*64*32   + 255)/256), dim3(256), 0, stream>>>(W_[2], wb + OW2);
    wprep<64,  128, false><<<dim3((9*128*64  + 255)/256), dim3(256), 0, stream>>>(W_[3], wb + OW3);
    wprep<128, 256, false><<<dim3((9*256*128 + 255)/256), dim3(256), 0, stream>>>(W_[4], wb + OW4);
    wprep<256, 128, true ><<<dim3((9*128*256 + 255)/256), dim3(256), 0, stream>>>(W_[5], wb + OW5);
    wprep<128, 64,  true ><<<dim3((9*64*128  + 255)/256), dim3(256), 0, stream>>>(W_[6], wb + OW6);
    wprep<64,  32,  true ><<<dim3((9*32*64   + 255)/256), dim3(256), 0, stream>>>(W_[7], wb + OW7);
    wprep<32,  16,  true ><<<dim3((9*16*32   + 255)/256), dim3(256), 0, stream>>>(W_[8], wb + OW8);
    wprep7<false><<<dim3(26), dim3(256), 0, stream>>>(W_[0], wb0);
    wprep7<true ><<<dim3(50), dim3(256), 0, stream>>>(W_[9], wb9);

    // L0: 7x7 3->16 @512, fp32 NCHW in -> NHWC bf16 out + stats. grid 2048.
    conv7x<false, false><<<dim3(2048), dim3(256), 0, stream>>>(
        x_in, nullptr, wb0, Bs[0], Ab, nullptr, 0.f, s_[0], nullptr, nullptr);

    // L1: conv 16->32 @512->256. grid 2048, LDS 42120.
    mfconv<16, 32, 512, 0, 2, 4, 4, 32><<<dim3(2048), dim3(256), 42120, stream>>>(
        Ab, wb + OW1, Bs[1], Bb2, s_[0], 1.f / 262144.f, s_[1]);

    // L2: conv 32->64 @256->128. grid 1024.
    mfconv<32, 64, 256, 0, 2, 4, 4, 32><<<dim3(1024), dim3(256), 42120, stream>>>(
        Bb2, wb + OW2, Bs[2], Ab, s_[1], 1.f / 65536.f, s_[2]);

    // L3: conv 64->128 @128->64. grid 512.
    mfconv<64, 128, 128, 0, 2, 4, 4, 32><<<dim3(512), dim3(256), 42120, stream>>>(
        Ab, wb + OW3, Bs[3], Bb2, s_[2], 1.f / 16384.f, s_[3]);

    // L4: conv 128->256 @64->32. grid 512, LDS 23400.
    mfconv<128, 256, 64, 0, 2, 2, 2, 32><<<dim3(512), dim3(256), 23400, stream>>>(
        Bb2, wb + OW4, Bs[4], Ab, s_[3], 1.f / 4096.f, s_[4]);

    // L5: deconv 256->128 @32->64. grid 512, LDS 7128.
    mfconv<256, 128, 32, 1, 1, 1, 2, 32><<<dim3(512), dim3(256), 7128, stream>>>(
        Ab, wb + OW5, Bs[5], Bb2, s_[4], 1.f / 1024.f, s_[5]);

    // L6: deconv 128->64 @64->128. grid 512.
    mfconv<128, 64, 64, 1, 2, 2, 2, 32><<<dim3(512), dim3(256), 7128, stream>>>(
        Bb2, wb + OW6, Bs[6], Ab, s_[5], 1.f / 4096.f, s_[6]);

    // L7: deconv 64->32 @128->256. grid 1024.
    mfconv<64, 32, 128, 1, 2, 2, 2, 32><<<dim3(1024), dim3(256), 7128, stream>>>(
        Ab, wb + OW7, Bs[7], Bb2, s_[6], 1.f / 16384.f, s_[7]);

    // L8: deconv 32->16 @256->512. grid 4096.
    mfconv<32, 16, 256, 1, 1, 1, 2, 32><<<dim3(4096), dim3(256), 7128, stream>>>(
        Bb2, wb + OW8, Bs[8], Ab, s_[7], 1.f / 65536.f, s_[8]);

    // L9: 7x7 16->3 @512, NHWC in + norm + tanh + seg. grid 2048.
    conv7x<true, true><<<dim3(2048), dim3(256), 0, stream>>>(
        nullptr, Ab, wb9, Bs[9], nullptr, s_[8], 1.f / 262144.f, nullptr, inst, segacc);

    seg_final<<<dim3(1), dim3(96), 0, stream>>>(segacc, means);
    seg_scatter<<<dim3(4096), dim3(256), 0, stream>>>(inst, means, out);
}

// Round 11
// 528.554 us; speedup vs baseline: 12.1723x; 1.0523x over previous
//
#include <hip/hip_runtime.h>
#include <math.h>

#define EPS_F 1e-5f

typedef __attribute__((ext_vector_type(8))) short short8;
typedef __attribute__((ext_vector_type(4))) float f32x4;
typedef __attribute__((ext_vector_type(8))) unsigned short ushort8;

__device__ __forceinline__ int reflect512(int v) {
    v = v < 0 ? -v : v;
    return v >= 512 ? 1022 - v : v;
}

// float -> bf16 bits, round-to-nearest-even
__device__ __forceinline__ ushort f2bf(float f) {
    union { float f; unsigned u; } v; v.f = f;
    unsigned r = v.u + 0x7FFFu + ((v.u >> 16) & 1u);
    return (ushort)(r >> 16);
}
__device__ __forceinline__ float bf2f(ushort u) {
    union { unsigned u; float f; } v; v.u = (unsigned)u << 16;
    return v.f;
}

// ---------------------------------------------------------------------------
// Weight prep (mid layers): fp32 conv(OIHW)/deconv(IOHW) -> bf16
// [tap][oc][ci(pad32)].
// ---------------------------------------------------------------------------
template<int CIN, int COUT, bool DEC>
__global__ __launch_bounds__(256) void wprep(
    const float* __restrict__ w, ushort* __restrict__ dst)
{
    constexpr int CIP = ((CIN + 31) / 32) * 32;
    int i = blockIdx.x * 256 + threadIdx.x;
    if (i >= 9 * COUT * CIP) return;
    int ci = i % CIP;
    int oc = (i / CIP) % COUT;
    int t  = i / (CIP * COUT);
    float x = 0.f;
    if (ci < CIN)
        x = DEC ? w[((size_t)ci * COUT + oc) * 9 + t]
                : w[((size_t)oc * CIN + ci) * 9 + t];
    dst[i] = f2bf(x);
}

// Weight prep for 7x7 layers: dst [chunk][kq][oc16][8] bf16.
// L0: k = tap*8 + ci(8, CIN=3 pad);  L9: k = tap*16 + ci(16).
template<bool L9>
__global__ __launch_bounds__(256) void wprep7(
    const float* __restrict__ w, ushort* __restrict__ dst)
{
    constexpr int NCHUNK = L9 ? 25 : 13;
    constexpr int CINR   = L9 ? 16 : 3;
    constexpr int COUTR  = L9 ? 3  : 16;
    int i = blockIdx.x * 256 + threadIdx.x;
    if (i >= NCHUNK * 512) return;
    int j   = i & 7;
    int oc  = (i >> 3) & 15;
    int kqe = (i >> 7) & 3;
    int cn  = i >> 9;
    int k = cn * 32 + kqe * 8 + j;
    int t, ci;
    if (L9) { t = k >> 4; ci = k & 15; } else { t = k >> 3; ci = k & 7; }
    float x = (t < 49 && oc < COUTR && ci < CINR)
              ? w[((size_t)oc * CINR + ci) * 49 + t] : 0.f;
    dst[i] = f2bf(x);
}

// ---------------------------------------------------------------------------
// MFMA implicit-GEMM conv (MODE 0: 3x3 s2 p1) / deconv (MODE 1: k3 s2 p1 op1).
// NHWC bf16 activations. A-tile in LDS [pix][36]; staging = one 16 B NHWC
// load + reg-preloaded norm per ch-octet. B-frags direct from global.
// Epilogue: acc -> LDS [pix][NOC+8] -> dense ushort8 coalesced stores.
// Frags (HW-verified): A[m=ln][k=kq*8+j]; B[k][n=ln]; C col=ln,row=kq*4+reg.
// ---------------------------------------------------------------------------
template<int CIN, int COUT, int WIN, int MODE, int NWN, int MSUB, int RT, int CT>
__global__ __launch_bounds__(256) void mfconv(
    const ushort* __restrict__ in, const ushort* __restrict__ wbf,
    const float* __restrict__ bias, ushort* __restrict__ out,
    const float* __restrict__ stats_in, float invHWin,
    float* __restrict__ stats_out)
{
    constexpr int HWIN = WIN * WIN;
    constexpr int WOUT = (MODE == 0) ? (WIN / 2) : (WIN * 2);
    constexpr int HWOUT = WOUT * WOUT;
    constexpr int NMG = 4 / NWN;
    constexpr int NOC = NWN * 16;
    constexpr int M = NMG * MSUB * 16;
    static_assert(M == RT * CT, "tile mismatch");
    constexpr int SPAN = (MODE == 0) ? WOUT : WIN;
    constexpr int XC = SPAN / CT, YC = SPAN / RT;
    constexpr int NG = COUT / NOC;
    constexpr int NR = (MODE == 0) ? (2 * RT + 1) : (RT + 1);
    constexpr int NCO = (MODE == 0) ? (2 * CT + 1) : (CT + 1);
    constexpr int NPIX = NR * NCO;
    constexpr int CIP = ((CIN + 31) / 32) * 32;
    constexpr int NQ = (MODE == 0) ? 1 : 4;
    constexpr int LPW = 36;               // A-tile LDS row stride (ushorts)
    constexpr int NPOUT = (MODE == 0 ? 1 : 4) * M;
    constexpr int NOCP = NOC + 8;         // epilogue LDS row stride

    constexpr int TDY[9] = {1,1,1,0,0,0,0,0,0};
    constexpr int TDX[9] = {1,0,0,1,0,0,1,0,0};
    constexpr int TQ [9] = {3,2,3,1,0,1,3,2,3};

    extern __shared__ ushort sa[];        // max(NPIX*36, NPOUT*NOCP)
    __shared__ float mrall[CIP][2];
    __shared__ float sred[4][16][2];

    const int tid = threadIdx.x;
    const int lane = tid & 63, wv = tid >> 6;
    const int ln = lane & 15, kq = lane >> 4;
    const int wn = wv % NWN, wm = wv / NWN;
    const int grp = tid & 3;              // fixed channel-octet per thread

    int bi = blockIdx.x;
    const int xc = bi % XC; bi /= XC;
    const int yc = bi % YC; bi /= YC;
    const int g  = bi % NG;
    const int b  = bi / NG;

    const int ocg = g * NOC + wn * 16 + ln;
    const float b0 = bias[ocg];
    f32x4 acc[NQ][MSUB];
    #pragma unroll
    for (int q = 0; q < NQ; q++)
        #pragma unroll
        for (int s = 0; s < MSUB; s++)
            acc[q][s] = (f32x4){b0, b0, b0, b0};

    for (int e = tid; e < CIP; e += 256) {
        float m = 0.f, r = 0.f;
        if (e < CIN) {
            int c = b * CIN + e;
            float s1 = stats_in[2 * c], s2 = stats_in[2 * c + 1];
            m = s1 * invHWin;
            r = rsqrtf(fmaf(s2, invHWin, -m * m) + EPS_F);
        }
        mrall[e][0] = m; mrall[e][1] = r;
    }

    const ushort* inb = in + (size_t)b * HWIN * CIN;

    for (int c0 = 0; c0 < CIP; c0 += 32) {
        __syncthreads();   // prev tile consumed; mrall visible on iter 0
        const int ch0 = c0 + 8 * grp;
        float m8[8], r8[8];
        #pragma unroll
        for (int j = 0; j < 8; j++) { m8[j] = mrall[ch0 + j][0]; r8[j] = mrall[ch0 + j][1]; }
        for (int pix = tid >> 2; pix < NPIX; pix += 64) {
            int pr = pix / NCO, pc = pix - pr * NCO;
            int gy, gx;
            if (MODE == 0) { gy = 2 * (yc * RT) - 1 + pr; gx = 2 * (xc * CT) - 1 + pc; }
            else           { gy = yc * RT + pr;           gx = xc * CT + pc; }
            ushort8 pk;
            #pragma unroll
            for (int j = 0; j < 8; j++) pk[j] = 0;
            if ((unsigned)gy < (unsigned)WIN && (unsigned)gx < (unsigned)WIN && ch0 < CIN) {
                ushort8 raw = *(const ushort8*)(inb + (size_t)(gy * WIN + gx) * CIN + ch0);
                #pragma unroll
                for (int j = 0; j < 8; j++) {
                    float x = bf2f(raw[j]);
                    pk[j] = f2bf(fmaxf((x - m8[j]) * r8[j], 0.f));
                }
            }
            *(ushort8*)&sa[pix * LPW + grp * 8] = pk;
        }
        __syncthreads();
        #pragma unroll
        for (int t = 0; t < 9; t++) {
            short8 bfr = *(const short8*)&wbf[((size_t)t * COUT + ocg) * CIP + c0 + kq * 8];
            #pragma unroll
            for (int s = 0; s < MSUB; s++) {
                const int mb = wm * MSUB * 16 + s * 16;
                const int r = mb / CT, cb = mb % CT;
                int pix;
                if (MODE == 0) pix = (t / 3 + 2 * r) * NCO + 2 * (cb + ln) + t % 3;
                else           pix = (TDY[t] + r) * NCO + cb + ln + TDX[t];
                short8 afr = *(const short8*)&sa[pix * LPW + kq * 8];
                int qd = (MODE == 0) ? 0 : TQ[t];
                acc[qd][s] = __builtin_amdgcn_mfma_f32_16x16x32_bf16(afr, bfr, acc[qd][s], 0, 0, 0);
            }
        }
    }

    // ---- stats partials (registers only) ----
    float s1 = 0.f, s2 = 0.f;
    #pragma unroll
    for (int q = 0; q < NQ; q++)
        #pragma unroll
        for (int s = 0; s < MSUB; s++)
            #pragma unroll
            for (int rg = 0; rg < 4; rg++) {
                float v = acc[q][s][rg];
                s1 += v; s2 = fmaf(v, v, s2);
            }
    s1 += __shfl_xor(s1, 16); s2 += __shfl_xor(s2, 16);
    s1 += __shfl_xor(s1, 32); s2 += __shfl_xor(s2, 32);
    if (lane < 16) { sred[wv][lane][0] = s1; sred[wv][lane][1] = s2; }

    // ---- assemble outputs in LDS (reuse sa) ----
    __syncthreads();                       // all waves done reading sa
    const int ocl = wn * 16 + ln;
    if (MODE == 0) {
        #pragma unroll
        for (int s = 0; s < MSUB; s++)
            #pragma unroll
            for (int rg = 0; rg < 4; rg++) {
                const int m = wm * MSUB * 16 + s * 16 + kq * 4 + rg;
                sa[m * NOCP + ocl] = f2bf(acc[0][s][rg]);
            }
    } else {
        #pragma unroll
        for (int q = 0; q < 4; q++) {
            const int dy = q >> 1, dx = q & 1;
            #pragma unroll
            for (int s = 0; s < MSUB; s++)
                #pragma unroll
                for (int rg = 0; rg < 4; rg++) {
                    const int m = wm * MSUB * 16 + s * 16 + kq * 4 + rg;
                    const int r = m / CT, c = m % CT;
                    const int lp = (2 * r + dy) * (2 * CT) + 2 * c + dx;
                    sa[lp * NOCP + ocl] = f2bf(acc[q][s][rg]);
                }
        }
    }
    __syncthreads();

    // ---- dense coalesced stores ----
    ushort* ob = out + (size_t)b * HWOUT * COUT + g * NOC;
    for (int e = tid; e < (NPOUT * NOC) / 8; e += 256) {
        int u = e * 8;
        int lp = u / NOC, co = u % NOC;
        int gp;
        if (MODE == 0) {
            int r = lp / CT, c = lp % CT;
            gp = (yc * RT + r) * WOUT + xc * CT + c;
        } else {
            int r2 = lp / (2 * CT), x2 = lp % (2 * CT);
            gp = (2 * (yc * RT) + r2) * WOUT + 2 * (xc * CT) + x2;
        }
        *(ushort8*)&ob[(size_t)gp * COUT + co] = *(const ushort8*)&sa[lp * NOCP + co];
    }

    if (tid < NOC) {
        int wnn = tid >> 4, oc = tid & 15;
        float t1 = 0.f, t2 = 0.f;
        #pragma unroll
        for (int k = 0; k < NMG; k++) {
            t1 += sred[wnn + k * NWN][oc][0];
            t2 += sred[wnn + k * NWN][oc][1];
        }
        int cix = b * COUT + g * NOC + wnn * 16 + oc;
        atomicAdd(&stats_out[2 * cix],     t1);
        atomicAdd(&stats_out[2 * cix + 1], t2);
    }
}

// ---------------------------------------------------------------------------
// 7x7 reflect conv @512 via MFMA. Tile: 8x64 out pixels per block.
// L0 (BFIN=false): fp32 NCHW input (3 ch), NHWC bf16 out (LDS-assembled) +
// stats. L9 (BFIN=true, SEG): NHWC bf16 input, fused norm+tanh+seg.
// Weights pre-packed in global [chunk][kq][oc16][8].
// ---------------------------------------------------------------------------
template<bool BFIN, bool SEG>
__global__ __launch_bounds__(256) void conv7x(
    const float* __restrict__ inf, const ushort* __restrict__ inb16,
    const ushort* __restrict__ wpk, const float* __restrict__ bias,
    ushort* __restrict__ out,
    const float* __restrict__ stats_in, float invHWin,
    float* __restrict__ stats_out,
    const int* __restrict__ inst, float* __restrict__ segacc)
{
    constexpr int W = 512, HW = 512 * 512;
    constexpr int NCHUNK = BFIN ? 25 : 13;
    constexpr int STR = BFIN ? 18 : 12;     // A-tile LDS row stride (ushorts)
    constexpr int SASZ = BFIN ? (980 * 18) : 12288;  // L0 also fits 512*24 epi

    __shared__ ushort sa[SASZ];
    __shared__ float mr[16][2];
    __shared__ float segl[SEG ? 128 : 1];
    __shared__ float sred[4][16][2];

    const int tid = threadIdx.x;
    const int lane = tid & 63, wv = tid >> 6;
    const int ln = lane & 15, kq = lane >> 4;

    int bi = blockIdx.x;
    const int xc = bi & 7;
    const int yr = (bi >> 3) & 63;
    const int b  = bi >> 9;
    const int y0 = yr * 8, x0 = xc * 64;

    if constexpr (SEG) { if (tid < 128) segl[tid] = 0.f; }
    if constexpr (BFIN) {
        if (tid < 16) {
            int c = b * 16 + tid;
            float s1 = stats_in[2 * c], s2 = stats_in[2 * c + 1];
            float m = s1 * invHWin;
            mr[tid][0] = m;
            mr[tid][1] = rsqrtf(fmaf(s2, invHWin, -m * m) + EPS_F);
        }
        __syncthreads();
        const int h = tid & 1;
        float m8[8], r8[8];
        #pragma unroll
        for (int j = 0; j < 8; j++) { m8[j] = mr[8 * h + j][0]; r8[j] = mr[8 * h + j][1]; }
        const ushort* inb = inb16 + (size_t)b * HW * 16;
        for (int pix = tid >> 1; pix < 980; pix += 128) {
            int pr = pix / 70, pc = pix - pr * 70;
            int gy = reflect512(y0 - 3 + pr);
            int gx = reflect512(x0 - 3 + pc);
            ushort8 raw = *(const ushort8*)(inb + (size_t)(gy * W + gx) * 16 + 8 * h);
            ushort8 pk;
            #pragma unroll
            for (int j = 0; j < 8; j++) {
                float x = bf2f(raw[j]);
                pk[j] = f2bf(fmaxf((x - m8[j]) * r8[j], 0.f));
            }
            *(ushort8*)&sa[pix * STR + 8 * h] = pk;
        }
    } else {
        const float* p0 = inf + (size_t)b * 3 * HW;
        for (int pix = tid; pix < 980; pix += 256) {
            int pr = pix / 70, pc = pix - pr * 70;
            int gy = reflect512(y0 - 3 + pr);
            int gx = reflect512(x0 - 3 + pc);
            const float* p = p0 + gy * W + gx;
            ushort8 pk;
            #pragma unroll
            for (int j = 0; j < 8; j++) pk[j] = 0;
            pk[0] = f2bf(p[0]); pk[1] = f2bf(p[HW]); pk[2] = f2bf(p[2 * (size_t)HW]);
            *(ushort8*)&sa[pix * STR] = pk;
        }
    }
    __syncthreads();

    const float b0 = (ln < (BFIN ? 3 : 16)) ? bias[ln] : 0.f;
    f32x4 acc[8];
    #pragma unroll
    for (int s = 0; s < 8; s++) acc[s] = (f32x4){b0, b0, b0, b0};

    for (int cn = 0; cn < NCHUNK; cn++) {
        short8 bfr = *(const short8*)&wpk[((size_t)(cn * 4 + kq) * 16 + ln) * 8];
        int t, off;
        if constexpr (BFIN) { t = 2 * cn + (kq >> 1); off = (kq & 1) * 8; }
        else                { t = 4 * cn + kq;        off = 0; }
        t = t > 48 ? 48 : t;
        const int ty = t / 7, tx = t - ty * 7;
        #pragma unroll
        for (int s = 0; s < 8; s++) {
            int m = wv * 128 + s * 16 + ln;
            int r = m >> 6, c = m & 63;
            short8 afr = *(const short8*)&sa[((r + ty) * 70 + c + tx) * STR + off];
            acc[s] = __builtin_amdgcn_mfma_f32_16x16x32_bf16(afr, bfr, acc[s], 0, 0, 0);
        }
    }

    if constexpr (SEG) {
        if (ln < 3) {
            const int* ib = inst + ((size_t)b << 18);
            #pragma unroll
            for (int s = 0; s < 8; s++) {
                #pragma unroll
                for (int rg = 0; rg < 4; rg++) {
                    int m = wv * 128 + s * 16 + kq * 4 + rg;
                    int r = m >> 6, c = m & 63;
                    int lab = ib[(y0 + r) * W + x0 + c] & 31;
                    float val = tanhf(acc[s][rg]);
                    atomicAdd(&segl[lab * 4 + ln], val);
                    if (ln == 0) atomicAdd(&segl[lab * 4 + 3], 1.f);
                }
            }
        }
        __syncthreads();
        if (tid < 128) {
            float v = segl[tid];
            if (v != 0.f) atomicAdd(&segacc[tid], v);
        }
    } else {
        // stats partials first (registers), then LDS-assembled NHWC store.
        float s1 = 0.f, s2 = 0.f;
        #pragma unroll
        for (int s = 0; s < 8; s++)
            #pragma unroll
            for (int rg = 0; rg < 4; rg++) {
                float v = acc[s][rg];
                s1 += v; s2 = fmaf(v, v, s2);
            }
        s1 += __shfl_xor(s1, 16); s2 += __shfl_xor(s2, 16);
        s1 += __shfl_xor(s1, 32); s2 += __shfl_xor(s2, 32);
        if (lane < 16) { sred[wv][lane][0] = s1; sred[wv][lane][1] = s2; }

        __syncthreads();   // A-tile reads done; reuse sa as [512][24]
        #pragma unroll
        for (int s = 0; s < 8; s++)
            #pragma unroll
            for (int rg = 0; rg < 4; rg++) {
                int m = wv * 128 + s * 16 + kq * 4 + rg;
                sa[m * 24 + ln] = f2bf(acc[s][rg]);
            }
        __syncthreads();
        ushort* ob = out + (size_t)b * HW * 16;
        for (int e = tid; e < 1024; e += 256) {
            int u = e * 8;
            int lp = u >> 4, co = u & 15;
            int gp = (y0 + (lp >> 6)) * W + x0 + (lp & 63);
            *(ushort8*)&ob[(size_t)gp * 16 + co] = *(const ushort8*)&sa[lp * 24 + co];
        }
        if (tid < 16) {
            float t1 = 0.f, t2 = 0.f;
            #pragma unroll
            for (int k = 0; k < 4; k++) { t1 += sred[k][tid][0]; t2 += sred[k][tid][1]; }
            int cix = b * 16 + tid;
            atomicAdd(&stats_out[2 * cix],     t1);
            atomicAdd(&stats_out[2 * cix + 1], t2);
        }
    }
}

// ---------------------------------------------------------------------------
// Segment finalize + scatter.
// ---------------------------------------------------------------------------
#define HW9 262144
__global__ void seg_final(const float* __restrict__ acc, float* __restrict__ means)
{
    int i = threadIdx.x;
    if (i < 96) {
        int s = i / 3, c = i - s * 3;
        means[i] = acc[s * 4 + c] / fmaxf(acc[s * 4 + 3], 1.f);
    }
}

__global__ __launch_bounds__(256) void seg_scatter(
    const int* __restrict__ inst, const float* __restrict__ means,
    float* __restrict__ out)
{
    int p   = blockIdx.x * 256 + threadIdx.x;
    int b   = p >> 18;
    int r   = p & (HW9 - 1);
    int lab = inst[p] & 31;
    float* ob = out + (size_t)b * 3 * HW9;
    ob[r]           = means[lab * 3 + 0];
    ob[HW9 + r]     = means[lab * 3 + 1];
    ob[2 * HW9 + r] = means[lab * 3 + 2];
}

// ---------------------------------------------------------------------------
// Launch.
// ---------------------------------------------------------------------------
extern "C" void kernel_launch(void* const* d_in, const int* in_sizes, int n_in,
                              void* d_out, int out_size, void* d_ws, size_t ws_size,
                              hipStream_t stream)
{
    const float* x_in = (const float*)d_in[0];
    const int*   inst = (const int*)d_in[1];
    const float* W_[10];
    const float* Bs[10];
    for (int i = 0; i < 10; i++) {
        W_[i] = (const float*)d_in[2 + 2 * i];
        Bs[i] = (const float*)d_in[3 + 2 * i];
    }
    float* out = (float*)d_out;

    // NHWC bf16 activation ping-pong + fp32 stats + bf16 weights.
    ushort* Ab  = (ushort*)d_ws;            // 16,777,216 el
    ushort* Bb2 = Ab + (size_t)16777216;    //  8,388,608 el
    float*  st  = (float*)(Bb2 + (size_t)8388608);
    const int coff[9] = {0, 128, 384, 896, 1920, 3968, 4992, 5504, 5760};
    float* s_[9];
    for (int i = 0; i < 9; i++) s_[i] = st + coff[i];
    float* segacc = st + 5888;
    float* means  = st + 6016;
    ushort* wb = (ushort*)(st + 8192);
    const size_t OW1 = 0, OW2 = 9216, OW3 = 27648, OW4 = 101376,
                 OW5 = 396288, OW6 = 691200, OW7 = 764928, OW8 = 783360;
    ushort* wb0 = wb + 790000;
    ushort* wb9 = wb0 + 6656;

    hipMemsetAsync(st, 0, 6016 * sizeof(float), stream);

    wprep<16,  32,  false><<<dim3((9*32*32   + 255)/256), dim3(256), 0, stream>>>(W_[1], wb + OW1);
    wprep<32,  64,  false><<<dim3((9*64*32   + 255)/256), dim3(256), 0, stream>>>(W_[2], wb + OW2);
    wprep<64,  128, false><<<dim3((9*128*64  + 255)/256), dim3(256), 0, stream>>>(W_[3], wb + OW3);
    wprep<128, 256, false><<<dim3((9*256*128 + 255)/256), dim3(256), 0, stream>>>(W_[4], wb + OW4);
    wprep<256, 128, true ><<<dim3((9*128*256 + 255)/256), dim3(256), 0, stream>>>(W_[5], wb + OW5);
    wprep<128, 64,  true ><<<dim3((9*64*128  + 255)/256), dim3(256), 0, stream>>>(W_[6], wb + OW6);
    wprep<64,  32,  true ><<<dim3((9*32*64   + 255)/256), dim3(256), 0, stream>>>(W_[7], wb + OW7);
    wprep<32,  16,  true ><<<dim3((9*16*32   + 255)/256), dim3(256), 0, stream>>>(W_[8], wb + OW8);
    wprep7<false><<<dim3(26), dim3(256), 0, stream>>>(W_[0], wb0);
    wprep7<true ><<<dim3(50), dim3(256), 0, stream>>>(W_[9], wb9);

    // L0: 7x7 3->16 @512, fp32 NCHW in -> NHWC bf16 out + stats. grid 2048.
    conv7x<false, false><<<dim3(2048), dim3(256), 0, stream>>>(
        x_in, nullptr, wb0, Bs[0], Ab, nullptr, 0.f, s_[0], nullptr, nullptr);

    // L1: conv 16->32 @512->256. grid 2048.
    mfconv<16, 32, 512, 0, 2, 4, 4, 32><<<dim3(2048), dim3(256), 42120, stream>>>(
        Ab, wb + OW1, Bs[1], Bb2, s_[0], 1.f / 262144.f, s_[1]);

    // L2: conv 32->64 @256->128. grid 1024.
    mfconv<32, 64, 256, 0, 2, 4, 4, 32><<<dim3(1024), dim3(256), 42120, stream>>>(
        Bb2, wb + OW2, Bs[2], Ab, s_[1], 1.f / 65536.f, s_[2]);

    // L3: conv 64->128 @128->64. grid 512.
    mfconv<64, 128, 128, 0, 2, 4, 4, 32><<<dim3(512), dim3(256), 42120, stream>>>(
        Ab, wb + OW3, Bs[3], Bb2, s_[2], 1.f / 16384.f, s_[3]);

    // L4: conv 128->256 @64->32. grid 512.
    mfconv<128, 256, 64, 0, 2, 2, 2, 32><<<dim3(512), dim3(256), 23400, stream>>>(
        Bb2, wb + OW4, Bs[4], Ab, s_[3], 1.f / 4096.f, s_[4]);

    // L5: deconv 256->128 @32->64. grid 512. LDS 12288 (epilogue-sized).
    mfconv<256, 128, 32, 1, 1, 1, 2, 32><<<dim3(512), dim3(256), 12288, stream>>>(
        Ab, wb + OW5, Bs[5], Bb2, s_[4], 1.f / 1024.f, s_[5]);

    // L6: deconv 128->64 @64->128. grid 512. LDS 20480.
    mfconv<128, 64, 64, 1, 2, 2, 2, 32><<<dim3(512), dim3(256), 20480, stream>>>(
        Bb2, wb + OW6, Bs[6], Ab, s_[5], 1.f / 4096.f, s_[6]);

    // L7: deconv 64->32 @128->256. grid 1024. LDS 20480.
    mfconv<64, 32, 128, 1, 2, 2, 2, 32><<<dim3(1024), dim3(256), 20480, stream>>>(
        Ab, wb + OW7, Bs[7], Bb2, s_[6], 1.f / 16384.f, s_[7]);

    // L8: deconv 32->16 @256->512. MSUB=2, CT=64 -> M=128, grid 2048. LDS 24576.
    mfconv<32, 16, 256, 1, 1, 2, 2, 64><<<dim3(2048), dim3(256), 24576, stream>>>(
        Bb2, wb + OW8, Bs[8], Ab, s_[7], 1.f / 65536.f, s_[8]);

    // L9: 7x7 16->3 @512, NHWC in + norm + tanh + seg. grid 2048.
    conv7x<true, true><<<dim3(2048), dim3(256), 0, stream>>>(
        nullptr, Ab, wb9, Bs[9], nullptr, s_[8], 1.f / 262144.f, nullptr, inst, segacc);

    seg_final<<<dim3(1), dim3(96), 0, stream>>>(segacc, means);
    seg_scatter<<<dim3(4096), dim3(256), 0, stream>>>(inst, means, out);
}

// Round 12
// 506.124 us; speedup vs baseline: 12.7117x; 1.0443x over previous
//
#include <hip/hip_runtime.h>
#include <math.h>

#define EPS_F 1e-5f

typedef __attribute__((ext_vector_type(8))) short short8;
typedef __attribute__((ext_vector_type(4))) float f32x4;
typedef __attribute__((ext_vector_type(8))) unsigned short ushort8;

__device__ __forceinline__ int reflect512(int v) {
    v = v < 0 ? -v : v;
    return v >= 512 ? 1022 - v : v;
}

// float -> bf16 bits, round-to-nearest-even
__device__ __forceinline__ ushort f2bf(float f) {
    union { float f; unsigned u; } v; v.f = f;
    unsigned r = v.u + 0x7FFFu + ((v.u >> 16) & 1u);
    return (ushort)(r >> 16);
}
__device__ __forceinline__ float bf2f(ushort u) {
    union { unsigned u; float f; } v; v.u = (unsigned)u << 16;
    return v.f;
}

// ---------------------------------------------------------------------------
// Weight prep, single fused dispatch.
// Mid layers: fp32 conv(OIHW)/deconv(IOHW) -> bf16 [tap][oc][ci(pad32)].
// 7x7 layers: -> [chunk][kq][oc16][8] bf16.
// ---------------------------------------------------------------------------
template<int CIN, int COUT, bool DEC>
__device__ __forceinline__ void wp_mid(
    const float* __restrict__ w, ushort* __restrict__ dst, int i)
{
    constexpr int CIP = ((CIN + 31) / 32) * 32;
    int ci = i % CIP;
    int oc = (i / CIP) % COUT;
    int t  = i / (CIP * COUT);
    float x = 0.f;
    if (ci < CIN)
        x = DEC ? w[((size_t)ci * COUT + oc) * 9 + t]
                : w[((size_t)oc * CIN + ci) * 9 + t];
    dst[i] = f2bf(x);
}

template<bool L9>
__device__ __forceinline__ void wp_7(
    const float* __restrict__ w, ushort* __restrict__ dst, int i)
{
    constexpr int CINR  = L9 ? 16 : 3;
    constexpr int COUTR = L9 ? 3  : 16;
    int j   = i & 7;
    int oc  = (i >> 3) & 15;
    int kqe = (i >> 7) & 3;
    int cn  = i >> 9;
    int k = cn * 32 + kqe * 8 + j;
    int t, ci;
    if (L9) { t = k >> 4; ci = k & 15; } else { t = k >> 3; ci = k & 7; }
    float x = (t < 49 && oc < COUTR && ci < CINR)
              ? w[((size_t)oc * CINR + ci) * 49 + t] : 0.f;
    dst[i] = f2bf(x);
}

struct WprepArgs {
    const float* w[10];
    ushort* d[10];   // d[0]=L0 pack, d[1..8]=mid, d[9]=L9 pack
};

__global__ __launch_bounds__(256) void wprep_all(WprepArgs a)
{
    int bi = blockIdx.x;
    int t  = threadIdx.x;
    if      (bi < 36)   wp_mid<16,  32,  false>(a.w[1], a.d[1], (bi        ) * 256 + t);
    else if (bi < 108)  wp_mid<32,  64,  false>(a.w[2], a.d[2], (bi - 36   ) * 256 + t);
    else if (bi < 396)  wp_mid<64,  128, false>(a.w[3], a.d[3], (bi - 108  ) * 256 + t);
    else if (bi < 1548) wp_mid<128, 256, false>(a.w[4], a.d[4], (bi - 396  ) * 256 + t);
    else if (bi < 2700) wp_mid<256, 128, true >(a.w[5], a.d[5], (bi - 1548 ) * 256 + t);
    else if (bi < 2988) wp_mid<128, 64,  true >(a.w[6], a.d[6], (bi - 2700 ) * 256 + t);
    else if (bi < 3060) wp_mid<64,  32,  true >(a.w[7], a.d[7], (bi - 2988 ) * 256 + t);
    else if (bi < 3078) wp_mid<32,  16,  true >(a.w[8], a.d[8], (bi - 3060 ) * 256 + t);
    else if (bi < 3104) wp_7<false>(a.w[0], a.d[0], (bi - 3078) * 256 + t);
    else                wp_7<true >(a.w[9], a.d[9], (bi - 3104) * 256 + t);
}

// ---------------------------------------------------------------------------
// MFMA implicit-GEMM conv (MODE 0: 3x3 s2 p1) / deconv (MODE 1: k3 s2 p1 op1).
// NHWC bf16 activations. A-tile in LDS [pix][36]; staging = one 16 B NHWC
// load + reg-preloaded norm per ch-octet. B-frags direct from global.
// Epilogue: acc -> LDS [pix][NOC+8] -> dense ushort8 coalesced stores.
// Frags (HW-verified): A[m=ln][k=kq*8+j]; B[k][n=ln]; C col=ln,row=kq*4+reg.
// ---------------------------------------------------------------------------
template<int CIN, int COUT, int WIN, int MODE, int NWN, int MSUB, int RT, int CT>
__global__ __launch_bounds__(256) void mfconv(
    const ushort* __restrict__ in, const ushort* __restrict__ wbf,
    const float* __restrict__ bias, ushort* __restrict__ out,
    const float* __restrict__ stats_in, float invHWin,
    float* __restrict__ stats_out)
{
    constexpr int HWIN = WIN * WIN;
    constexpr int WOUT = (MODE == 0) ? (WIN / 2) : (WIN * 2);
    constexpr int HWOUT = WOUT * WOUT;
    constexpr int NMG = 4 / NWN;
    constexpr int NOC = NWN * 16;
    constexpr int M = NMG * MSUB * 16;
    static_assert(M == RT * CT, "tile mismatch");
    constexpr int SPAN = (MODE == 0) ? WOUT : WIN;
    constexpr int XC = SPAN / CT, YC = SPAN / RT;
    constexpr int NG = COUT / NOC;
    constexpr int NR = (MODE == 0) ? (2 * RT + 1) : (RT + 1);
    constexpr int NCO = (MODE == 0) ? (2 * CT + 1) : (CT + 1);
    constexpr int NPIX = NR * NCO;
    constexpr int CIP = ((CIN + 31) / 32) * 32;
    constexpr int NQ = (MODE == 0) ? 1 : 4;
    constexpr int LPW = 36;               // A-tile LDS row stride (ushorts)
    constexpr int NPOUT = (MODE == 0 ? 1 : 4) * M;
    constexpr int NOCP = NOC + 8;         // epilogue LDS row stride

    constexpr int TDY[9] = {1,1,1,0,0,0,0,0,0};
    constexpr int TDX[9] = {1,0,0,1,0,0,1,0,0};
    constexpr int TQ [9] = {3,2,3,1,0,1,3,2,3};

    extern __shared__ ushort sa[];        // max(NPIX*36, NPOUT*NOCP)
    __shared__ float mrall[CIP][2];
    __shared__ float sred[4][16][2];

    const int tid = threadIdx.x;
    const int lane = tid & 63, wv = tid >> 6;
    const int ln = lane & 15, kq = lane >> 4;
    const int wn = wv % NWN, wm = wv / NWN;
    const int grp = tid & 3;              // fixed channel-octet per thread

    int bi = blockIdx.x;
    const int xc = bi % XC; bi /= XC;
    const int yc = bi % YC; bi /= YC;
    const int g  = bi % NG;
    const int b  = bi / NG;

    const int ocg = g * NOC + wn * 16 + ln;
    const float b0 = bias[ocg];
    f32x4 acc[NQ][MSUB];
    #pragma unroll
    for (int q = 0; q < NQ; q++)
        #pragma unroll
        for (int s = 0; s < MSUB; s++)
            acc[q][s] = (f32x4){b0, b0, b0, b0};

    for (int e = tid; e < CIP; e += 256) {
        float m = 0.f, r = 0.f;
        if (e < CIN) {
            int c = b * CIN + e;
            float s1 = stats_in[2 * c], s2 = stats_in[2 * c + 1];
            m = s1 * invHWin;
            r = rsqrtf(fmaf(s2, invHWin, -m * m) + EPS_F);
        }
        mrall[e][0] = m; mrall[e][1] = r;
    }

    const ushort* inb = in + (size_t)b * HWIN * CIN;

    for (int c0 = 0; c0 < CIP; c0 += 32) {
        __syncthreads();   // prev tile consumed; mrall visible on iter 0
        const int ch0 = c0 + 8 * grp;
        float m8[8], r8[8];
        #pragma unroll
        for (int j = 0; j < 8; j++) { m8[j] = mrall[ch0 + j][0]; r8[j] = mrall[ch0 + j][1]; }
        for (int pix = tid >> 2; pix < NPIX; pix += 64) {
            int pr = pix / NCO, pc = pix - pr * NCO;
            int gy, gx;
            if (MODE == 0) { gy = 2 * (yc * RT) - 1 + pr; gx = 2 * (xc * CT) - 1 + pc; }
            else           { gy = yc * RT + pr;           gx = xc * CT + pc; }
            ushort8 pk;
            #pragma unroll
            for (int j = 0; j < 8; j++) pk[j] = 0;
            if ((unsigned)gy < (unsigned)WIN && (unsigned)gx < (unsigned)WIN && ch0 < CIN) {
                ushort8 raw = *(const ushort8*)(inb + (size_t)(gy * WIN + gx) * CIN + ch0);
                #pragma unroll
                for (int j = 0; j < 8; j++) {
                    float x = bf2f(raw[j]);
                    pk[j] = f2bf(fmaxf((x - m8[j]) * r8[j], 0.f));
                }
            }
            *(ushort8*)&sa[pix * LPW + grp * 8] = pk;
        }
        __syncthreads();
        #pragma unroll
        for (int t = 0; t < 9; t++) {
            short8 bfr = *(const short8*)&wbf[((size_t)t * COUT + ocg) * CIP + c0 + kq * 8];
            #pragma unroll
            for (int s = 0; s < MSUB; s++) {
                const int mb = wm * MSUB * 16 + s * 16;
                const int r = mb / CT, cb = mb % CT;
                int pix;
                if (MODE == 0) pix = (t / 3 + 2 * r) * NCO + 2 * (cb + ln) + t % 3;
                else           pix = (TDY[t] + r) * NCO + cb + ln + TDX[t];
                short8 afr = *(const short8*)&sa[pix * LPW + kq * 8];
                int qd = (MODE == 0) ? 0 : TQ[t];
                acc[qd][s] = __builtin_amdgcn_mfma_f32_16x16x32_bf16(afr, bfr, acc[qd][s], 0, 0, 0);
            }
        }
    }

    // ---- stats partials (registers only) ----
    float s1 = 0.f, s2 = 0.f;
    #pragma unroll
    for (int q = 0; q < NQ; q++)
        #pragma unroll
        for (int s = 0; s < MSUB; s++)
            #pragma unroll
            for (int rg = 0; rg < 4; rg++) {
                float v = acc[q][s][rg];
                s1 += v; s2 = fmaf(v, v, s2);
            }
    s1 += __shfl_xor(s1, 16); s2 += __shfl_xor(s2, 16);
    s1 += __shfl_xor(s1, 32); s2 += __shfl_xor(s2, 32);
    if (lane < 16) { sred[wv][lane][0] = s1; sred[wv][lane][1] = s2; }

    // ---- assemble outputs in LDS (reuse sa) ----
    __syncthreads();                       // all waves done reading sa
    const int ocl = wn * 16 + ln;
    if (MODE == 0) {
        #pragma unroll
        for (int s = 0; s < MSUB; s++)
            #pragma unroll
            for (int rg = 0; rg < 4; rg++) {
                const int m = wm * MSUB * 16 + s * 16 + kq * 4 + rg;
                sa[m * NOCP + ocl] = f2bf(acc[0][s][rg]);
            }
    } else {
        #pragma unroll
        for (int q = 0; q < 4; q++) {
            const int dy = q >> 1, dx = q & 1;
            #pragma unroll
            for (int s = 0; s < MSUB; s++)
                #pragma unroll
                for (int rg = 0; rg < 4; rg++) {
                    const int m = wm * MSUB * 16 + s * 16 + kq * 4 + rg;
                    const int r = m / CT, c = m % CT;
                    const int lp = (2 * r + dy) * (2 * CT) + 2 * c + dx;
                    sa[lp * NOCP + ocl] = f2bf(acc[q][s][rg]);
                }
        }
    }
    __syncthreads();

    // ---- dense coalesced stores ----
    ushort* ob = out + (size_t)b * HWOUT * COUT + g * NOC;
    for (int e = tid; e < (NPOUT * NOC) / 8; e += 256) {
        int u = e * 8;
        int lp = u / NOC, co = u % NOC;
        int gp;
        if (MODE == 0) {
            int r = lp / CT, c = lp % CT;
            gp = (yc * RT + r) * WOUT + xc * CT + c;
        } else {
            int r2 = lp / (2 * CT), x2 = lp % (2 * CT);
            gp = (2 * (yc * RT) + r2) * WOUT + 2 * (xc * CT) + x2;
        }
        *(ushort8*)&ob[(size_t)gp * COUT + co] = *(const ushort8*)&sa[lp * NOCP + co];
    }

    if (tid < NOC) {
        int wnn = tid >> 4, oc = tid & 15;
        float t1 = 0.f, t2 = 0.f;
        #pragma unroll
        for (int k = 0; k < NMG; k++) {
            t1 += sred[wnn + k * NWN][oc][0];
            t2 += sred[wnn + k * NWN][oc][1];
        }
        int cix = b * COUT + g * NOC + wnn * 16 + oc;
        atomicAdd(&stats_out[2 * cix],     t1);
        atomicAdd(&stats_out[2 * cix + 1], t2);
    }
}

// ---------------------------------------------------------------------------
// 7x7 reflect conv @512 via MFMA. Tile: 8x64 out pixels per block.
// L0 (BFIN=false): fp32 NCHW input (3 ch), NHWC bf16 out (LDS-assembled) +
// stats. L9 (BFIN=true, SEG): NHWC bf16 input, fused norm+tanh+seg.
// A-tile row stride: L9 = 20 ushorts (10 dwords, even -> 2-way max = free);
// L0 = 12 (6 dwords, free). Seg epilogue: accs -> LDS (stride-5 f32), then
// ALL 256 threads split tanh + atomics evenly.
// ---------------------------------------------------------------------------
template<bool BFIN, bool SEG>
__global__ __launch_bounds__(256) void conv7x(
    const float* __restrict__ inf, const ushort* __restrict__ inb16,
    const ushort* __restrict__ wpk, const float* __restrict__ bias,
    ushort* __restrict__ out,
    const float* __restrict__ stats_in, float invHWin,
    float* __restrict__ stats_out,
    const int* __restrict__ inst, float* __restrict__ segacc)
{
    constexpr int W = 512, HW = 512 * 512;
    constexpr int NCHUNK = BFIN ? 25 : 13;
    constexpr int STR = BFIN ? 20 : 12;     // A-tile LDS row stride (ushorts)
    constexpr int SASZ = BFIN ? (980 * 20) : 12288;

    __shared__ ushort sa[SASZ];
    __shared__ float mr[16][2];
    __shared__ float segl[SEG ? 128 : 1];
    __shared__ float sred[4][16][2];

    const int tid = threadIdx.x;
    const int lane = tid & 63, wv = tid >> 6;
    const int ln = lane & 15, kq = lane >> 4;

    int bi = blockIdx.x;
    const int xc = bi & 7;
    const int yr = (bi >> 3) & 63;
    const int b  = bi >> 9;
    const int y0 = yr * 8, x0 = xc * 64;

    if constexpr (SEG) { if (tid < 128) segl[tid] = 0.f; }
    if constexpr (BFIN) {
        if (tid < 16) {
            int c = b * 16 + tid;
            float s1 = stats_in[2 * c], s2 = stats_in[2 * c + 1];
            float m = s1 * invHWin;
            mr[tid][0] = m;
            mr[tid][1] = rsqrtf(fmaf(s2, invHWin, -m * m) + EPS_F);
        }
        __syncthreads();
        const int h = tid & 1;
        float m8[8], r8[8];
        #pragma unroll
        for (int j = 0; j < 8; j++) { m8[j] = mr[8 * h + j][0]; r8[j] = mr[8 * h + j][1]; }
        const ushort* inb = inb16 + (size_t)b * HW * 16;
        for (int pix = tid >> 1; pix < 980; pix += 128) {
            int pr = pix / 70, pc = pix - pr * 70;
            int gy = reflect512(y0 - 3 + pr);
            int gx = reflect512(x0 - 3 + pc);
            ushort8 raw = *(const ushort8*)(inb + (size_t)(gy * W + gx) * 16 + 8 * h);
            ushort8 pk;
            #pragma unroll
            for (int j = 0; j < 8; j++) {
                float x = bf2f(raw[j]);
                pk[j] = f2bf(fmaxf((x - m8[j]) * r8[j], 0.f));
            }
            *(ushort8*)&sa[pix * STR + 8 * h] = pk;
        }
    } else {
        const float* p0 = inf + (size_t)b * 3 * HW;
        for (int pix = tid; pix < 980; pix += 256) {
            int pr = pix / 70, pc = pix - pr * 70;
            int gy = reflect512(y0 - 3 + pr);
            int gx = reflect512(x0 - 3 + pc);
            const float* p = p0 + gy * W + gx;
            ushort8 pk;
            #pragma unroll
            for (int j = 0; j < 8; j++) pk[j] = 0;
            pk[0] = f2bf(p[0]); pk[1] = f2bf(p[HW]); pk[2] = f2bf(p[2 * (size_t)HW]);
            *(ushort8*)&sa[pix * STR] = pk;
        }
    }
    __syncthreads();

    const float b0 = (ln < (BFIN ? 3 : 16)) ? bias[ln] : 0.f;
    f32x4 acc[8];
    #pragma unroll
    for (int s = 0; s < 8; s++) acc[s] = (f32x4){b0, b0, b0, b0};

    for (int cn = 0; cn < NCHUNK; cn++) {
        short8 bfr = *(const short8*)&wpk[((size_t)(cn * 4 + kq) * 16 + ln) * 8];
        int t, off;
        if constexpr (BFIN) { t = 2 * cn + (kq >> 1); off = (kq & 1) * 8; }
        else                { t = 4 * cn + kq;        off = 0; }
        t = t > 48 ? 48 : t;
        const int ty = t / 7, tx = t - ty * 7;
        #pragma unroll
        for (int s = 0; s < 8; s++) {
            int m = wv * 128 + s * 16 + ln;
            int r = m >> 6, c = m & 63;
            short8 afr = *(const short8*)&sa[((r + ty) * 70 + c + tx) * STR + off];
            acc[s] = __builtin_amdgcn_mfma_f32_16x16x32_bf16(afr, bfr, acc[s], 0, 0, 0);
        }
    }

    if constexpr (SEG) {
        // Phase 1: raw accs -> LDS [512][5] fp32 (stride 5 dwords: bank-free).
        float* sf = (float*)sa;
        __syncthreads();   // all A-tile reads done
        if (ln < 3) {
            #pragma unroll
            for (int s = 0; s < 8; s++)
                #pragma unroll
                for (int rg = 0; rg < 4; rg++) {
                    int m = wv * 128 + s * 16 + kq * 4 + rg;
                    sf[m * 5 + ln] = acc[s][rg];
                }
        }
        __syncthreads();
        // Phase 2: all 256 threads, 2 pixels each: tanh + LDS atomics.
        const int* ib = inst + ((size_t)b << 18);
        for (int p2 = tid; p2 < 512; p2 += 256) {
            int r = p2 >> 6, c = p2 & 63;
            int lab = ib[(y0 + r) * W + x0 + c] & 31;
            atomicAdd(&segl[lab * 4 + 0], tanhf(sf[p2 * 5 + 0]));
            atomicAdd(&segl[lab * 4 + 1], tanhf(sf[p2 * 5 + 1]));
            atomicAdd(&segl[lab * 4 + 2], tanhf(sf[p2 * 5 + 2]));
            atomicAdd(&segl[lab * 4 + 3], 1.f);
        }
        __syncthreads();
        if (tid < 128) {
            float v = segl[tid];
            if (v != 0.f) atomicAdd(&segacc[tid], v);
        }
    } else {
        // stats partials first (registers), then LDS-assembled NHWC store.
        float s1 = 0.f, s2 = 0.f;
        #pragma unroll
        for (int s = 0; s < 8; s++)
            #pragma unroll
            for (int rg = 0; rg < 4; rg++) {
                float v = acc[s][rg];
                s1 += v; s2 = fmaf(v, v, s2);
            }
        s1 += __shfl_xor(s1, 16); s2 += __shfl_xor(s2, 16);
        s1 += __shfl_xor(s1, 32); s2 += __shfl_xor(s2, 32);
        if (lane < 16) { sred[wv][lane][0] = s1; sred[wv][lane][1] = s2; }

        __syncthreads();   // A-tile reads done; reuse sa as [512][24]
        #pragma unroll
        for (int s = 0; s < 8; s++)
            #pragma unroll
            for (int rg = 0; rg < 4; rg++) {
                int m = wv * 128 + s * 16 + kq * 4 + rg;
                sa[m * 24 + ln] = f2bf(acc[s][rg]);
            }
        __syncthreads();
        ushort* ob = out + (size_t)b * HW * 16;
        for (int e = tid; e < 1024; e += 256) {
            int u = e * 8;
            int lp = u >> 4, co = u & 15;
            int gp = (y0 + (lp >> 6)) * W + x0 + (lp & 63);
            *(ushort8*)&ob[(size_t)gp * 16 + co] = *(const ushort8*)&sa[lp * 24 + co];
        }
        if (tid < 16) {
            float t1 = 0.f, t2 = 0.f;
            #pragma unroll
            for (int k = 0; k < 4; k++) { t1 += sred[k][tid][0]; t2 += sred[k][tid][1]; }
            int cix = b * 16 + tid;
            atomicAdd(&stats_out[2 * cix],     t1);
            atomicAdd(&stats_out[2 * cix + 1], t2);
        }
    }
}

// ---------------------------------------------------------------------------
// Segment finalize + scatter.
// ---------------------------------------------------------------------------
#define HW9 262144
__global__ void seg_final(const float* __restrict__ acc, float* __restrict__ means)
{
    int i = threadIdx.x;
    if (i < 96) {
        int s = i / 3, c = i - s * 3;
        means[i] = acc[s * 4 + c] / fmaxf(acc[s * 4 + 3], 1.f);
    }
}

__global__ __launch_bounds__(256) void seg_scatter(
    const int* __restrict__ inst, const float* __restrict__ means,
    float* __restrict__ out)
{
    int p   = blockIdx.x * 256 + threadIdx.x;
    int b   = p >> 18;
    int r   = p & (HW9 - 1);
    int lab = inst[p] & 31;
    float* ob = out + (size_t)b * 3 * HW9;
    ob[r]           = means[lab * 3 + 0];
    ob[HW9 + r]     = means[lab * 3 + 1];
    ob[2 * HW9 + r] = means[lab * 3 + 2];
}

// ---------------------------------------------------------------------------
// Launch.
// ---------------------------------------------------------------------------
extern "C" void kernel_launch(void* const* d_in, const int* in_sizes, int n_in,
                              void* d_out, int out_size, void* d_ws, size_t ws_size,
                              hipStream_t stream)
{
    const float* x_in = (const float*)d_in[0];
    const int*   inst = (const int*)d_in[1];
    const float* W_[10];
    const float* Bs[10];
    for (int i = 0; i < 10; i++) {
        W_[i] = (const float*)d_in[2 + 2 * i];
        Bs[i] = (const float*)d_in[3 + 2 * i];
    }
    float* out = (float*)d_out;

    // NHWC bf16 activation ping-pong + fp32 stats + bf16 weights.
    ushort* Ab  = (ushort*)d_ws;            // 16,777,216 el
    ushort* Bb2 = Ab + (size_t)16777216;    //  8,388,608 el
    float*  st  = (float*)(Bb2 + (size_t)8388608);
    const int coff[9] = {0, 128, 384, 896, 1920, 3968, 4992, 5504, 5760};
    float* s_[9];
    for (int i = 0; i < 9; i++) s_[i] = st + coff[i];
    float* segacc = st + 5888;
    float* means  = st + 6016;
    ushort* wb = (ushort*)(st + 8192);
    const size_t OW1 = 0, OW2 = 9216, OW3 = 27648, OW4 = 101376,
                 OW5 = 396288, OW6 = 691200, OW7 = 764928, OW8 = 783360;
    ushort* wb0 = wb + 790000;
    ushort* wb9 = wb0 + 6656;

    hipMemsetAsync(st, 0, 6016 * sizeof(float), stream);

    WprepArgs wa;
    for (int i = 0; i < 10; i++) wa.w[i] = W_[i];
    wa.d[0] = wb0;
    wa.d[1] = wb + OW1; wa.d[2] = wb + OW2; wa.d[3] = wb + OW3; wa.d[4] = wb + OW4;
    wa.d[5] = wb + OW5; wa.d[6] = wb + OW6; wa.d[7] = wb + OW7; wa.d[8] = wb + OW8;
    wa.d[9] = wb9;
    wprep_all<<<dim3(3154), dim3(256), 0, stream>>>(wa);

    // L0: 7x7 3->16 @512, fp32 NCHW in -> NHWC bf16 out + stats. grid 2048.
    conv7x<false, false><<<dim3(2048), dim3(256), 0, stream>>>(
        x_in, nullptr, wb0, Bs[0], Ab, nullptr, 0.f, s_[0], nullptr, nullptr);

    // L1: conv 16->32 @512->256. grid 2048.
    mfconv<16, 32, 512, 0, 2, 4, 4, 32><<<dim3(2048), dim3(256), 42120, stream>>>(
        Ab, wb + OW1, Bs[1], Bb2, s_[0], 1.f / 262144.f, s_[1]);

    // L2: conv 32->64 @256->128. grid 1024.
    mfconv<32, 64, 256, 0, 2, 4, 4, 32><<<dim3(1024), dim3(256), 42120, stream>>>(
        Bb2, wb + OW2, Bs[2], Ab, s_[1], 1.f / 65536.f, s_[2]);

    // L3: conv 64->128 @128->64. grid 512.
    mfconv<64, 128, 128, 0, 2, 4, 4, 32><<<dim3(512), dim3(256), 42120, stream>>>(
        Ab, wb + OW3, Bs[3], Bb2, s_[2], 1.f / 16384.f, s_[3]);

    // L4: conv 128->256 @64->32. grid 512.
    mfconv<128, 256, 64, 0, 2, 2, 2, 32><<<dim3(512), dim3(256), 23400, stream>>>(
        Bb2, wb + OW4, Bs[4], Ab, s_[3], 1.f / 4096.f, s_[4]);

    // L5: deconv 256->128 @32->64. grid 512. LDS 12288 (epilogue-sized).
    mfconv<256, 128, 32, 1, 1, 1, 2, 32><<<dim3(512), dim3(256), 12288, stream>>>(
        Ab, wb + OW5, Bs[5], Bb2, s_[4], 1.f / 1024.f, s_[5]);

    // L6: deconv 128->64 @64->128. grid 512. LDS 20480.
    mfconv<128, 64, 64, 1, 2, 2, 2, 32><<<dim3(512), dim3(256), 20480, stream>>>(
        Bb2, wb + OW6, Bs[6], Ab, s_[5], 1.f / 4096.f, s_[6]);

    // L7: deconv 64->32 @128->256. grid 1024. LDS 20480.
    mfconv<64, 32, 128, 1, 2, 2, 2, 32><<<dim3(1024), dim3(256), 20480, stream>>>(
        Ab, wb + OW7, Bs[7], Bb2, s_[6], 1.f / 16384.f, s_[7]);

    // L8: deconv 32->16 @256->512. M=128, grid 2048. LDS 24576.
    mfconv<32, 16, 256, 1, 1, 2, 2, 64><<<dim3(2048), dim3(256), 24576, stream>>>(
        Bb2, wb + OW8, Bs[8], Ab, s_[7], 1.f / 65536.f, s_[8]);

    // L9: 7x7 16->3 @512, NHWC in + norm + tanh + seg. grid 2048.
    conv7x<true, true><<<dim3(2048), dim3(256), 0, stream>>>(
        nullptr, Ab, wb9, Bs[9], nullptr, s_[8], 1.f / 262144.f, nullptr, inst, segacc);

    seg_final<<<dim3(1), dim3(96), 0, stream>>>(segacc, means);
    seg_scatter<<<dim3(4096), dim3(256), 0, stream>>>(inst, means, out);
}